// Round 20
// baseline (264.817 us; speedup 1.0000x reference)
//
#include <hip/hip_runtime.h>
#include <hip/hip_bf16.h>

#define BB 16
#define NN 4096
#define NPOINTS 1024
#define KK 32
#define NPTS (BB*NPOINTS)        // 16384
#define NWN  (BB*NPOINTS*KK)     // 524288
#define EPSF 1e-5f
#define SGBLK 512
#define SGIT  4

typedef unsigned short u16;
typedef u16  u16x8 __attribute__((ext_vector_type(8)));
typedef u16  u16x4 __attribute__((ext_vector_type(4)));
typedef short s16x8 __attribute__((ext_vector_type(8)));
typedef float f32x4 __attribute__((ext_vector_type(4)));
typedef float f32x4u __attribute__((ext_vector_type(4), aligned(4)));

__device__ __forceinline__ float bf(u16 u){
  union { unsigned int i; float f; } v; v.i = ((unsigned int)u) << 16; return v.f;
}
__device__ __forceinline__ u16 f2b(float f){
  __hip_bfloat16 h = __float2bfloat16(f);
  union { __hip_bfloat16 hh; u16 u; } v; v.hh = h; return v.u;
}

// F layout (folded weights): [0..47] w0f, [48..63] b0f, [64..319] w1f,
// [320..335] b1f, [336..1359] w2f, [1360..1423] b2f
// npw: transposed position space q = o*64 + i  (original channel ch = i*64 + o)
// ptsw[B*N][64] bf16: pre-converted concat(points, xyz) rows
// Gr LDS: K-major, 16B k-blocks XOR-swizzled by (ch>>3)&3
// k_main: H0bf aliases the first 1280 u16 of WrBuf[pt] — dead after barrier(2),
//         Wr written only after barrier(2), so the alias is barrier-ordered.
// NOTE (round 15): device atomics bypass L2 on MI355X -> keep stats streaming.

// ---------------- k_init: newxyz (0..63) + lwbt (64..127) + ptsw build (128..639) ----------------
__global__ __launch_bounds__(256) void k_init(const float* xyz, const int* didx, float* out,
                                              const float* lw, u16* lwbt,
                                              const float* points, u16* ptsw){
  int t = threadIdx.x;
  if (blockIdx.x < 64){
    int p = blockIdx.x * 256 + t;
    int b = p >> 10;
    int idx = didx[p];
    const float* src = xyz + ((size_t)(b * NN + idx)) * 3;
    float* dst = out + (size_t)p * 3;
    dst[0] = src[0]; dst[1] = src[1]; dst[2] = src[2];
  } else if (blockIdx.x < 128){
    __shared__ float T[64][65];
    int ib = blockIdx.x - 64;
    int kb = ib * 64;
    {
      int k = t >> 2, c4 = t & 3;
      #pragma unroll
      for (int j = 0; j < 4; ++j)
        *(f32x4*)&T[k][c4*16 + j*4] = *(const f32x4*)(lw + (size_t)(kb + k)*64 + c4*16 + j*4);
    }
    __syncthreads();
    {
      int n = t >> 2, k4 = t & 3;
      #pragma unroll
      for (int j = 0; j < 16; ++j){
        int k = k4*16 + j;
        lwbt[(size_t)n*4096 + k*64 + ib] = f2b(T[k][n]);
      }
    }
  } else {
    int gid0 = (blockIdx.x - 128) * 256 + t;
    #pragma unroll
    for (int rep = 0; rep < 4; ++rep){
      int idx = gid0 + rep * 131072;
      int row = idx >> 3, c8 = idx & 7;
      const float* prow = points + (size_t)row * 61;
      u16x8 g;
      if (c8 < 7){
        f32x4 lo = *(const f32x4u*)(prow + c8*8);
        f32x4 hi = *(const f32x4u*)(prow + c8*8 + 4);
        g[0]=f2b(lo.x); g[1]=f2b(lo.y); g[2]=f2b(lo.z); g[3]=f2b(lo.w);
        g[4]=f2b(hi.x); g[5]=f2b(hi.y); g[6]=f2b(hi.z); g[7]=f2b(hi.w);
      } else {
        const float* xr = xyz + (size_t)row * 3;
        f32x4 lo = *(const f32x4u*)(prow + 56);
        g[0]=f2b(lo.x); g[1]=f2b(lo.y); g[2]=f2b(lo.z); g[3]=f2b(lo.w);
        g[4]=f2b(prow[60]);
        g[5]=f2b(xr[0]); g[6]=f2b(xr[1]); g[7]=f2b(xr[2]);
      }
      *(u16x8*)(ptsw + (size_t)row*64 + c8*8) = g;
    }
  }
}

// ---------------- k_stat0 ----------------
__global__ __launch_bounds__(256) void k_stat0(const float* lc, float* PA){
  int t = threadIdx.x;
  float a[9];
  #pragma unroll
  for (int r = 0; r < 9; ++r) a[r] = 0.f;
  size_t base = (size_t)blockIdx.x * 1024 + t;
  for (int ip = 0; ip < 4; ++ip){
    size_t p = base + (size_t)ip * 256;
    float x0 = lc[p*3], x1 = lc[p*3+1], x2 = lc[p*3+2];
    a[0]+=x0; a[1]+=x1; a[2]+=x2;
    a[3]+=x0*x0; a[4]+=x0*x1; a[5]+=x0*x2;
    a[6]+=x1*x1; a[7]+=x1*x2; a[8]+=x2*x2;
  }
  #pragma unroll
  for (int m = 1; m < 64; m <<= 1){
    #pragma unroll
    for (int r = 0; r < 9; ++r) a[r] += __shfl_xor(a[r], m);
  }
  if ((t & 63) == 0){
    float* dst = PA + (size_t)(blockIdx.x*4 + (t>>6)) * 16;
    f32x4 v0 = {a[0],a[1],a[2],a[3]}, v1 = {a[4],a[5],a[6],a[7]}, v2 = {a[8],0.f,0.f,0.f};
    *(f32x4*)dst = v0; *(f32x4*)(dst+4) = v1; *(f32x4*)(dst+8) = v2;
  }
}

// ---------------- k_red0 ----------------
__global__ __launch_bounds__(256) void k_red0(const float* PA, const float* w0, const float* b0,
                                              const float* g0, const float* be0, float* F){
  __shared__ float ms[12];
  __shared__ float a0sh[16];
  int t = threadIdx.x;
  if (t < 12){
    float s0=0,s1=0,s2=0,s3=0;
    const float* p = PA + t;
    for (int r = 0; r < 2048; r += 4){
      s0 += p[(size_t)(r+0)*16]; s1 += p[(size_t)(r+1)*16];
      s2 += p[(size_t)(r+2)*16]; s3 += p[(size_t)(r+3)*16];
    }
    ms[t] = (s0+s1)+(s2+s3);
  }
  __syncthreads();
  if (t < 16){
    float wx = w0[t*3], wy = w0[t*3+1], wz = w0[t*3+2], bb = b0[t];
    float lin = wx*ms[0] + wy*ms[1] + wz*ms[2];
    float quad = wx*wx*ms[3] + wy*wy*ms[6] + wz*wz*ms[8]
               + 2.f*(wx*wy*ms[4] + wx*wz*ms[5] + wy*wz*ms[7]);
    float S = lin + (float)NWN * bb;
    float Q = quad + 2.f*bb*lin + (float)NWN*bb*bb;
    float m = S * (1.f/NWN);
    float v = Q * (1.f/NWN) - m*m;
    float a = g0[t] * rsqrtf(v + EPSF);
    float d = be0[t] - m*a;
    a0sh[t] = a;
    F[48+t] = a*bb + d;
  }
  __syncthreads();
  if (t < 48) F[t] = a0sh[t/3] * w0[t];
}

// ---------------- k_statG1: h0 Gram (VALU h0, MFMA Gram) ----------------
__global__ __launch_bounds__(256) void k_statG1(const float* lc, const float* F, float* PB){
  __shared__ f32x4 w0p[16];
  __shared__ __align__(16) u16 Ht[4][16*72];
  __shared__ float GS[4][16][17];
  __shared__ float SHs[4][16];
  int t = threadIdx.x;
  int w = t >> 6, l = t & 63;
  if (t < 16){
    f32x4 wv = {F[t*3], F[t*3+1], F[t*3+2], F[48+t]};
    w0p[t] = wv;
  }
  __syncthreads();
  f32x4 acc = {0.f,0.f,0.f,0.f};
  float sh[16];
  #pragma unroll
  for (int r = 0; r < 16; ++r) sh[r] = 0.f;
  u16* Hw = &Ht[w][0];
  for (int it = 0; it < SGIT; ++it){
    size_t p = (size_t)blockIdx.x * (SGIT*256) + (size_t)it*256 + w*64 + l;
    float x0 = lc[p*3], x1 = lc[p*3+1], x2 = lc[p*3+2];
    float h[16];
    #pragma unroll
    for (int oc = 0; oc < 16; ++oc){
      f32x4 wv = w0p[oc];
      h[oc] = fmaxf(0.f, wv.x*x0 + wv.y*x1 + wv.z*x2 + wv.w);
      sh[oc] += h[oc];
    }
    #pragma unroll
    for (int c = 0; c < 16; ++c) Hw[c*72 + l] = f2b(h[c]);
    __syncthreads();
    #pragma unroll
    for (int tt = 0; tt < 2; ++tt){
      s16x8 af = *(const s16x8*)&Hw[(l & 15)*72 + tt*32 + (l >> 4)*8];
      acc = __builtin_amdgcn_mfma_f32_16x16x32_bf16(af, af, acc, 0, 0, 0);
    }
    __syncthreads();
  }
  #pragma unroll
  for (int r = 0; r < 4; ++r)
    GS[w][(l>>4)*4 + r][l & 15] = acc[r];
  #pragma unroll
  for (int m = 1; m < 64; m <<= 1){
    #pragma unroll
    for (int r = 0; r < 16; ++r) sh[r] += __shfl_xor(sh[r], m);
  }
  if (l == 0){
    #pragma unroll
    for (int r = 0; r < 16; ++r) SHs[w][r] = sh[r];
  }
  __syncthreads();
  {
    int i = t >> 4, j = t & 15;
    float g = GS[0][i][j] + GS[1][i][j] + GS[2][i][j] + GS[3][i][j];
    PB[(size_t)blockIdx.x*272 + t] = g;
    if (t < 16)
      PB[(size_t)blockIdx.x*272 + 256 + t] = SHs[0][t]+SHs[1][t]+SHs[2][t]+SHs[3][t];
  }
}

// ---------------- k_statG2: h1 Gram (MFMA h1 via w1Bg + MFMA Gram) ----------------
__global__ __launch_bounds__(256) void k_statG2(const float* lc, const float* F,
                                                const u16* w1Bg, float* PB){
  __shared__ f32x4 w0p[16];
  __shared__ __align__(16) u16 Ht0[4][64*40];
  __shared__ __align__(16) u16 Ht1[4][16*72];
  __shared__ float GS[4][16][17];
  __shared__ float SHs[4][16];
  int t = threadIdx.x;
  int w = t >> 6, l = t & 63;
  if (t < 16){
    f32x4 wv = {F[t*3], F[t*3+1], F[t*3+2], F[48+t]};
    w0p[t] = wv;
  }
  s16x8 w1B = *(const s16x8*)&w1Bg[l*8];
  float b1f = F[320 + (l & 15)];
  u16* H0w = &Ht0[w][0];
  u16* H1w = &Ht1[w][0];
  {
    u16x8 z8 = {0,0,0,0,0,0,0,0};
    *(u16x8*)&H0w[l*40 + 16] = z8;
    *(u16x8*)&H0w[l*40 + 24] = z8;
  }
  __syncthreads();
  f32x4 acc = {0.f,0.f,0.f,0.f};
  float shloc = 0.f;
  for (int it = 0; it < SGIT; ++it){
    size_t p = (size_t)blockIdx.x * (SGIT*256) + (size_t)it*256 + w*64 + l;
    float x0 = lc[p*3], x1 = lc[p*3+1], x2 = lc[p*3+2];
    u16x8 p0, p1;
    #pragma unroll
    for (int oc = 0; oc < 8; ++oc){
      f32x4 wv = w0p[oc];
      p0[oc] = f2b(fmaxf(0.f, wv.x*x0 + wv.y*x1 + wv.z*x2 + wv.w));
    }
    #pragma unroll
    for (int oc = 0; oc < 8; ++oc){
      f32x4 wv = w0p[8+oc];
      p1[oc] = f2b(fmaxf(0.f, wv.x*x0 + wv.y*x1 + wv.z*x2 + wv.w));
    }
    *(u16x8*)&H0w[l*40]     = p0;
    *(u16x8*)&H0w[l*40 + 8] = p1;
    __syncthreads();
    #pragma unroll
    for (int mt = 0; mt < 4; ++mt){
      s16x8 af = *(const s16x8*)&H0w[(mt*16 + (l & 15))*40 + (l >> 4)*8];
      f32x4 c = {b1f, b1f, b1f, b1f};
      c = __builtin_amdgcn_mfma_f32_16x16x32_bf16(af, w1B, c, 0, 0, 0);
      #pragma unroll
      for (int r = 0; r < 4; ++r){
        float v = fmaxf(0.f, c[r]);
        shloc += v;
        H1w[(l & 15)*72 + mt*16 + (l >> 4)*4 + r] = f2b(v);
      }
    }
    __syncthreads();
    #pragma unroll
    for (int tt = 0; tt < 2; ++tt){
      s16x8 afg = *(const s16x8*)&H1w[(l & 15)*72 + tt*32 + (l >> 4)*8];
      acc = __builtin_amdgcn_mfma_f32_16x16x32_bf16(afg, afg, acc, 0, 0, 0);
    }
    __syncthreads();
  }
  #pragma unroll
  for (int r = 0; r < 4; ++r)
    GS[w][(l>>4)*4 + r][l & 15] = acc[r];
  shloc += __shfl_xor(shloc, 16);
  shloc += __shfl_xor(shloc, 32);
  if (l < 16) SHs[w][l] = shloc;
  __syncthreads();
  {
    int i = t >> 4, j = t & 15;
    float g = GS[0][i][j] + GS[1][i][j] + GS[2][i][j] + GS[3][i][j];
    PB[(size_t)blockIdx.x*272 + t] = g;
    if (t < 16)
      PB[(size_t)blockIdx.x*272 + 256 + t] = SHs[0][t]+SHs[1][t]+SHs[2][t]+SHs[3][t];
  }
}

// ---------------- k_red1 ----------------
__global__ __launch_bounds__(256) void k_red1(const float* PB, const float* w1, const float* b1,
                                              const float* g1, const float* be1, float* F,
                                              u16* w1Bg){
  __shared__ float red[272];
  __shared__ float a1sh[16];
  int t = threadIdx.x;
  for (int e = t; e < 272; e += 256){
    float s = 0.f;
    for (int r = 0; r < SGBLK; ++r) s += PB[(size_t)r*272 + e];
    red[e] = s;
  }
  __syncthreads();
  if (t < 16){
    float wv[16];
    #pragma unroll
    for (int ic = 0; ic < 16; ++ic) wv[ic] = w1[t*16+ic];
    float lin = 0.f;
    #pragma unroll
    for (int ic = 0; ic < 16; ++ic) lin += wv[ic]*red[256+ic];
    float quad = 0.f;
    for (int i = 0; i < 16; ++i){
      float ri = 0.f;
      #pragma unroll
      for (int j = 0; j < 16; ++j) ri += wv[j]*red[i*16+j];
      quad += wv[i]*ri;
    }
    float bb = b1[t];
    float S = lin + (float)NWN * bb;
    float Q = quad + 2.f*bb*lin + (float)NWN*bb*bb;
    float m = S * (1.f/NWN);
    float v = Q * (1.f/NWN) - m*m;
    float a = g1[t] * rsqrtf(v + EPSF);
    float d = be1[t] - m*a;
    a1sh[t] = a;
    F[320+t] = a*bb + d;
  }
  __syncthreads();
  F[64 + t] = a1sh[t >> 4] * w1[t];
  if (t < 64){
    int oc = t & 15, icb = (t >> 4) * 8;
    u16x8 fr;
    #pragma unroll
    for (int j = 0; j < 8; ++j){
      int ic = icb + j;
      fr[j] = (ic < 16) ? f2b(a1sh[oc] * w1[oc*16 + ic]) : (u16)0;
    }
    *(u16x8*)&w1Bg[t*8] = fr;
  }
}

// ---------------- k_red2 ----------------
__global__ __launch_bounds__(256) void k_red2(const float* PB, const float* w2, const float* b2,
                                              const float* g2, const float* be2, float* F,
                                              u16* w2Bg){
  __shared__ float red[272];
  __shared__ float a2sh[64];
  int t = threadIdx.x;
  for (int e = t; e < 272; e += 256){
    float s = 0.f;
    for (int r = 0; r < SGBLK; ++r) s += PB[(size_t)r*272 + e];
    red[e] = s;
  }
  __syncthreads();
  if (t < 64){
    float wv[16];
    #pragma unroll
    for (int ic = 0; ic < 16; ++ic) wv[ic] = w2[t*16+ic];
    float lin = 0.f;
    #pragma unroll
    for (int ic = 0; ic < 16; ++ic) lin += wv[ic]*red[256+ic];
    float quad = 0.f;
    for (int i = 0; i < 16; ++i){
      float ri = 0.f;
      #pragma unroll
      for (int j = 0; j < 16; ++j) ri += wv[j]*red[i*16+j];
      quad += wv[i]*ri;
    }
    float bb = b2[t];
    float S = lin + (float)NWN * bb;
    float Q = quad + 2.f*bb*lin + (float)NWN*bb*bb;
    float m = S * (1.f/NWN);
    float v = Q * (1.f/NWN) - m*m;
    float a = g2[t] * rsqrtf(v + EPSF);
    float d = be2[t] - m*a;
    a2sh[t] = a;
    F[1360+t] = a*bb + d;
  }
  __syncthreads();
  for (int i = t; i < 1024; i += 256) F[336+i] = a2sh[i >> 4] * w2[i];
  {
    int ot = t >> 6, lane = t & 63;
    int oc = ot*16 + (lane & 15), icb = ((lane >> 4)) * 8;
    u16x8 fr;
    #pragma unroll
    for (int j = 0; j < 8; ++j){
      int ic = icb + j;
      fr[j] = (ic < 16) ? f2b(a2sh[oc] * w2[oc*16 + ic]) : (u16)0;
    }
    *(u16x8*)&w2Bg[t*8] = fr;
  }
}

// ---------------- K5: TWO points per block — MFMA WeightNet + MFMA matmul, 3 barriers ----------------
// H0bf aliases WrBuf[pt][0..1279]; safe: H0 reads end at barrier(2), Wr writes start after it.
__global__ __launch_bounds__(256) void k_main(const float* lcg, const int* nbrg,
    const u16* ptsw, const float* F,
    const u16* w1Bg, const u16* w2Bg,
    u16* npw){
  __shared__ __align__(16) u16 Gr[2][64*40];        // swizzled K-major per point
  __shared__ __align__(16) u16 WrBuf[2][64*40];     // W output; [0..1279] doubles as H0bf
  __shared__ __align__(16) u16 H1bf[2][32*40];
  int t = threadIdx.x;
  int w = t >> 6, l = t & 63;
  int p0 = blockIdx.x * 2;
  s16x8 w1B  = *(const s16x8*)&w1Bg[l*8];
  s16x8 w2B0 = *(const s16x8*)&w2Bg[(0*64 + l)*8];
  s16x8 w2B1 = *(const s16x8*)&w2Bg[(1*64 + l)*8];
  s16x8 w2B2 = *(const s16x8*)&w2Bg[(2*64 + l)*8];
  s16x8 w2B3 = *(const s16x8*)&w2Bg[(3*64 + l)*8];
  float b1f  = F[320 + (l & 15)];
  float b2f0 = F[1360 +  0 + (l & 15)];
  float b2f1 = F[1360 + 16 + (l & 15)];
  float b2f2 = F[1360 + 32 + (l & 15)];
  float b2f3 = F[1360 + 48 + (l & 15)];
  int oc0 = (t & 7) * 2;
  f32x4 w0a = {F[oc0*3], F[oc0*3+1], F[oc0*3+2], F[48+oc0]};
  f32x4 w0b = {F[oc0*3+3], F[oc0*3+4], F[oc0*3+5], F[48+oc0+1]};
  // zero-pad ic 16..31 rows of H0(=WrBuf lower part) and H1bf
  {
    int k = t >> 3, c = 16 + (t & 7)*2;
    *(unsigned int*)&WrBuf[0][k*40 + c] = 0u;
    *(unsigned int*)&WrBuf[1][k*40 + c] = 0u;
    *(unsigned int*)&H1bf[0][k*40 + c] = 0u;
    *(unsigned int*)&H1bf[1][k*40 + c] = 0u;
  }
  // gather both points -> Gr swizzled K-major
  {
    int kg = w*8 + (l >> 3), c8 = l & 7;
    int kphys = ((w ^ (c8 & 3)) << 3) + (l >> 3);
    #pragma unroll
    for (int pt = 0; pt < 2; ++pt){
      int point = p0 + pt;
      int bbp = point >> 10;
      int n = nbrg[(size_t)point*32 + kg];
      u16x8 g = *(const u16x8*)(ptsw + (size_t)(bbp * NN + n)*64 + c8*8);
      #pragma unroll
      for (int j = 0; j < 8; ++j)
        Gr[pt][(c8*8 + j)*40 + kphys] = g[j];
    }
  }
  // H0 both points (w0 in registers)
  {
    int k = t >> 3;
    #pragma unroll
    for (int pt = 0; pt < 2; ++pt){
      const float* xp = lcg + (size_t)(p0 + pt)*96 + k*3;
      float x0 = xp[0], x1 = xp[1], x2 = xp[2];
      WrBuf[pt][k*40 + oc0]     = f2b(fmaxf(0.f, w0a.x*x0 + w0a.y*x1 + w0a.z*x2 + w0a.w));
      WrBuf[pt][k*40 + oc0 + 1] = f2b(fmaxf(0.f, w0b.x*x0 + w0b.y*x1 + w0b.z*x2 + w0b.w));
    }
  }
  __syncthreads();   // (1) H0(=WrBuf low) + pads ready
  // H1: wave w -> pt = w>>1, kt = w&1
  {
    int pt = w >> 1, kt = w & 1;
    s16x8 af = *(const s16x8*)&WrBuf[pt][(kt*16 + (l & 15))*40 + (l >> 4)*8];
    f32x4 acc = {b1f, b1f, b1f, b1f};
    acc = __builtin_amdgcn_mfma_f32_16x16x32_bf16(af, w1B, acc, 0, 0, 0);
    #pragma unroll
    for (int r = 0; r < 4; ++r)
      H1bf[pt][(kt*16 + (l >> 4)*4 + r)*40 + (l & 15)] = f2b(fmaxf(0.f, acc[r]));
  }
  __syncthreads();   // (2) H1bf ready; H0 region now dead -> Wr may overwrite
  // W: wave w -> pt = w&1, kt = w>>1; 4 o-tiles
  {
    int pt = w & 1, kt = w >> 1;
    s16x8 af = *(const s16x8*)&H1bf[pt][(kt*16 + (l & 15))*40 + (l >> 4)*8];
    int kbase = kt*16 + (l >> 4)*4;
    f32x4 a0c = {b2f0,b2f0,b2f0,b2f0};
    a0c = __builtin_amdgcn_mfma_f32_16x16x32_bf16(af, w2B0, a0c, 0, 0, 0);
    u16x4 s0v; s0v[0]=f2b(fmaxf(0.f,a0c[0])); s0v[1]=f2b(fmaxf(0.f,a0c[1]));
    s0v[2]=f2b(fmaxf(0.f,a0c[2])); s0v[3]=f2b(fmaxf(0.f,a0c[3]));
    *(u16x4*)&WrBuf[pt][( 0 + (l & 15))*40 + kbase] = s0v;
    f32x4 a1c = {b2f1,b2f1,b2f1,b2f1};
    a1c = __builtin_amdgcn_mfma_f32_16x16x32_bf16(af, w2B1, a1c, 0, 0, 0);
    u16x4 s1v; s1v[0]=f2b(fmaxf(0.f,a1c[0])); s1v[1]=f2b(fmaxf(0.f,a1c[1]));
    s1v[2]=f2b(fmaxf(0.f,a1c[2])); s1v[3]=f2b(fmaxf(0.f,a1c[3]));
    *(u16x4*)&WrBuf[pt][(16 + (l & 15))*40 + kbase] = s1v;
    f32x4 a2c = {b2f2,b2f2,b2f2,b2f2};
    a2c = __builtin_amdgcn_mfma_f32_16x16x32_bf16(af, w2B2, a2c, 0, 0, 0);
    u16x4 s2v; s2v[0]=f2b(fmaxf(0.f,a2c[0])); s2v[1]=f2b(fmaxf(0.f,a2c[1]));
    s2v[2]=f2b(fmaxf(0.f,a2c[2])); s2v[3]=f2b(fmaxf(0.f,a2c[3]));
    *(u16x4*)&WrBuf[pt][(32 + (l & 15))*40 + kbase] = s2v;
    f32x4 a3c = {b2f3,b2f3,b2f3,b2f3};
    a3c = __builtin_amdgcn_mfma_f32_16x16x32_bf16(af, w2B3, a3c, 0, 0, 0);
    u16x4 s3v; s3v[0]=f2b(fmaxf(0.f,a3c[0])); s3v[1]=f2b(fmaxf(0.f,a3c[1]));
    s3v[2]=f2b(fmaxf(0.f,a3c[2])); s3v[3]=f2b(fmaxf(0.f,a3c[3]));
    *(u16x4*)&WrBuf[pt][(48 + (l & 15))*40 + kbase] = s3v;
  }
  __syncthreads();   // (3) Gr, Wr ready
  // np = G^T W: wave w owns o-tile w, both points
  {
    int li = l & 15, lkb = l >> 4, lr = (l >> 4) * 4;
    #pragma unroll
    for (int pt = 0; pt < 2; ++pt){
      s16x8 bfrag = *(const s16x8*)&WrBuf[pt][(w*16 + li)*40 + lkb*8];
      size_t obase = (size_t)(p0 + pt)*4096 + (size_t)(w*16 + li)*64 + lr;
      #pragma unroll
      for (int it = 0; it < 4; ++it){
        int ch = it*16 + li;
        int key = (ch >> 3) & 3;
        s16x8 afrag = *(const s16x8*)&Gr[pt][ch*40 + ((lkb ^ key) << 3)];
        f32x4 z = {0.f, 0.f, 0.f, 0.f};
        f32x4 d = __builtin_amdgcn_mfma_f32_16x16x32_bf16(afrag, bfrag, z, 0, 0, 0);
        u16x4 st;
        st[0] = f2b(d[0]); st[1] = f2b(d[1]); st[2] = f2b(d[2]); st[3] = f2b(d[3]);
        *(u16x4*)(npw + obase + it*16) = st;
      }
    }
  }
}

// ---------------- k_statC ----------------
__global__ __launch_bounds__(256) void k_statC(const u16* npw, float* PC){
  int t = threadIdx.x;
  float s[16], q[16];
  #pragma unroll
  for (int j = 0; j < 16; ++j){ s[j] = 0.f; q[j] = 0.f; }
  size_t rowbase = (size_t)blockIdx.x * 64;
  for (int p = 0; p < 64; ++p){
    const u16* row = npw + (rowbase + p) * 4096 + t * 16;
    u16x8 a = *(const u16x8*)row;
    u16x8 b = *(const u16x8*)(row + 8);
    #pragma unroll
    for (int j = 0; j < 8; ++j){ float v = bf(a[j]); s[j]   += v; q[j]   += v*v; }
    #pragma unroll
    for (int j = 0; j < 8; ++j){ float v = bf(b[j]); s[8+j] += v; q[8+j] += v*v; }
  }
  float* dst = PC + (size_t)blockIdx.x * 8192 + t * 16;
  #pragma unroll
  for (int j = 0; j < 16; ++j){ dst[j] = s[j]; dst[4096 + j] = q[j]; }
}

// ---------------- k_finC (position space; gc/bc permuted) ----------------
__global__ __launch_bounds__(256) void k_finC(const float* PC, const float* gc, const float* bc,
                                              float* AC, float* DC){
  int qpos = blockIdx.x * 256 + threadIdx.x;
  float s = 0.f, q = 0.f;
  for (int r = 0; r < 256; ++r){
    s += PC[(size_t)r * 8192 + qpos];
    q += PC[(size_t)r * 8192 + 4096 + qpos];
  }
  int ch = (qpos & 63)*64 + (qpos >> 6);
  float m = s * (1.f/16384.f);
  float v = q * (1.f/16384.f) - m*m;
  float a = gc[ch] * rsqrtf(v + EPSF);
  AC[qpos] = a; DC[qpos] = bc[ch] - m*a;
}

// ---------------- k_linear: 16 rows/block, grid 1024 (occupancy fix) ----------------
__global__ __launch_bounds__(256) void k_linear(const u16* npw, const float* AC, const float* DC,
                                                const u16* lwbt, const float* lb, float* yw,
                                                float* PL){
  __shared__ u16 Al[16*72];
  __shared__ u16 Bl[64*72];
  __shared__ float cps[64], cpq[64];
  int t = threadIdx.x;
  int w = t >> 6, l = t & 63;
  int rowbase = blockIdx.x * 16;
  f32x4 acc0 = {0.f,0.f,0.f,0.f};
  for (int kb = 0; kb < 4096; kb += 64){
    __syncthreads();
    // stage A: 16 rows x 64 k; one u16x4 per thread
    {
      int r = t >> 4, c4 = t & 15;
      int kk = kb + c4*4;
      u16x4 u = *(const u16x4*)(npw + (size_t)(rowbase + r)*4096 + kk);
      f32x4 av = *(const f32x4*)(AC + kk);
      f32x4 dv = *(const f32x4*)(DC + kk);
      u16x4 o;
      o[0] = f2b(fmaxf(0.f, av.x*bf(u[0]) + dv.x));
      o[1] = f2b(fmaxf(0.f, av.y*bf(u[1]) + dv.y));
      o[2] = f2b(fmaxf(0.f, av.z*bf(u[2]) + dv.z));
      o[3] = f2b(fmaxf(0.f, av.w*bf(u[3]) + dv.w));
      *(u16x4*)&Al[r*72 + c4*4] = o;
    }
    // stage B: 64 x 64
    #pragma unroll
    for (int jj = 0; jj < 2; ++jj){
      int n = (t >> 3) + jj*32, c8 = t & 7;
      u16x8 u = *(const u16x8*)(lwbt + (size_t)n*4096 + kb + c8*8);
      *(u16x8*)&Bl[n*72 + c8*8] = u;
    }
    __syncthreads();
    #pragma unroll
    for (int ks = 0; ks < 2; ++ks){
      s16x8 af  = *(const s16x8*)&Al[((l & 15))*72 + ks*32 + (l >> 4)*8];
      s16x8 bf0 = *(const s16x8*)&Bl[(w*16 + (l & 15))*72 + ks*32 + (l >> 4)*8];
      acc0 = __builtin_amdgcn_mfma_f32_16x16x32_bf16(af, bf0, acc0, 0, 0, 0);
    }
  }
  int col0 = w*16 + (l & 15);
  float lb0 = lb[col0];
  float s0 = 0.f, q0 = 0.f;
  if (t < 64){ cps[t] = 0.f; cpq[t] = 0.f; }
  __syncthreads();
  #pragma unroll
  for (int r = 0; r < 4; ++r){
    int row = rowbase + (l >> 4)*4 + r;
    float y0 = acc0[r] + lb0;
    yw[(size_t)row*64 + col0] = y0;
    s0 += y0; q0 += y0*y0;
  }
  atomicAdd(&cps[col0], s0); atomicAdd(&cpq[col0], q0);
  __syncthreads();
  if (t < 64){
    PL[blockIdx.x*128 + t]      = cps[t];
    PL[blockIdx.x*128 + 64 + t] = cpq[t];
  }
}

// ---------------- k_redF (1024 blocks of PL) ----------------
__global__ __launch_bounds__(128) void k_redF(const float* PL, float* SL){
  int t = threadIdx.x;
  float s = 0.f;
  for (int b = 0; b < 1024; ++b) s += PL[b*128 + t];
  SL[t] = s;
}

// ---------------- k_final ----------------
__global__ __launch_bounds__(256) void k_final(const float* yw, const float* SL,
                                               const float* gl, const float* bl, float* out){
  int e = (blockIdx.x * 256 + threadIdx.x) * 4;
  int o = e & 63;
  f32x4 y = *(const f32x4*)(yw + e);
  f32x4 r;
  #pragma unroll
  for (int j = 0; j < 4; ++j){
    float m = SL[o+j] * (1.f/16384.f);
    float v = SL[64+o+j] * (1.f/16384.f) - m*m;
    float a = gl[o+j] * rsqrtf(v + EPSF);
    float d = bl[o+j] - m*a;
    r[j] = fmaxf(0.f, a*y[j] + d);
  }
  *(f32x4*)(out + 49152 + e) = r;
}

extern "C" void kernel_launch(void* const* d_in, const int* in_sizes, int n_in,
                              void* d_out, int out_size, void* d_ws, size_t ws_size,
                              hipStream_t stream){
  (void)in_sizes; (void)n_in; (void)out_size; (void)ws_size;
  const float* xyz    = (const float*)d_in[0];
  const float* points = (const float*)d_in[1];
  const float* lc     = (const float*)d_in[2];
  const int*   nbrl   = (const int*)d_in[3];
  const int*   didx   = (const int*)d_in[4];
  const float* w0 = (const float*)d_in[5];
  const float* b0 = (const float*)d_in[6];
  const float* g0 = (const float*)d_in[7];
  const float* be0= (const float*)d_in[8];
  const float* w1 = (const float*)d_in[9];
  const float* b1 = (const float*)d_in[10];
  const float* g1 = (const float*)d_in[11];
  const float* be1= (const float*)d_in[12];
  const float* w2 = (const float*)d_in[13];
  const float* b2 = (const float*)d_in[14];
  const float* g2 = (const float*)d_in[15];
  const float* be2= (const float*)d_in[16];
  const float* gc = (const float*)d_in[17];
  const float* bc = (const float*)d_in[18];
  const float* lw = (const float*)d_in[19];
  const float* lb = (const float*)d_in[20];
  const float* gl = (const float*)d_in[21];
  const float* bl = (const float*)d_in[22];
  float* out = (float*)d_out;
  char* ws = (char*)d_ws;

  float* F   = (float*)ws;           // 1536
  float* SL  = F + 1536;             // 128
  float* AC  = SL + 128;             // 4096
  float* DC  = AC + 4096;            // 4096
  float* PA  = DC + 4096;            // 32768
  float* PB1 = PA + 32768;           // 139264
  float* PB2 = PB1 + 139264;         // 139264
  float* PL  = PB2 + 139264;         // 131072 (1024 blocks x 128)
  u16*  w1Bg = (u16*)(PL + 131072);  // 512 u16
  u16*  w2Bg = w1Bg + 512;           // 2048 u16
  float* PC  = (float*)(ws + 4194304);                        // 8 MB
  u16*  npw  = (u16*)(ws + 4194304 + 8388608);                // 128 MB bf16 (transposed)
  float* yw  = (float*)(ws + 4194304 + 8388608 + 134217728);  // 4 MB f32
  u16*  lwbt = (u16*)(ws + 4194304 + 8388608 + 134217728 + 4194304); // 512 KB (permuted)
  u16*  ptsw = (u16*)(ws + 4194304 + 8388608 + 134217728 + 4194304 + 1048576); // 8 MB bf16

  k_init  <<<640,   256, 0, stream>>>(xyz, didx, out, lw, lwbt, points, ptsw);
  k_stat0 <<<512,   256, 0, stream>>>(lc, PA);
  k_red0  <<<1,     256, 0, stream>>>(PA, w0, b0, g0, be0, F);
  k_statG1<<<SGBLK, 256, 0, stream>>>(lc, F, PB1);
  k_red1  <<<1,     256, 0, stream>>>(PB1, w1, b1, g1, be1, F, w1Bg);
  k_statG2<<<SGBLK, 256, 0, stream>>>(lc, F, w1Bg, PB2);
  k_red2  <<<1,     256, 0, stream>>>(PB2, w2, b2, g2, be2, F, w2Bg);
  k_main  <<<8192,  256, 0, stream>>>(lc, nbrl, ptsw, F, w1Bg, w2Bg, npw);
  k_statC <<<256,   256, 0, stream>>>(npw, PC);
  k_finC  <<<16,    256, 0, stream>>>(PC, gc, bc, AC, DC);
  k_linear<<<1024,  256, 0, stream>>>(npw, AC, DC, lwbt, lb, yw, PL);
  k_redF  <<<1,     128, 0, stream>>>(PL, SL);
  k_final <<<1024,  256, 0, stream>>>(yw, SL, gl, bl, out);
}

// Round 21
// 259.062 us; speedup vs baseline: 1.0222x; 1.0222x over previous
//
#include <hip/hip_runtime.h>
#include <hip/hip_bf16.h>

#define BB 16
#define NN 4096
#define NPOINTS 1024
#define KK 32
#define NPTS (BB*NPOINTS)        // 16384
#define NWN  (BB*NPOINTS*KK)     // 524288
#define EPSF 1e-5f
#define SGBLK 512
#define SGIT  4

typedef unsigned short u16;
typedef u16  u16x8 __attribute__((ext_vector_type(8)));
typedef u16  u16x4 __attribute__((ext_vector_type(4)));
typedef short s16x8 __attribute__((ext_vector_type(8)));
typedef float f32x4 __attribute__((ext_vector_type(4)));
typedef float f32x4u __attribute__((ext_vector_type(4), aligned(4)));

__device__ __forceinline__ float bf(u16 u){
  union { unsigned int i; float f; } v; v.i = ((unsigned int)u) << 16; return v.f;
}
__device__ __forceinline__ u16 f2b(float f){
  __hip_bfloat16 h = __float2bfloat16(f);
  union { __hip_bfloat16 hh; u16 u; } v; v.hh = h; return v.u;
}

// F layout (folded weights): [0..47] w0f, [48..63] b0f, [64..319] w1f,
// [320..335] b1f, [336..1359] w2f, [1360..1423] b2f
// npw: transposed position space q = o*64 + i  (original channel ch = i*64 + o)
// ptsw[B*N][64] bf16: pre-converted concat(points, xyz) rows
// Gr LDS: K-major, 16B k-blocks XOR-swizzled by (ch>>3)&3
// k_main: H0bf aliases WrBuf[pt][0..1279] — dead after barrier(2), Wr written after it.
// k_linear: register-prefetch software pipeline (round 21).
// NOTE (round 15): device atomics bypass L2 on MI355X -> keep stats streaming.

// ---------------- k_init: newxyz (0..63) + lwbt (64..127) + ptsw build (128..639) ----------------
__global__ __launch_bounds__(256) void k_init(const float* xyz, const int* didx, float* out,
                                              const float* lw, u16* lwbt,
                                              const float* points, u16* ptsw){
  int t = threadIdx.x;
  if (blockIdx.x < 64){
    int p = blockIdx.x * 256 + t;
    int b = p >> 10;
    int idx = didx[p];
    const float* src = xyz + ((size_t)(b * NN + idx)) * 3;
    float* dst = out + (size_t)p * 3;
    dst[0] = src[0]; dst[1] = src[1]; dst[2] = src[2];
  } else if (blockIdx.x < 128){
    __shared__ float T[64][65];
    int ib = blockIdx.x - 64;
    int kb = ib * 64;
    {
      int k = t >> 2, c4 = t & 3;
      #pragma unroll
      for (int j = 0; j < 4; ++j)
        *(f32x4*)&T[k][c4*16 + j*4] = *(const f32x4*)(lw + (size_t)(kb + k)*64 + c4*16 + j*4);
    }
    __syncthreads();
    {
      int n = t >> 2, k4 = t & 3;
      #pragma unroll
      for (int j = 0; j < 16; ++j){
        int k = k4*16 + j;
        lwbt[(size_t)n*4096 + k*64 + ib] = f2b(T[k][n]);
      }
    }
  } else {
    int gid0 = (blockIdx.x - 128) * 256 + t;
    #pragma unroll
    for (int rep = 0; rep < 4; ++rep){
      int idx = gid0 + rep * 131072;
      int row = idx >> 3, c8 = idx & 7;
      const float* prow = points + (size_t)row * 61;
      u16x8 g;
      if (c8 < 7){
        f32x4 lo = *(const f32x4u*)(prow + c8*8);
        f32x4 hi = *(const f32x4u*)(prow + c8*8 + 4);
        g[0]=f2b(lo.x); g[1]=f2b(lo.y); g[2]=f2b(lo.z); g[3]=f2b(lo.w);
        g[4]=f2b(hi.x); g[5]=f2b(hi.y); g[6]=f2b(hi.z); g[7]=f2b(hi.w);
      } else {
        const float* xr = xyz + (size_t)row * 3;
        f32x4 lo = *(const f32x4u*)(prow + 56);
        g[0]=f2b(lo.x); g[1]=f2b(lo.y); g[2]=f2b(lo.z); g[3]=f2b(lo.w);
        g[4]=f2b(prow[60]);
        g[5]=f2b(xr[0]); g[6]=f2b(xr[1]); g[7]=f2b(xr[2]);
      }
      *(u16x8*)(ptsw + (size_t)row*64 + c8*8) = g;
    }
  }
}

// ---------------- k_stat0 ----------------
__global__ __launch_bounds__(256) void k_stat0(const float* lc, float* PA){
  int t = threadIdx.x;
  float a[9];
  #pragma unroll
  for (int r = 0; r < 9; ++r) a[r] = 0.f;
  size_t base = (size_t)blockIdx.x * 1024 + t;
  for (int ip = 0; ip < 4; ++ip){
    size_t p = base + (size_t)ip * 256;
    float x0 = lc[p*3], x1 = lc[p*3+1], x2 = lc[p*3+2];
    a[0]+=x0; a[1]+=x1; a[2]+=x2;
    a[3]+=x0*x0; a[4]+=x0*x1; a[5]+=x0*x2;
    a[6]+=x1*x1; a[7]+=x1*x2; a[8]+=x2*x2;
  }
  #pragma unroll
  for (int m = 1; m < 64; m <<= 1){
    #pragma unroll
    for (int r = 0; r < 9; ++r) a[r] += __shfl_xor(a[r], m);
  }
  if ((t & 63) == 0){
    float* dst = PA + (size_t)(blockIdx.x*4 + (t>>6)) * 16;
    f32x4 v0 = {a[0],a[1],a[2],a[3]}, v1 = {a[4],a[5],a[6],a[7]}, v2 = {a[8],0.f,0.f,0.f};
    *(f32x4*)dst = v0; *(f32x4*)(dst+4) = v1; *(f32x4*)(dst+8) = v2;
  }
}

// ---------------- k_red0 ----------------
__global__ __launch_bounds__(256) void k_red0(const float* PA, const float* w0, const float* b0,
                                              const float* g0, const float* be0, float* F){
  __shared__ float ms[12];
  __shared__ float a0sh[16];
  int t = threadIdx.x;
  if (t < 12){
    float s0=0,s1=0,s2=0,s3=0;
    const float* p = PA + t;
    for (int r = 0; r < 2048; r += 4){
      s0 += p[(size_t)(r+0)*16]; s1 += p[(size_t)(r+1)*16];
      s2 += p[(size_t)(r+2)*16]; s3 += p[(size_t)(r+3)*16];
    }
    ms[t] = (s0+s1)+(s2+s3);
  }
  __syncthreads();
  if (t < 16){
    float wx = w0[t*3], wy = w0[t*3+1], wz = w0[t*3+2], bb = b0[t];
    float lin = wx*ms[0] + wy*ms[1] + wz*ms[2];
    float quad = wx*wx*ms[3] + wy*wy*ms[6] + wz*wz*ms[8]
               + 2.f*(wx*wy*ms[4] + wx*wz*ms[5] + wy*wz*ms[7]);
    float S = lin + (float)NWN * bb;
    float Q = quad + 2.f*bb*lin + (float)NWN*bb*bb;
    float m = S * (1.f/NWN);
    float v = Q * (1.f/NWN) - m*m;
    float a = g0[t] * rsqrtf(v + EPSF);
    float d = be0[t] - m*a;
    a0sh[t] = a;
    F[48+t] = a*bb + d;
  }
  __syncthreads();
  if (t < 48) F[t] = a0sh[t/3] * w0[t];
}

// ---------------- k_statG1: h0 Gram (VALU h0, MFMA Gram) ----------------
__global__ __launch_bounds__(256) void k_statG1(const float* lc, const float* F, float* PB){
  __shared__ f32x4 w0p[16];
  __shared__ __align__(16) u16 Ht[4][16*72];
  __shared__ float GS[4][16][17];
  __shared__ float SHs[4][16];
  int t = threadIdx.x;
  int w = t >> 6, l = t & 63;
  if (t < 16){
    f32x4 wv = {F[t*3], F[t*3+1], F[t*3+2], F[48+t]};
    w0p[t] = wv;
  }
  __syncthreads();
  f32x4 acc = {0.f,0.f,0.f,0.f};
  float sh[16];
  #pragma unroll
  for (int r = 0; r < 16; ++r) sh[r] = 0.f;
  u16* Hw = &Ht[w][0];
  for (int it = 0; it < SGIT; ++it){
    size_t p = (size_t)blockIdx.x * (SGIT*256) + (size_t)it*256 + w*64 + l;
    float x0 = lc[p*3], x1 = lc[p*3+1], x2 = lc[p*3+2];
    float h[16];
    #pragma unroll
    for (int oc = 0; oc < 16; ++oc){
      f32x4 wv = w0p[oc];
      h[oc] = fmaxf(0.f, wv.x*x0 + wv.y*x1 + wv.z*x2 + wv.w);
      sh[oc] += h[oc];
    }
    #pragma unroll
    for (int c = 0; c < 16; ++c) Hw[c*72 + l] = f2b(h[c]);
    __syncthreads();
    #pragma unroll
    for (int tt = 0; tt < 2; ++tt){
      s16x8 af = *(const s16x8*)&Hw[(l & 15)*72 + tt*32 + (l >> 4)*8];
      acc = __builtin_amdgcn_mfma_f32_16x16x32_bf16(af, af, acc, 0, 0, 0);
    }
    __syncthreads();
  }
  #pragma unroll
  for (int r = 0; r < 4; ++r)
    GS[w][(l>>4)*4 + r][l & 15] = acc[r];
  #pragma unroll
  for (int m = 1; m < 64; m <<= 1){
    #pragma unroll
    for (int r = 0; r < 16; ++r) sh[r] += __shfl_xor(sh[r], m);
  }
  if (l == 0){
    #pragma unroll
    for (int r = 0; r < 16; ++r) SHs[w][r] = sh[r];
  }
  __syncthreads();
  {
    int i = t >> 4, j = t & 15;
    float g = GS[0][i][j] + GS[1][i][j] + GS[2][i][j] + GS[3][i][j];
    PB[(size_t)blockIdx.x*272 + t] = g;
    if (t < 16)
      PB[(size_t)blockIdx.x*272 + 256 + t] = SHs[0][t]+SHs[1][t]+SHs[2][t]+SHs[3][t];
  }
}

// ---------------- k_statG2: h1 Gram (MFMA h1 via w1Bg + MFMA Gram) ----------------
__global__ __launch_bounds__(256) void k_statG2(const float* lc, const float* F,
                                                const u16* w1Bg, float* PB){
  __shared__ f32x4 w0p[16];
  __shared__ __align__(16) u16 Ht0[4][64*40];
  __shared__ __align__(16) u16 Ht1[4][16*72];
  __shared__ float GS[4][16][17];
  __shared__ float SHs[4][16];
  int t = threadIdx.x;
  int w = t >> 6, l = t & 63;
  if (t < 16){
    f32x4 wv = {F[t*3], F[t*3+1], F[t*3+2], F[48+t]};
    w0p[t] = wv;
  }
  s16x8 w1B = *(const s16x8*)&w1Bg[l*8];
  float b1f = F[320 + (l & 15)];
  u16* H0w = &Ht0[w][0];
  u16* H1w = &Ht1[w][0];
  {
    u16x8 z8 = {0,0,0,0,0,0,0,0};
    *(u16x8*)&H0w[l*40 + 16] = z8;
    *(u16x8*)&H0w[l*40 + 24] = z8;
  }
  __syncthreads();
  f32x4 acc = {0.f,0.f,0.f,0.f};
  float shloc = 0.f;
  for (int it = 0; it < SGIT; ++it){
    size_t p = (size_t)blockIdx.x * (SGIT*256) + (size_t)it*256 + w*64 + l;
    float x0 = lc[p*3], x1 = lc[p*3+1], x2 = lc[p*3+2];
    u16x8 p0, p1;
    #pragma unroll
    for (int oc = 0; oc < 8; ++oc){
      f32x4 wv = w0p[oc];
      p0[oc] = f2b(fmaxf(0.f, wv.x*x0 + wv.y*x1 + wv.z*x2 + wv.w));
    }
    #pragma unroll
    for (int oc = 0; oc < 8; ++oc){
      f32x4 wv = w0p[8+oc];
      p1[oc] = f2b(fmaxf(0.f, wv.x*x0 + wv.y*x1 + wv.z*x2 + wv.w));
    }
    *(u16x8*)&H0w[l*40]     = p0;
    *(u16x8*)&H0w[l*40 + 8] = p1;
    __syncthreads();
    #pragma unroll
    for (int mt = 0; mt < 4; ++mt){
      s16x8 af = *(const s16x8*)&H0w[(mt*16 + (l & 15))*40 + (l >> 4)*8];
      f32x4 c = {b1f, b1f, b1f, b1f};
      c = __builtin_amdgcn_mfma_f32_16x16x32_bf16(af, w1B, c, 0, 0, 0);
      #pragma unroll
      for (int r = 0; r < 4; ++r){
        float v = fmaxf(0.f, c[r]);
        shloc += v;
        H1w[(l & 15)*72 + mt*16 + (l >> 4)*4 + r] = f2b(v);
      }
    }
    __syncthreads();
    #pragma unroll
    for (int tt = 0; tt < 2; ++tt){
      s16x8 afg = *(const s16x8*)&H1w[(l & 15)*72 + tt*32 + (l >> 4)*8];
      acc = __builtin_amdgcn_mfma_f32_16x16x32_bf16(afg, afg, acc, 0, 0, 0);
    }
    __syncthreads();
  }
  #pragma unroll
  for (int r = 0; r < 4; ++r)
    GS[w][(l>>4)*4 + r][l & 15] = acc[r];
  shloc += __shfl_xor(shloc, 16);
  shloc += __shfl_xor(shloc, 32);
  if (l < 16) SHs[w][l] = shloc;
  __syncthreads();
  {
    int i = t >> 4, j = t & 15;
    float g = GS[0][i][j] + GS[1][i][j] + GS[2][i][j] + GS[3][i][j];
    PB[(size_t)blockIdx.x*272 + t] = g;
    if (t < 16)
      PB[(size_t)blockIdx.x*272 + 256 + t] = SHs[0][t]+SHs[1][t]+SHs[2][t]+SHs[3][t];
  }
}

// ---------------- k_red1 ----------------
__global__ __launch_bounds__(256) void k_red1(const float* PB, const float* w1, const float* b1,
                                              const float* g1, const float* be1, float* F,
                                              u16* w1Bg){
  __shared__ float red[272];
  __shared__ float a1sh[16];
  int t = threadIdx.x;
  for (int e = t; e < 272; e += 256){
    float s = 0.f;
    for (int r = 0; r < SGBLK; ++r) s += PB[(size_t)r*272 + e];
    red[e] = s;
  }
  __syncthreads();
  if (t < 16){
    float wv[16];
    #pragma unroll
    for (int ic = 0; ic < 16; ++ic) wv[ic] = w1[t*16+ic];
    float lin = 0.f;
    #pragma unroll
    for (int ic = 0; ic < 16; ++ic) lin += wv[ic]*red[256+ic];
    float quad = 0.f;
    for (int i = 0; i < 16; ++i){
      float ri = 0.f;
      #pragma unroll
      for (int j = 0; j < 16; ++j) ri += wv[j]*red[i*16+j];
      quad += wv[i]*ri;
    }
    float bb = b1[t];
    float S = lin + (float)NWN * bb;
    float Q = quad + 2.f*bb*lin + (float)NWN*bb*bb;
    float m = S * (1.f/NWN);
    float v = Q * (1.f/NWN) - m*m;
    float a = g1[t] * rsqrtf(v + EPSF);
    float d = be1[t] - m*a;
    a1sh[t] = a;
    F[320+t] = a*bb + d;
  }
  __syncthreads();
  F[64 + t] = a1sh[t >> 4] * w1[t];
  if (t < 64){
    int oc = t & 15, icb = (t >> 4) * 8;
    u16x8 fr;
    #pragma unroll
    for (int j = 0; j < 8; ++j){
      int ic = icb + j;
      fr[j] = (ic < 16) ? f2b(a1sh[oc] * w1[oc*16 + ic]) : (u16)0;
    }
    *(u16x8*)&w1Bg[t*8] = fr;
  }
}

// ---------------- k_red2 ----------------
__global__ __launch_bounds__(256) void k_red2(const float* PB, const float* w2, const float* b2,
                                              const float* g2, const float* be2, float* F,
                                              u16* w2Bg){
  __shared__ float red[272];
  __shared__ float a2sh[64];
  int t = threadIdx.x;
  for (int e = t; e < 272; e += 256){
    float s = 0.f;
    for (int r = 0; r < SGBLK; ++r) s += PB[(size_t)r*272 + e];
    red[e] = s;
  }
  __syncthreads();
  if (t < 64){
    float wv[16];
    #pragma unroll
    for (int ic = 0; ic < 16; ++ic) wv[ic] = w2[t*16+ic];
    float lin = 0.f;
    #pragma unroll
    for (int ic = 0; ic < 16; ++ic) lin += wv[ic]*red[256+ic];
    float quad = 0.f;
    for (int i = 0; i < 16; ++i){
      float ri = 0.f;
      #pragma unroll
      for (int j = 0; j < 16; ++j) ri += wv[j]*red[i*16+j];
      quad += wv[i]*ri;
    }
    float bb = b2[t];
    float S = lin + (float)NWN * bb;
    float Q = quad + 2.f*bb*lin + (float)NWN*bb*bb;
    float m = S * (1.f/NWN);
    float v = Q * (1.f/NWN) - m*m;
    float a = g2[t] * rsqrtf(v + EPSF);
    float d = be2[t] - m*a;
    a2sh[t] = a;
    F[1360+t] = a*bb + d;
  }
  __syncthreads();
  for (int i = t; i < 1024; i += 256) F[336+i] = a2sh[i >> 4] * w2[i];
  {
    int ot = t >> 6, lane = t & 63;
    int oc = ot*16 + (lane & 15), icb = ((lane >> 4)) * 8;
    u16x8 fr;
    #pragma unroll
    for (int j = 0; j < 8; ++j){
      int ic = icb + j;
      fr[j] = (ic < 16) ? f2b(a2sh[oc] * w2[oc*16 + ic]) : (u16)0;
    }
    *(u16x8*)&w2Bg[t*8] = fr;
  }
}

// ---------------- K5: TWO points per block — MFMA WeightNet + MFMA matmul, 3 barriers ----------------
__global__ __launch_bounds__(256) void k_main(const float* lcg, const int* nbrg,
    const u16* ptsw, const float* F,
    const u16* w1Bg, const u16* w2Bg,
    u16* npw){
  __shared__ __align__(16) u16 Gr[2][64*40];        // swizzled K-major per point
  __shared__ __align__(16) u16 WrBuf[2][64*40];     // W output; [0..1279] doubles as H0bf
  __shared__ __align__(16) u16 H1bf[2][32*40];
  int t = threadIdx.x;
  int w = t >> 6, l = t & 63;
  int p0 = blockIdx.x * 2;
  s16x8 w1B  = *(const s16x8*)&w1Bg[l*8];
  s16x8 w2B0 = *(const s16x8*)&w2Bg[(0*64 + l)*8];
  s16x8 w2B1 = *(const s16x8*)&w2Bg[(1*64 + l)*8];
  s16x8 w2B2 = *(const s16x8*)&w2Bg[(2*64 + l)*8];
  s16x8 w2B3 = *(const s16x8*)&w2Bg[(3*64 + l)*8];
  float b1f  = F[320 + (l & 15)];
  float b2f0 = F[1360 +  0 + (l & 15)];
  float b2f1 = F[1360 + 16 + (l & 15)];
  float b2f2 = F[1360 + 32 + (l & 15)];
  float b2f3 = F[1360 + 48 + (l & 15)];
  int oc0 = (t & 7) * 2;
  f32x4 w0a = {F[oc0*3], F[oc0*3+1], F[oc0*3+2], F[48+oc0]};
  f32x4 w0b = {F[oc0*3+3], F[oc0*3+4], F[oc0*3+5], F[48+oc0+1]};
  {
    int k = t >> 3, c = 16 + (t & 7)*2;
    *(unsigned int*)&WrBuf[0][k*40 + c] = 0u;
    *(unsigned int*)&WrBuf[1][k*40 + c] = 0u;
    *(unsigned int*)&H1bf[0][k*40 + c] = 0u;
    *(unsigned int*)&H1bf[1][k*40 + c] = 0u;
  }
  {
    int kg = w*8 + (l >> 3), c8 = l & 7;
    int kphys = ((w ^ (c8 & 3)) << 3) + (l >> 3);
    #pragma unroll
    for (int pt = 0; pt < 2; ++pt){
      int point = p0 + pt;
      int bbp = point >> 10;
      int n = nbrg[(size_t)point*32 + kg];
      u16x8 g = *(const u16x8*)(ptsw + (size_t)(bbp * NN + n)*64 + c8*8);
      #pragma unroll
      for (int j = 0; j < 8; ++j)
        Gr[pt][(c8*8 + j)*40 + kphys] = g[j];
    }
  }
  {
    int k = t >> 3;
    #pragma unroll
    for (int pt = 0; pt < 2; ++pt){
      const float* xp = lcg + (size_t)(p0 + pt)*96 + k*3;
      float x0 = xp[0], x1 = xp[1], x2 = xp[2];
      WrBuf[pt][k*40 + oc0]     = f2b(fmaxf(0.f, w0a.x*x0 + w0a.y*x1 + w0a.z*x2 + w0a.w));
      WrBuf[pt][k*40 + oc0 + 1] = f2b(fmaxf(0.f, w0b.x*x0 + w0b.y*x1 + w0b.z*x2 + w0b.w));
    }
  }
  __syncthreads();   // (1) H0(=WrBuf low) + pads ready
  {
    int pt = w >> 1, kt = w & 1;
    s16x8 af = *(const s16x8*)&WrBuf[pt][(kt*16 + (l & 15))*40 + (l >> 4)*8];
    f32x4 acc = {b1f, b1f, b1f, b1f};
    acc = __builtin_amdgcn_mfma_f32_16x16x32_bf16(af, w1B, acc, 0, 0, 0);
    #pragma unroll
    for (int r = 0; r < 4; ++r)
      H1bf[pt][(kt*16 + (l >> 4)*4 + r)*40 + (l & 15)] = f2b(fmaxf(0.f, acc[r]));
  }
  __syncthreads();   // (2) H1bf ready; H0 region dead -> Wr may overwrite
  {
    int pt = w & 1, kt = w >> 1;
    s16x8 af = *(const s16x8*)&H1bf[pt][(kt*16 + (l & 15))*40 + (l >> 4)*8];
    int kbase = kt*16 + (l >> 4)*4;
    f32x4 a0c = {b2f0,b2f0,b2f0,b2f0};
    a0c = __builtin_amdgcn_mfma_f32_16x16x32_bf16(af, w2B0, a0c, 0, 0, 0);
    u16x4 s0v; s0v[0]=f2b(fmaxf(0.f,a0c[0])); s0v[1]=f2b(fmaxf(0.f,a0c[1]));
    s0v[2]=f2b(fmaxf(0.f,a0c[2])); s0v[3]=f2b(fmaxf(0.f,a0c[3]));
    *(u16x4*)&WrBuf[pt][( 0 + (l & 15))*40 + kbase] = s0v;
    f32x4 a1c = {b2f1,b2f1,b2f1,b2f1};
    a1c = __builtin_amdgcn_mfma_f32_16x16x32_bf16(af, w2B1, a1c, 0, 0, 0);
    u16x4 s1v; s1v[0]=f2b(fmaxf(0.f,a1c[0])); s1v[1]=f2b(fmaxf(0.f,a1c[1]));
    s1v[2]=f2b(fmaxf(0.f,a1c[2])); s1v[3]=f2b(fmaxf(0.f,a1c[3]));
    *(u16x4*)&WrBuf[pt][(16 + (l & 15))*40 + kbase] = s1v;
    f32x4 a2c = {b2f2,b2f2,b2f2,b2f2};
    a2c = __builtin_amdgcn_mfma_f32_16x16x32_bf16(af, w2B2, a2c, 0, 0, 0);
    u16x4 s2v; s2v[0]=f2b(fmaxf(0.f,a2c[0])); s2v[1]=f2b(fmaxf(0.f,a2c[1]));
    s2v[2]=f2b(fmaxf(0.f,a2c[2])); s2v[3]=f2b(fmaxf(0.f,a2c[3]));
    *(u16x4*)&WrBuf[pt][(32 + (l & 15))*40 + kbase] = s2v;
    f32x4 a3c = {b2f3,b2f3,b2f3,b2f3};
    a3c = __builtin_amdgcn_mfma_f32_16x16x32_bf16(af, w2B3, a3c, 0, 0, 0);
    u16x4 s3v; s3v[0]=f2b(fmaxf(0.f,a3c[0])); s3v[1]=f2b(fmaxf(0.f,a3c[1]));
    s3v[2]=f2b(fmaxf(0.f,a3c[2])); s3v[3]=f2b(fmaxf(0.f,a3c[3]));
    *(u16x4*)&WrBuf[pt][(48 + (l & 15))*40 + kbase] = s3v;
  }
  __syncthreads();   // (3) Gr, Wr ready
  {
    int li = l & 15, lkb = l >> 4, lr = (l >> 4) * 4;
    #pragma unroll
    for (int pt = 0; pt < 2; ++pt){
      s16x8 bfrag = *(const s16x8*)&WrBuf[pt][(w*16 + li)*40 + lkb*8];
      size_t obase = (size_t)(p0 + pt)*4096 + (size_t)(w*16 + li)*64 + lr;
      #pragma unroll
      for (int it = 0; it < 4; ++it){
        int ch = it*16 + li;
        int key = (ch >> 3) & 3;
        s16x8 afrag = *(const s16x8*)&Gr[pt][ch*40 + ((lkb ^ key) << 3)];
        f32x4 z = {0.f, 0.f, 0.f, 0.f};
        f32x4 d = __builtin_amdgcn_mfma_f32_16x16x32_bf16(afrag, bfrag, z, 0, 0, 0);
        u16x4 st;
        st[0] = f2b(d[0]); st[1] = f2b(d[1]); st[2] = f2b(d[2]); st[3] = f2b(d[3]);
        *(u16x4*)(npw + obase + it*16) = st;
      }
    }
  }
}

// ---------------- k_statC ----------------
__global__ __launch_bounds__(256) void k_statC(const u16* npw, float* PC){
  int t = threadIdx.x;
  float s[16], q[16];
  #pragma unroll
  for (int j = 0; j < 16; ++j){ s[j] = 0.f; q[j] = 0.f; }
  size_t rowbase = (size_t)blockIdx.x * 64;
  for (int p = 0; p < 64; ++p){
    const u16* row = npw + (rowbase + p) * 4096 + t * 16;
    u16x8 a = *(const u16x8*)row;
    u16x8 b = *(const u16x8*)(row + 8);
    #pragma unroll
    for (int j = 0; j < 8; ++j){ float v = bf(a[j]); s[j]   += v; q[j]   += v*v; }
    #pragma unroll
    for (int j = 0; j < 8; ++j){ float v = bf(b[j]); s[8+j] += v; q[8+j] += v*v; }
  }
  float* dst = PC + (size_t)blockIdx.x * 8192 + t * 16;
  #pragma unroll
  for (int j = 0; j < 16; ++j){ dst[j] = s[j]; dst[4096 + j] = q[j]; }
}

// ---------------- k_finC (position space; gc/bc permuted) ----------------
__global__ __launch_bounds__(256) void k_finC(const float* PC, const float* gc, const float* bc,
                                              float* AC, float* DC){
  int qpos = blockIdx.x * 256 + threadIdx.x;
  float s = 0.f, q = 0.f;
  for (int r = 0; r < 256; ++r){
    s += PC[(size_t)r * 8192 + qpos];
    q += PC[(size_t)r * 8192 + 4096 + qpos];
  }
  int ch = (qpos & 63)*64 + (qpos >> 6);
  float m = s * (1.f/16384.f);
  float v = q * (1.f/16384.f) - m*m;
  float a = gc[ch] * rsqrtf(v + EPSF);
  AC[qpos] = a; DC[qpos] = bc[ch] - m*a;
}

// ---------------- k_linear: 16 rows/block, grid 1024, register-prefetch pipeline ----------------
__global__ __launch_bounds__(256) void k_linear(const u16* npw, const float* AC, const float* DC,
                                                const u16* lwbt, const float* lb, float* yw,
                                                float* PL){
  __shared__ u16 Al[16*72];
  __shared__ u16 Bl[64*72];
  __shared__ float cps[64], cpq[64];
  int t = threadIdx.x;
  int w = t >> 6, l = t & 63;
  int rowbase = blockIdx.x * 16;
  int rA = t >> 4, cA = t & 15;      // A-stage coords (16 rows x 16 col-groups x4)
  int nB = t >> 3, cB = t & 7;       // B-stage coords (rows nB, nB+32)
  const u16* Aptr = npw + (size_t)(rowbase + rA)*4096 + cA*4;
  const u16* B0ptr = lwbt + (size_t)nB*4096 + cB*8;
  const u16* B1ptr = lwbt + (size_t)(nB + 32)*4096 + cB*8;
  f32x4 acc0 = {0.f,0.f,0.f,0.f};
  // prefetch kb = 0
  u16x4 uA  = *(const u16x4*)(Aptr);
  u16x8 uB0 = *(const u16x8*)(B0ptr);
  u16x8 uB1 = *(const u16x8*)(B1ptr);
  for (int kb = 0; kb < 4096; kb += 64){
    __syncthreads();   // previous MFMA reads complete
    // write staged regs -> LDS (bn+relu fused on A)
    {
      int kk = kb + cA*4;
      f32x4 av = *(const f32x4*)(AC + kk);
      f32x4 dv = *(const f32x4*)(DC + kk);
      u16x4 o;
      o[0] = f2b(fmaxf(0.f, av.x*bf(uA[0]) + dv.x));
      o[1] = f2b(fmaxf(0.f, av.y*bf(uA[1]) + dv.y));
      o[2] = f2b(fmaxf(0.f, av.z*bf(uA[2]) + dv.z));
      o[3] = f2b(fmaxf(0.f, av.w*bf(uA[3]) + dv.w));
      *(u16x4*)&Al[rA*72 + cA*4] = o;
      *(u16x8*)&Bl[nB*72 + cB*8]        = uB0;
      *(u16x8*)&Bl[(nB + 32)*72 + cB*8] = uB1;
    }
    // prefetch next K-step (latency overlaps MFMA + barriers)
    if (kb + 64 < 4096){
      uA  = *(const u16x4*)(Aptr + kb + 64);
      uB0 = *(const u16x8*)(B0ptr + kb + 64);
      uB1 = *(const u16x8*)(B1ptr + kb + 64);
    }
    __syncthreads();   // LDS writes visible
    #pragma unroll
    for (int ks = 0; ks < 2; ++ks){
      s16x8 af  = *(const s16x8*)&Al[((l & 15))*72 + ks*32 + (l >> 4)*8];
      s16x8 bf0 = *(const s16x8*)&Bl[(w*16 + (l & 15))*72 + ks*32 + (l >> 4)*8];
      acc0 = __builtin_amdgcn_mfma_f32_16x16x32_bf16(af, bf0, acc0, 0, 0, 0);
    }
  }
  int col0 = w*16 + (l & 15);
  float lb0 = lb[col0];
  float s0 = 0.f, q0 = 0.f;
  if (t < 64){ cps[t] = 0.f; cpq[t] = 0.f; }
  __syncthreads();
  #pragma unroll
  for (int r = 0; r < 4; ++r){
    int row = rowbase + (l >> 4)*4 + r;
    float y0 = acc0[r] + lb0;
    yw[(size_t)row*64 + col0] = y0;
    s0 += y0; q0 += y0*y0;
  }
  atomicAdd(&cps[col0], s0); atomicAdd(&cpq[col0], q0);
  __syncthreads();
  if (t < 64){
    PL[blockIdx.x*128 + t]      = cps[t];
    PL[blockIdx.x*128 + 64 + t] = cpq[t];
  }
}

// ---------------- k_redF (1024 blocks of PL) ----------------
__global__ __launch_bounds__(128) void k_redF(const float* PL, float* SL){
  int t = threadIdx.x;
  float s = 0.f;
  for (int b = 0; b < 1024; ++b) s += PL[b*128 + t];
  SL[t] = s;
}

// ---------------- k_final ----------------
__global__ __launch_bounds__(256) void k_final(const float* yw, const float* SL,
                                               const float* gl, const float* bl, float* out){
  int e = (blockIdx.x * 256 + threadIdx.x) * 4;
  int o = e & 63;
  f32x4 y = *(const f32x4*)(yw + e);
  f32x4 r;
  #pragma unroll
  for (int j = 0; j < 4; ++j){
    float m = SL[o+j] * (1.f/16384.f);
    float v = SL[64+o+j] * (1.f/16384.f) - m*m;
    float a = gl[o+j] * rsqrtf(v + EPSF);
    float d = bl[o+j] - m*a;
    r[j] = fmaxf(0.f, a*y[j] + d);
  }
  *(f32x4*)(out + 49152 + e) = r;
}

extern "C" void kernel_launch(void* const* d_in, const int* in_sizes, int n_in,
                              void* d_out, int out_size, void* d_ws, size_t ws_size,
                              hipStream_t stream){
  (void)in_sizes; (void)n_in; (void)out_size; (void)ws_size;
  const float* xyz    = (const float*)d_in[0];
  const float* points = (const float*)d_in[1];
  const float* lc     = (const float*)d_in[2];
  const int*   nbrl   = (const int*)d_in[3];
  const int*   didx   = (const int*)d_in[4];
  const float* w0 = (const float*)d_in[5];
  const float* b0 = (const float*)d_in[6];
  const float* g0 = (const float*)d_in[7];
  const float* be0= (const float*)d_in[8];
  const float* w1 = (const float*)d_in[9];
  const float* b1 = (const float*)d_in[10];
  const float* g1 = (const float*)d_in[11];
  const float* be1= (const float*)d_in[12];
  const float* w2 = (const float*)d_in[13];
  const float* b2 = (const float*)d_in[14];
  const float* g2 = (const float*)d_in[15];
  const float* be2= (const float*)d_in[16];
  const float* gc = (const float*)d_in[17];
  const float* bc = (const float*)d_in[18];
  const float* lw = (const float*)d_in[19];
  const float* lb = (const float*)d_in[20];
  const float* gl = (const float*)d_in[21];
  const float* bl = (const float*)d_in[22];
  float* out = (float*)d_out;
  char* ws = (char*)d_ws;

  float* F   = (float*)ws;           // 1536
  float* SL  = F + 1536;             // 128
  float* AC  = SL + 128;             // 4096
  float* DC  = AC + 4096;            // 4096
  float* PA  = DC + 4096;            // 32768
  float* PB1 = PA + 32768;           // 139264
  float* PB2 = PB1 + 139264;         // 139264
  float* PL  = PB2 + 139264;         // 131072 (1024 blocks x 128)
  u16*  w1Bg = (u16*)(PL + 131072);  // 512 u16
  u16*  w2Bg = w1Bg + 512;           // 2048 u16
  float* PC  = (float*)(ws + 4194304);                        // 8 MB
  u16*  npw  = (u16*)(ws + 4194304 + 8388608);                // 128 MB bf16 (transposed)
  float* yw  = (float*)(ws + 4194304 + 8388608 + 134217728);  // 4 MB f32
  u16*  lwbt = (u16*)(ws + 4194304 + 8388608 + 134217728 + 4194304); // 512 KB (permuted)
  u16*  ptsw = (u16*)(ws + 4194304 + 8388608 + 134217728 + 4194304 + 1048576); // 8 MB bf16

  k_init  <<<640,   256, 0, stream>>>(xyz, didx, out, lw, lwbt, points, ptsw);
  k_stat0 <<<512,   256, 0, stream>>>(lc, PA);
  k_red0  <<<1,     256, 0, stream>>>(PA, w0, b0, g0, be0, F);
  k_statG1<<<SGBLK, 256, 0, stream>>>(lc, F, PB1);
  k_red1  <<<1,     256, 0, stream>>>(PB1, w1, b1, g1, be1, F, w1Bg);
  k_statG2<<<SGBLK, 256, 0, stream>>>(lc, F, w1Bg, PB2);
  k_red2  <<<1,     256, 0, stream>>>(PB2, w2, b2, g2, be2, F, w2Bg);
  k_main  <<<8192,  256, 0, stream>>>(lc, nbrl, ptsw, F, w1Bg, w2Bg, npw);
  k_statC <<<256,   256, 0, stream>>>(npw, PC);
  k_finC  <<<16,    256, 0, stream>>>(PC, gc, bc, AC, DC);
  k_linear<<<1024,  256, 0, stream>>>(npw, AC, DC, lwbt, lb, yw, PL);
  k_redF  <<<1,     128, 0, stream>>>(PL, SL);
  k_final <<<1024,  256, 0, stream>>>(yw, SL, gl, bl, out);
}

// Round 22
// 257.855 us; speedup vs baseline: 1.0270x; 1.0047x over previous
//
#include <hip/hip_runtime.h>
#include <hip/hip_bf16.h>

#define BB 16
#define NN 4096
#define NPOINTS 1024
#define KK 32
#define NPTS (BB*NPOINTS)        // 16384
#define NWN  (BB*NPOINTS*KK)     // 524288
#define EPSF 1e-5f
#define SGBLK 512
#define SGIT  4

typedef unsigned short u16;
typedef u16  u16x8 __attribute__((ext_vector_type(8)));
typedef u16  u16x4 __attribute__((ext_vector_type(4)));
typedef short s16x8 __attribute__((ext_vector_type(8)));
typedef float f32x4 __attribute__((ext_vector_type(4)));
typedef float f32x4u __attribute__((ext_vector_type(4), aligned(4)));

__device__ __forceinline__ float bf(u16 u){
  union { unsigned int i; float f; } v; v.i = ((unsigned int)u) << 16; return v.f;
}
__device__ __forceinline__ u16 f2b(float f){
  __hip_bfloat16 h = __float2bfloat16(f);
  union { __hip_bfloat16 hh; u16 u; } v; v.hh = h; return v.u;
}

// F layout (folded weights): [0..47] w0f, [48..63] b0f, [64..319] w1f,
// [320..335] b1f, [336..1359] w2f, [1360..1423] b2f
// npw: transposed position space q = o*64 + i  (original channel ch = i*64 + o)
// ptsw[B*N][64] bf16: pre-converted concat(points, xyz) rows
// Gr LDS: K-major, 16B k-blocks XOR-swizzled by (ch>>3)&3
// k_main: H0bf aliases WrBuf[pt][0..1279] — dead after barrier(2), Wr written after it.
// k_linear: double-buffered LDS, 1 barrier/K-step (round 22).
// NOTE (round 15): device atomics bypass L2 on MI355X -> keep stats streaming.

// ---------------- k_init: newxyz (0..63) + lwbt (64..127) + ptsw (128..639) + lc moments (640..1151) ----------------
__global__ __launch_bounds__(256) void k_init(const float* xyz, const int* didx, float* out,
                                              const float* lw, u16* lwbt,
                                              const float* points, u16* ptsw,
                                              const float* lc, float* PA){
  int t = threadIdx.x;
  if (blockIdx.x < 64){
    int p = blockIdx.x * 256 + t;
    int b = p >> 10;
    int idx = didx[p];
    const float* src = xyz + ((size_t)(b * NN + idx)) * 3;
    float* dst = out + (size_t)p * 3;
    dst[0] = src[0]; dst[1] = src[1]; dst[2] = src[2];
  } else if (blockIdx.x < 128){
    __shared__ float T[64][65];
    int ib = blockIdx.x - 64;
    int kb = ib * 64;
    {
      int k = t >> 2, c4 = t & 3;
      #pragma unroll
      for (int j = 0; j < 4; ++j)
        *(f32x4*)&T[k][c4*16 + j*4] = *(const f32x4*)(lw + (size_t)(kb + k)*64 + c4*16 + j*4);
    }
    __syncthreads();
    {
      int n = t >> 2, k4 = t & 3;
      #pragma unroll
      for (int j = 0; j < 16; ++j){
        int k = k4*16 + j;
        lwbt[(size_t)n*4096 + k*64 + ib] = f2b(T[k][n]);
      }
    }
  } else if (blockIdx.x < 640){
    int gid0 = (blockIdx.x - 128) * 256 + t;
    #pragma unroll
    for (int rep = 0; rep < 4; ++rep){
      int idx = gid0 + rep * 131072;
      int row = idx >> 3, c8 = idx & 7;
      const float* prow = points + (size_t)row * 61;
      u16x8 g;
      if (c8 < 7){
        f32x4 lo = *(const f32x4u*)(prow + c8*8);
        f32x4 hi = *(const f32x4u*)(prow + c8*8 + 4);
        g[0]=f2b(lo.x); g[1]=f2b(lo.y); g[2]=f2b(lo.z); g[3]=f2b(lo.w);
        g[4]=f2b(hi.x); g[5]=f2b(hi.y); g[6]=f2b(hi.z); g[7]=f2b(hi.w);
      } else {
        const float* xr = xyz + (size_t)row * 3;
        f32x4 lo = *(const f32x4u*)(prow + 56);
        g[0]=f2b(lo.x); g[1]=f2b(lo.y); g[2]=f2b(lo.z); g[3]=f2b(lo.w);
        g[4]=f2b(prow[60]);
        g[5]=f2b(xr[0]); g[6]=f2b(xr[1]); g[7]=f2b(xr[2]);
      }
      *(u16x8*)(ptsw + (size_t)row*64 + c8*8) = g;
    }
  } else {
    // raw-lc moments (3-dim Gram), merged from old k_stat0
    int bid = blockIdx.x - 640;
    float a[9];
    #pragma unroll
    for (int r = 0; r < 9; ++r) a[r] = 0.f;
    size_t base = (size_t)bid * 1024 + t;
    for (int ip = 0; ip < 4; ++ip){
      size_t p = base + (size_t)ip * 256;
      float x0 = lc[p*3], x1 = lc[p*3+1], x2 = lc[p*3+2];
      a[0]+=x0; a[1]+=x1; a[2]+=x2;
      a[3]+=x0*x0; a[4]+=x0*x1; a[5]+=x0*x2;
      a[6]+=x1*x1; a[7]+=x1*x2; a[8]+=x2*x2;
    }
    #pragma unroll
    for (int m = 1; m < 64; m <<= 1){
      #pragma unroll
      for (int r = 0; r < 9; ++r) a[r] += __shfl_xor(a[r], m);
    }
    if ((t & 63) == 0){
      float* dst = PA + (size_t)(bid*4 + (t>>6)) * 16;
      f32x4 v0 = {a[0],a[1],a[2],a[3]}, v1 = {a[4],a[5],a[6],a[7]}, v2 = {a[8],0.f,0.f,0.f};
      *(f32x4*)dst = v0; *(f32x4*)(dst+4) = v1; *(f32x4*)(dst+8) = v2;
    }
  }
}

// ---------------- k_red0 ----------------
__global__ __launch_bounds__(256) void k_red0(const float* PA, const float* w0, const float* b0,
                                              const float* g0, const float* be0, float* F){
  __shared__ float ms[12];
  __shared__ float a0sh[16];
  int t = threadIdx.x;
  if (t < 12){
    float s0=0,s1=0,s2=0,s3=0;
    const float* p = PA + t;
    for (int r = 0; r < 2048; r += 4){
      s0 += p[(size_t)(r+0)*16]; s1 += p[(size_t)(r+1)*16];
      s2 += p[(size_t)(r+2)*16]; s3 += p[(size_t)(r+3)*16];
    }
    ms[t] = (s0+s1)+(s2+s3);
  }
  __syncthreads();
  if (t < 16){
    float wx = w0[t*3], wy = w0[t*3+1], wz = w0[t*3+2], bb = b0[t];
    float lin = wx*ms[0] + wy*ms[1] + wz*ms[2];
    float quad = wx*wx*ms[3] + wy*wy*ms[6] + wz*wz*ms[8]
               + 2.f*(wx*wy*ms[4] + wx*wz*ms[5] + wy*wz*ms[7]);
    float S = lin + (float)NWN * bb;
    float Q = quad + 2.f*bb*lin + (float)NWN*bb*bb;
    float m = S * (1.f/NWN);
    float v = Q * (1.f/NWN) - m*m;
    float a = g0[t] * rsqrtf(v + EPSF);
    float d = be0[t] - m*a;
    a0sh[t] = a;
    F[48+t] = a*bb + d;
  }
  __syncthreads();
  if (t < 48) F[t] = a0sh[t/3] * w0[t];
}

// ---------------- k_statG1: h0 Gram (VALU h0, MFMA Gram) ----------------
__global__ __launch_bounds__(256) void k_statG1(const float* lc, const float* F, float* PB){
  __shared__ f32x4 w0p[16];
  __shared__ __align__(16) u16 Ht[4][16*72];
  __shared__ float GS[4][16][17];
  __shared__ float SHs[4][16];
  int t = threadIdx.x;
  int w = t >> 6, l = t & 63;
  if (t < 16){
    f32x4 wv = {F[t*3], F[t*3+1], F[t*3+2], F[48+t]};
    w0p[t] = wv;
  }
  __syncthreads();
  f32x4 acc = {0.f,0.f,0.f,0.f};
  float sh[16];
  #pragma unroll
  for (int r = 0; r < 16; ++r) sh[r] = 0.f;
  u16* Hw = &Ht[w][0];
  for (int it = 0; it < SGIT; ++it){
    size_t p = (size_t)blockIdx.x * (SGIT*256) + (size_t)it*256 + w*64 + l;
    float x0 = lc[p*3], x1 = lc[p*3+1], x2 = lc[p*3+2];
    float h[16];
    #pragma unroll
    for (int oc = 0; oc < 16; ++oc){
      f32x4 wv = w0p[oc];
      h[oc] = fmaxf(0.f, wv.x*x0 + wv.y*x1 + wv.z*x2 + wv.w);
      sh[oc] += h[oc];
    }
    #pragma unroll
    for (int c = 0; c < 16; ++c) Hw[c*72 + l] = f2b(h[c]);
    __syncthreads();
    #pragma unroll
    for (int tt = 0; tt < 2; ++tt){
      s16x8 af = *(const s16x8*)&Hw[(l & 15)*72 + tt*32 + (l >> 4)*8];
      acc = __builtin_amdgcn_mfma_f32_16x16x32_bf16(af, af, acc, 0, 0, 0);
    }
    __syncthreads();
  }
  #pragma unroll
  for (int r = 0; r < 4; ++r)
    GS[w][(l>>4)*4 + r][l & 15] = acc[r];
  #pragma unroll
  for (int m = 1; m < 64; m <<= 1){
    #pragma unroll
    for (int r = 0; r < 16; ++r) sh[r] += __shfl_xor(sh[r], m);
  }
  if (l == 0){
    #pragma unroll
    for (int r = 0; r < 16; ++r) SHs[w][r] = sh[r];
  }
  __syncthreads();
  {
    int i = t >> 4, j = t & 15;
    float g = GS[0][i][j] + GS[1][i][j] + GS[2][i][j] + GS[3][i][j];
    PB[(size_t)blockIdx.x*272 + t] = g;
    if (t < 16)
      PB[(size_t)blockIdx.x*272 + 256 + t] = SHs[0][t]+SHs[1][t]+SHs[2][t]+SHs[3][t];
  }
}

// ---------------- k_statG2: h1 Gram (MFMA h1 via w1Bg + MFMA Gram) ----------------
__global__ __launch_bounds__(256) void k_statG2(const float* lc, const float* F,
                                                const u16* w1Bg, float* PB){
  __shared__ f32x4 w0p[16];
  __shared__ __align__(16) u16 Ht0[4][64*40];
  __shared__ __align__(16) u16 Ht1[4][16*72];
  __shared__ float GS[4][16][17];
  __shared__ float SHs[4][16];
  int t = threadIdx.x;
  int w = t >> 6, l = t & 63;
  if (t < 16){
    f32x4 wv = {F[t*3], F[t*3+1], F[t*3+2], F[48+t]};
    w0p[t] = wv;
  }
  s16x8 w1B = *(const s16x8*)&w1Bg[l*8];
  float b1f = F[320 + (l & 15)];
  u16* H0w = &Ht0[w][0];
  u16* H1w = &Ht1[w][0];
  {
    u16x8 z8 = {0,0,0,0,0,0,0,0};
    *(u16x8*)&H0w[l*40 + 16] = z8;
    *(u16x8*)&H0w[l*40 + 24] = z8;
  }
  __syncthreads();
  f32x4 acc = {0.f,0.f,0.f,0.f};
  float shloc = 0.f;
  for (int it = 0; it < SGIT; ++it){
    size_t p = (size_t)blockIdx.x * (SGIT*256) + (size_t)it*256 + w*64 + l;
    float x0 = lc[p*3], x1 = lc[p*3+1], x2 = lc[p*3+2];
    u16x8 p0, p1;
    #pragma unroll
    for (int oc = 0; oc < 8; ++oc){
      f32x4 wv = w0p[oc];
      p0[oc] = f2b(fmaxf(0.f, wv.x*x0 + wv.y*x1 + wv.z*x2 + wv.w));
    }
    #pragma unroll
    for (int oc = 0; oc < 8; ++oc){
      f32x4 wv = w0p[8+oc];
      p1[oc] = f2b(fmaxf(0.f, wv.x*x0 + wv.y*x1 + wv.z*x2 + wv.w));
    }
    *(u16x8*)&H0w[l*40]     = p0;
    *(u16x8*)&H0w[l*40 + 8] = p1;
    __syncthreads();
    #pragma unroll
    for (int mt = 0; mt < 4; ++mt){
      s16x8 af = *(const s16x8*)&H0w[(mt*16 + (l & 15))*40 + (l >> 4)*8];
      f32x4 c = {b1f, b1f, b1f, b1f};
      c = __builtin_amdgcn_mfma_f32_16x16x32_bf16(af, w1B, c, 0, 0, 0);
      #pragma unroll
      for (int r = 0; r < 4; ++r){
        float v = fmaxf(0.f, c[r]);
        shloc += v;
        H1w[(l & 15)*72 + mt*16 + (l >> 4)*4 + r] = f2b(v);
      }
    }
    __syncthreads();
    #pragma unroll
    for (int tt = 0; tt < 2; ++tt){
      s16x8 afg = *(const s16x8*)&H1w[(l & 15)*72 + tt*32 + (l >> 4)*8];
      acc = __builtin_amdgcn_mfma_f32_16x16x32_bf16(afg, afg, acc, 0, 0, 0);
    }
    __syncthreads();
  }
  #pragma unroll
  for (int r = 0; r < 4; ++r)
    GS[w][(l>>4)*4 + r][l & 15] = acc[r];
  shloc += __shfl_xor(shloc, 16);
  shloc += __shfl_xor(shloc, 32);
  if (l < 16) SHs[w][l] = shloc;
  __syncthreads();
  {
    int i = t >> 4, j = t & 15;
    float g = GS[0][i][j] + GS[1][i][j] + GS[2][i][j] + GS[3][i][j];
    PB[(size_t)blockIdx.x*272 + t] = g;
    if (t < 16)
      PB[(size_t)blockIdx.x*272 + 256 + t] = SHs[0][t]+SHs[1][t]+SHs[2][t]+SHs[3][t];
  }
}

// ---------------- k_red1 ----------------
__global__ __launch_bounds__(256) void k_red1(const float* PB, const float* w1, const float* b1,
                                              const float* g1, const float* be1, float* F,
                                              u16* w1Bg){
  __shared__ float red[272];
  __shared__ float a1sh[16];
  int t = threadIdx.x;
  for (int e = t; e < 272; e += 256){
    float s = 0.f;
    for (int r = 0; r < SGBLK; ++r) s += PB[(size_t)r*272 + e];
    red[e] = s;
  }
  __syncthreads();
  if (t < 16){
    float wv[16];
    #pragma unroll
    for (int ic = 0; ic < 16; ++ic) wv[ic] = w1[t*16+ic];
    float lin = 0.f;
    #pragma unroll
    for (int ic = 0; ic < 16; ++ic) lin += wv[ic]*red[256+ic];
    float quad = 0.f;
    for (int i = 0; i < 16; ++i){
      float ri = 0.f;
      #pragma unroll
      for (int j = 0; j < 16; ++j) ri += wv[j]*red[i*16+j];
      quad += wv[i]*ri;
    }
    float bb = b1[t];
    float S = lin + (float)NWN * bb;
    float Q = quad + 2.f*bb*lin + (float)NWN*bb*bb;
    float m = S * (1.f/NWN);
    float v = Q * (1.f/NWN) - m*m;
    float a = g1[t] * rsqrtf(v + EPSF);
    float d = be1[t] - m*a;
    a1sh[t] = a;
    F[320+t] = a*bb + d;
  }
  __syncthreads();
  F[64 + t] = a1sh[t >> 4] * w1[t];
  if (t < 64){
    int oc = t & 15, icb = (t >> 4) * 8;
    u16x8 fr;
    #pragma unroll
    for (int j = 0; j < 8; ++j){
      int ic = icb + j;
      fr[j] = (ic < 16) ? f2b(a1sh[oc] * w1[oc*16 + ic]) : (u16)0;
    }
    *(u16x8*)&w1Bg[t*8] = fr;
  }
}

// ---------------- k_red2 ----------------
__global__ __launch_bounds__(256) void k_red2(const float* PB, const float* w2, const float* b2,
                                              const float* g2, const float* be2, float* F,
                                              u16* w2Bg){
  __shared__ float red[272];
  __shared__ float a2sh[64];
  int t = threadIdx.x;
  for (int e = t; e < 272; e += 256){
    float s = 0.f;
    for (int r = 0; r < SGBLK; ++r) s += PB[(size_t)r*272 + e];
    red[e] = s;
  }
  __syncthreads();
  if (t < 64){
    float wv[16];
    #pragma unroll
    for (int ic = 0; ic < 16; ++ic) wv[ic] = w2[t*16+ic];
    float lin = 0.f;
    #pragma unroll
    for (int ic = 0; ic < 16; ++ic) lin += wv[ic]*red[256+ic];
    float quad = 0.f;
    for (int i = 0; i < 16; ++i){
      float ri = 0.f;
      #pragma unroll
      for (int j = 0; j < 16; ++j) ri += wv[j]*red[i*16+j];
      quad += wv[i]*ri;
    }
    float bb = b2[t];
    float S = lin + (float)NWN * bb;
    float Q = quad + 2.f*bb*lin + (float)NWN*bb*bb;
    float m = S * (1.f/NWN);
    float v = Q * (1.f/NWN) - m*m;
    float a = g2[t] * rsqrtf(v + EPSF);
    float d = be2[t] - m*a;
    a2sh[t] = a;
    F[1360+t] = a*bb + d;
  }
  __syncthreads();
  for (int i = t; i < 1024; i += 256) F[336+i] = a2sh[i >> 4] * w2[i];
  {
    int ot = t >> 6, lane = t & 63;
    int oc = ot*16 + (lane & 15), icb = ((lane >> 4)) * 8;
    u16x8 fr;
    #pragma unroll
    for (int j = 0; j < 8; ++j){
      int ic = icb + j;
      fr[j] = (ic < 16) ? f2b(a2sh[oc] * w2[oc*16 + ic]) : (u16)0;
    }
    *(u16x8*)&w2Bg[t*8] = fr;
  }
}

// ---------------- K5: TWO points per block — MFMA WeightNet + MFMA matmul, 3 barriers ----------------
__global__ __launch_bounds__(256) void k_main(const float* lcg, const int* nbrg,
    const u16* ptsw, const float* F,
    const u16* w1Bg, const u16* w2Bg,
    u16* npw){
  __shared__ __align__(16) u16 Gr[2][64*40];        // swizzled K-major per point
  __shared__ __align__(16) u16 WrBuf[2][64*40];     // W output; [0..1279] doubles as H0bf
  __shared__ __align__(16) u16 H1bf[2][32*40];
  int t = threadIdx.x;
  int w = t >> 6, l = t & 63;
  int p0 = blockIdx.x * 2;
  s16x8 w1B  = *(const s16x8*)&w1Bg[l*8];
  s16x8 w2B0 = *(const s16x8*)&w2Bg[(0*64 + l)*8];
  s16x8 w2B1 = *(const s16x8*)&w2Bg[(1*64 + l)*8];
  s16x8 w2B2 = *(const s16x8*)&w2Bg[(2*64 + l)*8];
  s16x8 w2B3 = *(const s16x8*)&w2Bg[(3*64 + l)*8];
  float b1f  = F[320 + (l & 15)];
  float b2f0 = F[1360 +  0 + (l & 15)];
  float b2f1 = F[1360 + 16 + (l & 15)];
  float b2f2 = F[1360 + 32 + (l & 15)];
  float b2f3 = F[1360 + 48 + (l & 15)];
  int oc0 = (t & 7) * 2;
  f32x4 w0a = {F[oc0*3], F[oc0*3+1], F[oc0*3+2], F[48+oc0]};
  f32x4 w0b = {F[oc0*3+3], F[oc0*3+4], F[oc0*3+5], F[48+oc0+1]};
  {
    int k = t >> 3, c = 16 + (t & 7)*2;
    *(unsigned int*)&WrBuf[0][k*40 + c] = 0u;
    *(unsigned int*)&WrBuf[1][k*40 + c] = 0u;
    *(unsigned int*)&H1bf[0][k*40 + c] = 0u;
    *(unsigned int*)&H1bf[1][k*40 + c] = 0u;
  }
  {
    int kg = w*8 + (l >> 3), c8 = l & 7;
    int kphys = ((w ^ (c8 & 3)) << 3) + (l >> 3);
    #pragma unroll
    for (int pt = 0; pt < 2; ++pt){
      int point = p0 + pt;
      int bbp = point >> 10;
      int n = nbrg[(size_t)point*32 + kg];
      u16x8 g = *(const u16x8*)(ptsw + (size_t)(bbp * NN + n)*64 + c8*8);
      #pragma unroll
      for (int j = 0; j < 8; ++j)
        Gr[pt][(c8*8 + j)*40 + kphys] = g[j];
    }
  }
  {
    int k = t >> 3;
    #pragma unroll
    for (int pt = 0; pt < 2; ++pt){
      const float* xp = lcg + (size_t)(p0 + pt)*96 + k*3;
      float x0 = xp[0], x1 = xp[1], x2 = xp[2];
      WrBuf[pt][k*40 + oc0]     = f2b(fmaxf(0.f, w0a.x*x0 + w0a.y*x1 + w0a.z*x2 + w0a.w));
      WrBuf[pt][k*40 + oc0 + 1] = f2b(fmaxf(0.f, w0b.x*x0 + w0b.y*x1 + w0b.z*x2 + w0b.w));
    }
  }
  __syncthreads();   // (1) H0(=WrBuf low) + pads ready
  {
    int pt = w >> 1, kt = w & 1;
    s16x8 af = *(const s16x8*)&WrBuf[pt][(kt*16 + (l & 15))*40 + (l >> 4)*8];
    f32x4 acc = {b1f, b1f, b1f, b1f};
    acc = __builtin_amdgcn_mfma_f32_16x16x32_bf16(af, w1B, acc, 0, 0, 0);
    #pragma unroll
    for (int r = 0; r < 4; ++r)
      H1bf[pt][(kt*16 + (l >> 4)*4 + r)*40 + (l & 15)] = f2b(fmaxf(0.f, acc[r]));
  }
  __syncthreads();   // (2) H1bf ready; H0 region dead -> Wr may overwrite
  {
    int pt = w & 1, kt = w >> 1;
    s16x8 af = *(const s16x8*)&H1bf[pt][(kt*16 + (l & 15))*40 + (l >> 4)*8];
    int kbase = kt*16 + (l >> 4)*4;
    f32x4 a0c = {b2f0,b2f0,b2f0,b2f0};
    a0c = __builtin_amdgcn_mfma_f32_16x16x32_bf16(af, w2B0, a0c, 0, 0, 0);
    u16x4 s0v; s0v[0]=f2b(fmaxf(0.f,a0c[0])); s0v[1]=f2b(fmaxf(0.f,a0c[1]));
    s0v[2]=f2b(fmaxf(0.f,a0c[2])); s0v[3]=f2b(fmaxf(0.f,a0c[3]));
    *(u16x4*)&WrBuf[pt][( 0 + (l & 15))*40 + kbase] = s0v;
    f32x4 a1c = {b2f1,b2f1,b2f1,b2f1};
    a1c = __builtin_amdgcn_mfma_f32_16x16x32_bf16(af, w2B1, a1c, 0, 0, 0);
    u16x4 s1v; s1v[0]=f2b(fmaxf(0.f,a1c[0])); s1v[1]=f2b(fmaxf(0.f,a1c[1]));
    s1v[2]=f2b(fmaxf(0.f,a1c[2])); s1v[3]=f2b(fmaxf(0.f,a1c[3]));
    *(u16x4*)&WrBuf[pt][(16 + (l & 15))*40 + kbase] = s1v;
    f32x4 a2c = {b2f2,b2f2,b2f2,b2f2};
    a2c = __builtin_amdgcn_mfma_f32_16x16x32_bf16(af, w2B2, a2c, 0, 0, 0);
    u16x4 s2v; s2v[0]=f2b(fmaxf(0.f,a2c[0])); s2v[1]=f2b(fmaxf(0.f,a2c[1]));
    s2v[2]=f2b(fmaxf(0.f,a2c[2])); s2v[3]=f2b(fmaxf(0.f,a2c[3]));
    *(u16x4*)&WrBuf[pt][(32 + (l & 15))*40 + kbase] = s2v;
    f32x4 a3c = {b2f3,b2f3,b2f3,b2f3};
    a3c = __builtin_amdgcn_mfma_f32_16x16x32_bf16(af, w2B3, a3c, 0, 0, 0);
    u16x4 s3v; s3v[0]=f2b(fmaxf(0.f,a3c[0])); s3v[1]=f2b(fmaxf(0.f,a3c[1]));
    s3v[2]=f2b(fmaxf(0.f,a3c[2])); s3v[3]=f2b(fmaxf(0.f,a3c[3]));
    *(u16x4*)&WrBuf[pt][(48 + (l & 15))*40 + kbase] = s3v;
  }
  __syncthreads();   // (3) Gr, Wr ready
  {
    int li = l & 15, lkb = l >> 4, lr = (l >> 4) * 4;
    #pragma unroll
    for (int pt = 0; pt < 2; ++pt){
      s16x8 bfrag = *(const s16x8*)&WrBuf[pt][(w*16 + li)*40 + lkb*8];
      size_t obase = (size_t)(p0 + pt)*4096 + (size_t)(w*16 + li)*64 + lr;
      #pragma unroll
      for (int it = 0; it < 4; ++it){
        int ch = it*16 + li;
        int key = (ch >> 3) & 3;
        s16x8 afrag = *(const s16x8*)&Gr[pt][ch*40 + ((lkb ^ key) << 3)];
        f32x4 z = {0.f, 0.f, 0.f, 0.f};
        f32x4 d = __builtin_amdgcn_mfma_f32_16x16x32_bf16(afrag, bfrag, z, 0, 0, 0);
        u16x4 st;
        st[0] = f2b(d[0]); st[1] = f2b(d[1]); st[2] = f2b(d[2]); st[3] = f2b(d[3]);
        *(u16x4*)(npw + obase + it*16) = st;
      }
    }
  }
}

// ---------------- k_statC ----------------
__global__ __launch_bounds__(256) void k_statC(const u16* npw, float* PC){
  int t = threadIdx.x;
  float s[16], q[16];
  #pragma unroll
  for (int j = 0; j < 16; ++j){ s[j] = 0.f; q[j] = 0.f; }
  size_t rowbase = (size_t)blockIdx.x * 64;
  for (int p = 0; p < 64; ++p){
    const u16* row = npw + (rowbase + p) * 4096 + t * 16;
    u16x8 a = *(const u16x8*)row;
    u16x8 b = *(const u16x8*)(row + 8);
    #pragma unroll
    for (int j = 0; j < 8; ++j){ float v = bf(a[j]); s[j]   += v; q[j]   += v*v; }
    #pragma unroll
    for (int j = 0; j < 8; ++j){ float v = bf(b[j]); s[8+j] += v; q[8+j] += v*v; }
  }
  float* dst = PC + (size_t)blockIdx.x * 8192 + t * 16;
  #pragma unroll
  for (int j = 0; j < 16; ++j){ dst[j] = s[j]; dst[4096 + j] = q[j]; }
}

// ---------------- k_finC (position space; gc/bc permuted) ----------------
__global__ __launch_bounds__(256) void k_finC(const float* PC, const float* gc, const float* bc,
                                              float* AC, float* DC){
  int qpos = blockIdx.x * 256 + threadIdx.x;
  float s = 0.f, q = 0.f;
  for (int r = 0; r < 256; ++r){
    s += PC[(size_t)r * 8192 + qpos];
    q += PC[(size_t)r * 8192 + 4096 + qpos];
  }
  int ch = (qpos & 63)*64 + (qpos >> 6);
  float m = s * (1.f/16384.f);
  float v = q * (1.f/16384.f) - m*m;
  float a = gc[ch] * rsqrtf(v + EPSF);
  AC[qpos] = a; DC[qpos] = bc[ch] - m*a;
}

// ---------------- k_linear: 16 rows/block, grid 1024, double-buffered LDS (1 barrier/K-step) ----------------
__global__ __launch_bounds__(256) void k_linear(const u16* npw, const float* AC, const float* DC,
                                                const u16* lwbt, const float* lb, float* yw,
                                                float* PL){
  __shared__ u16 Al[2][16*72];
  __shared__ u16 Bl[2][64*72];
  __shared__ float cps[64], cpq[64];
  int t = threadIdx.x;
  int w = t >> 6, l = t & 63;
  int rowbase = blockIdx.x * 16;
  int rA = t >> 4, cA = t & 15;
  int nB = t >> 3, cB = t & 7;
  const u16* Aptr  = npw  + (size_t)(rowbase + rA)*4096 + cA*4;
  const u16* B0ptr = lwbt + (size_t)nB*4096 + cB*8;
  const u16* B1ptr = lwbt + (size_t)(nB + 32)*4096 + cB*8;
  f32x4 acc0 = {0.f,0.f,0.f,0.f};
  // prologue: load kb=0, write buf0, prefetch kb=64
  u16x4 uA  = *(const u16x4*)(Aptr);
  u16x8 uB0 = *(const u16x8*)(B0ptr);
  u16x8 uB1 = *(const u16x8*)(B1ptr);
  {
    int kk = cA*4;
    f32x4 av = *(const f32x4*)(AC + kk);
    f32x4 dv = *(const f32x4*)(DC + kk);
    u16x4 o;
    o[0] = f2b(fmaxf(0.f, av.x*bf(uA[0]) + dv.x));
    o[1] = f2b(fmaxf(0.f, av.y*bf(uA[1]) + dv.y));
    o[2] = f2b(fmaxf(0.f, av.z*bf(uA[2]) + dv.z));
    o[3] = f2b(fmaxf(0.f, av.w*bf(uA[3]) + dv.w));
    *(u16x4*)&Al[0][rA*72 + cA*4] = o;
    *(u16x8*)&Bl[0][nB*72 + cB*8]        = uB0;
    *(u16x8*)&Bl[0][(nB + 32)*72 + cB*8] = uB1;
  }
  uA  = *(const u16x4*)(Aptr + 64);
  uB0 = *(const u16x8*)(B0ptr + 64);
  uB1 = *(const u16x8*)(B1ptr + 64);
  __syncthreads();   // buf0 ready
  int cur = 0;
  for (int kb = 0; kb < 4096; kb += 64){
    // write buf[cur^1] from prefetched regs (data for kb+64)
    if (kb + 64 < 4096){
      int kk = kb + 64 + cA*4;
      f32x4 av = *(const f32x4*)(AC + kk);
      f32x4 dv = *(const f32x4*)(DC + kk);
      u16x4 o;
      o[0] = f2b(fmaxf(0.f, av.x*bf(uA[0]) + dv.x));
      o[1] = f2b(fmaxf(0.f, av.y*bf(uA[1]) + dv.y));
      o[2] = f2b(fmaxf(0.f, av.z*bf(uA[2]) + dv.z));
      o[3] = f2b(fmaxf(0.f, av.w*bf(uA[3]) + dv.w));
      *(u16x4*)&Al[cur^1][rA*72 + cA*4] = o;
      *(u16x8*)&Bl[cur^1][nB*72 + cB*8]        = uB0;
      *(u16x8*)&Bl[cur^1][(nB + 32)*72 + cB*8] = uB1;
      // prefetch kb+128 (latency hides under MFMA + barrier)
      if (kb + 128 < 4096){
        uA  = *(const u16x4*)(Aptr + kb + 128);
        uB0 = *(const u16x8*)(B0ptr + kb + 128);
        uB1 = *(const u16x8*)(B1ptr + kb + 128);
      }
    }
    // MFMA on buf[cur]
    #pragma unroll
    for (int ks = 0; ks < 2; ++ks){
      s16x8 af  = *(const s16x8*)&Al[cur][((l & 15))*72 + ks*32 + (l >> 4)*8];
      s16x8 bf0 = *(const s16x8*)&Bl[cur][(w*16 + (l & 15))*72 + ks*32 + (l >> 4)*8];
      acc0 = __builtin_amdgcn_mfma_f32_16x16x32_bf16(af, bf0, acc0, 0, 0, 0);
    }
    __syncthreads();   // buf[cur] reads done + buf[cur^1] writes visible
    cur ^= 1;
  }
  int col0 = w*16 + (l & 15);
  float lb0 = lb[col0];
  float s0 = 0.f, q0 = 0.f;
  if (t < 64){ cps[t] = 0.f; cpq[t] = 0.f; }
  __syncthreads();
  #pragma unroll
  for (int r = 0; r < 4; ++r){
    int row = rowbase + (l >> 4)*4 + r;
    float y0 = acc0[r] + lb0;
    yw[(size_t)row*64 + col0] = y0;
    s0 += y0; q0 += y0*y0;
  }
  atomicAdd(&cps[col0], s0); atomicAdd(&cpq[col0], q0);
  __syncthreads();
  if (t < 64){
    PL[blockIdx.x*128 + t]      = cps[t];
    PL[blockIdx.x*128 + 64 + t] = cpq[t];
  }
}

// ---------------- k_redF (1024 blocks of PL) ----------------
__global__ __launch_bounds__(128) void k_redF(const float* PL, float* SL){
  int t = threadIdx.x;
  float s = 0.f;
  for (int b = 0; b < 1024; ++b) s += PL[b*128 + t];
  SL[t] = s;
}

// ---------------- k_final ----------------
__global__ __launch_bounds__(256) void k_final(const float* yw, const float* SL,
                                               const float* gl, const float* bl, float* out){
  int e = (blockIdx.x * 256 + threadIdx.x) * 4;
  int o = e & 63;
  f32x4 y = *(const f32x4*)(yw + e);
  f32x4 r;
  #pragma unroll
  for (int j = 0; j < 4; ++j){
    float m = SL[o+j] * (1.f/16384.f);
    float v = SL[64+o+j] * (1.f/16384.f) - m*m;
    float a = gl[o+j] * rsqrtf(v + EPSF);
    float d = bl[o+j] - m*a;
    r[j] = fmaxf(0.f, a*y[j] + d);
  }
  *(f32x4*)(out + 49152 + e) = r;
}

extern "C" void kernel_launch(void* const* d_in, const int* in_sizes, int n_in,
                              void* d_out, int out_size, void* d_ws, size_t ws_size,
                              hipStream_t stream){
  (void)in_sizes; (void)n_in; (void)out_size; (void)ws_size;
  const float* xyz    = (const float*)d_in[0];
  const float* points = (const float*)d_in[1];
  const float* lc     = (const float*)d_in[2];
  const int*   nbrl   = (const int*)d_in[3];
  const int*   didx   = (const int*)d_in[4];
  const float* w0 = (const float*)d_in[5];
  const float* b0 = (const float*)d_in[6];
  const float* g0 = (const float*)d_in[7];
  const float* be0= (const float*)d_in[8];
  const float* w1 = (const float*)d_in[9];
  const float* b1 = (const float*)d_in[10];
  const float* g1 = (const float*)d_in[11];
  const float* be1= (const float*)d_in[12];
  const float* w2 = (const float*)d_in[13];
  const float* b2 = (const float*)d_in[14];
  const float* g2 = (const float*)d_in[15];
  const float* be2= (const float*)d_in[16];
  const float* gc = (const float*)d_in[17];
  const float* bc = (const float*)d_in[18];
  const float* lw = (const float*)d_in[19];
  const float* lb = (const float*)d_in[20];
  const float* gl = (const float*)d_in[21];
  const float* bl = (const float*)d_in[22];
  float* out = (float*)d_out;
  char* ws = (char*)d_ws;

  float* F   = (float*)ws;           // 1536
  float* SL  = F + 1536;             // 128
  float* AC  = SL + 128;             // 4096
  float* DC  = AC + 4096;            // 4096
  float* PA  = DC + 4096;            // 32768
  float* PB1 = PA + 32768;           // 139264
  float* PB2 = PB1 + 139264;         // 139264
  float* PL  = PB2 + 139264;         // 131072 (1024 blocks x 128)
  u16*  w1Bg = (u16*)(PL + 131072);  // 512 u16
  u16*  w2Bg = w1Bg + 512;           // 2048 u16
  float* PC  = (float*)(ws + 4194304);                        // 8 MB
  u16*  npw  = (u16*)(ws + 4194304 + 8388608);                // 128 MB bf16 (transposed)
  float* yw  = (float*)(ws + 4194304 + 8388608 + 134217728);  // 4 MB f32
  u16*  lwbt = (u16*)(ws + 4194304 + 8388608 + 134217728 + 4194304); // 512 KB (permuted)
  u16*  ptsw = (u16*)(ws + 4194304 + 8388608 + 134217728 + 4194304 + 1048576); // 8 MB bf16

  k_init  <<<1152,  256, 0, stream>>>(xyz, didx, out, lw, lwbt, points, ptsw, lc, PA);
  k_red0  <<<1,     256, 0, stream>>>(PA, w0, b0, g0, be0, F);
  k_statG1<<<SGBLK, 256, 0, stream>>>(lc, F, PB1);
  k_red1  <<<1,     256, 0, stream>>>(PB1, w1, b1, g1, be1, F, w1Bg);
  k_statG2<<<SGBLK, 256, 0, stream>>>(lc, F, w1Bg, PB2);
  k_red2  <<<1,     256, 0, stream>>>(PB2, w2, b2, g2, be2, F, w2Bg);
  k_main  <<<8192,  256, 0, stream>>>(lc, nbrl, ptsw, F, w1Bg, w2Bg, npw);
  k_statC <<<256,   256, 0, stream>>>(npw, PC);
  k_finC  <<<16,    256, 0, stream>>>(PC, gc, bc, AC, DC);
  k_linear<<<1024,  256, 0, stream>>>(npw, AC, DC, lwbt, lb, yw, PL);
  k_redF  <<<1,     128, 0, stream>>>(PL, SL);
  k_final <<<1024,  256, 0, stream>>>(yw, SL, gl, bl, out);
}

// Round 23
// 249.302 us; speedup vs baseline: 1.0622x; 1.0343x over previous
//
#include <hip/hip_runtime.h>
#include <hip/hip_bf16.h>

#define BB 16
#define NN 4096
#define NPOINTS 1024
#define KK 32
#define NPTS (BB*NPOINTS)        // 16384
#define NWN  (BB*NPOINTS*KK)     // 524288
#define EPSF 1e-5f
#define SGBLK 512
#define SGIT  4

typedef unsigned short u16;
typedef u16  u16x8 __attribute__((ext_vector_type(8)));
typedef u16  u16x4 __attribute__((ext_vector_type(4)));
typedef short s16x8 __attribute__((ext_vector_type(8)));
typedef float f32x4 __attribute__((ext_vector_type(4)));
typedef float f32x4u __attribute__((ext_vector_type(4), aligned(4)));

__device__ __forceinline__ float bf(u16 u){
  union { unsigned int i; float f; } v; v.i = ((unsigned int)u) << 16; return v.f;
}
__device__ __forceinline__ u16 f2b(float f){
  __hip_bfloat16 h = __float2bfloat16(f);
  union { __hip_bfloat16 hh; u16 u; } v; v.hh = h; return v.u;
}

// F layout (folded weights): [0..47] w0f, [48..63] b0f, [64..319] w1f,
// [320..335] b1f, [336..1359] w2f, [1360..1423] b2f
// npw: transposed position space q = o*64 + i  (original channel ch = i*64 + o)
// ptsw[B*N][64] bf16: pre-converted concat(points, xyz) rows
// Gr LDS: K-major, 16B k-blocks XOR-swizzled by (ch>>3)&3
// k_main (round 23): 16 points/block (grid 1024); channel-stat partials fused
//   into registers (positions are point-invariant per thread) -> PC[1024][8192];
//   k_statC deleted. WrBuf H0-pads re-zeroed each loop iter (W overwrites them).
// yw aliases the PC region (PC dead after k_finC, yw born at k_linear).
// NOTE (round 15): device atomics bypass L2 on MI355X -> keep stats streaming.

// ---------------- k_init: newxyz (0..63) + lwbt (64..127) + ptsw (128..639) + lc moments (640..1151) ----------------
__global__ __launch_bounds__(256) void k_init(const float* xyz, const int* didx, float* out,
                                              const float* lw, u16* lwbt,
                                              const float* points, u16* ptsw,
                                              const float* lc, float* PA){
  int t = threadIdx.x;
  if (blockIdx.x < 64){
    int p = blockIdx.x * 256 + t;
    int b = p >> 10;
    int idx = didx[p];
    const float* src = xyz + ((size_t)(b * NN + idx)) * 3;
    float* dst = out + (size_t)p * 3;
    dst[0] = src[0]; dst[1] = src[1]; dst[2] = src[2];
  } else if (blockIdx.x < 128){
    __shared__ float T[64][65];
    int ib = blockIdx.x - 64;
    int kb = ib * 64;
    {
      int k = t >> 2, c4 = t & 3;
      #pragma unroll
      for (int j = 0; j < 4; ++j)
        *(f32x4*)&T[k][c4*16 + j*4] = *(const f32x4*)(lw + (size_t)(kb + k)*64 + c4*16 + j*4);
    }
    __syncthreads();
    {
      int n = t >> 2, k4 = t & 3;
      #pragma unroll
      for (int j = 0; j < 16; ++j){
        int k = k4*16 + j;
        lwbt[(size_t)n*4096 + k*64 + ib] = f2b(T[k][n]);
      }
    }
  } else if (blockIdx.x < 640){
    int gid0 = (blockIdx.x - 128) * 256 + t;
    #pragma unroll
    for (int rep = 0; rep < 4; ++rep){
      int idx = gid0 + rep * 131072;
      int row = idx >> 3, c8 = idx & 7;
      const float* prow = points + (size_t)row * 61;
      u16x8 g;
      if (c8 < 7){
        f32x4 lo = *(const f32x4u*)(prow + c8*8);
        f32x4 hi = *(const f32x4u*)(prow + c8*8 + 4);
        g[0]=f2b(lo.x); g[1]=f2b(lo.y); g[2]=f2b(lo.z); g[3]=f2b(lo.w);
        g[4]=f2b(hi.x); g[5]=f2b(hi.y); g[6]=f2b(hi.z); g[7]=f2b(hi.w);
      } else {
        const float* xr = xyz + (size_t)row * 3;
        f32x4 lo = *(const f32x4u*)(prow + 56);
        g[0]=f2b(lo.x); g[1]=f2b(lo.y); g[2]=f2b(lo.z); g[3]=f2b(lo.w);
        g[4]=f2b(prow[60]);
        g[5]=f2b(xr[0]); g[6]=f2b(xr[1]); g[7]=f2b(xr[2]);
      }
      *(u16x8*)(ptsw + (size_t)row*64 + c8*8) = g;
    }
  } else {
    int bid = blockIdx.x - 640;
    float a[9];
    #pragma unroll
    for (int r = 0; r < 9; ++r) a[r] = 0.f;
    size_t base = (size_t)bid * 1024 + t;
    for (int ip = 0; ip < 4; ++ip){
      size_t p = base + (size_t)ip * 256;
      float x0 = lc[p*3], x1 = lc[p*3+1], x2 = lc[p*3+2];
      a[0]+=x0; a[1]+=x1; a[2]+=x2;
      a[3]+=x0*x0; a[4]+=x0*x1; a[5]+=x0*x2;
      a[6]+=x1*x1; a[7]+=x1*x2; a[8]+=x2*x2;
    }
    #pragma unroll
    for (int m = 1; m < 64; m <<= 1){
      #pragma unroll
      for (int r = 0; r < 9; ++r) a[r] += __shfl_xor(a[r], m);
    }
    if ((t & 63) == 0){
      float* dst = PA + (size_t)(bid*4 + (t>>6)) * 16;
      f32x4 v0 = {a[0],a[1],a[2],a[3]}, v1 = {a[4],a[5],a[6],a[7]}, v2 = {a[8],0.f,0.f,0.f};
      *(f32x4*)dst = v0; *(f32x4*)(dst+4) = v1; *(f32x4*)(dst+8) = v2;
    }
  }
}

// ---------------- k_red0 ----------------
__global__ __launch_bounds__(256) void k_red0(const float* PA, const float* w0, const float* b0,
                                              const float* g0, const float* be0, float* F){
  __shared__ float ms[12];
  __shared__ float a0sh[16];
  int t = threadIdx.x;
  if (t < 12){
    float s0=0,s1=0,s2=0,s3=0;
    const float* p = PA + t;
    for (int r = 0; r < 2048; r += 4){
      s0 += p[(size_t)(r+0)*16]; s1 += p[(size_t)(r+1)*16];
      s2 += p[(size_t)(r+2)*16]; s3 += p[(size_t)(r+3)*16];
    }
    ms[t] = (s0+s1)+(s2+s3);
  }
  __syncthreads();
  if (t < 16){
    float wx = w0[t*3], wy = w0[t*3+1], wz = w0[t*3+2], bb = b0[t];
    float lin = wx*ms[0] + wy*ms[1] + wz*ms[2];
    float quad = wx*wx*ms[3] + wy*wy*ms[6] + wz*wz*ms[8]
               + 2.f*(wx*wy*ms[4] + wx*wz*ms[5] + wy*wz*ms[7]);
    float S = lin + (float)NWN * bb;
    float Q = quad + 2.f*bb*lin + (float)NWN*bb*bb;
    float m = S * (1.f/NWN);
    float v = Q * (1.f/NWN) - m*m;
    float a = g0[t] * rsqrtf(v + EPSF);
    float d = be0[t] - m*a;
    a0sh[t] = a;
    F[48+t] = a*bb + d;
  }
  __syncthreads();
  if (t < 48) F[t] = a0sh[t/3] * w0[t];
}

// ---------------- k_statG1: h0 Gram (VALU h0, MFMA Gram) ----------------
__global__ __launch_bounds__(256) void k_statG1(const float* lc, const float* F, float* PB){
  __shared__ f32x4 w0p[16];
  __shared__ __align__(16) u16 Ht[4][16*72];
  __shared__ float GS[4][16][17];
  __shared__ float SHs[4][16];
  int t = threadIdx.x;
  int w = t >> 6, l = t & 63;
  if (t < 16){
    f32x4 wv = {F[t*3], F[t*3+1], F[t*3+2], F[48+t]};
    w0p[t] = wv;
  }
  __syncthreads();
  f32x4 acc = {0.f,0.f,0.f,0.f};
  float sh[16];
  #pragma unroll
  for (int r = 0; r < 16; ++r) sh[r] = 0.f;
  u16* Hw = &Ht[w][0];
  for (int it = 0; it < SGIT; ++it){
    size_t p = (size_t)blockIdx.x * (SGIT*256) + (size_t)it*256 + w*64 + l;
    float x0 = lc[p*3], x1 = lc[p*3+1], x2 = lc[p*3+2];
    float h[16];
    #pragma unroll
    for (int oc = 0; oc < 16; ++oc){
      f32x4 wv = w0p[oc];
      h[oc] = fmaxf(0.f, wv.x*x0 + wv.y*x1 + wv.z*x2 + wv.w);
      sh[oc] += h[oc];
    }
    #pragma unroll
    for (int c = 0; c < 16; ++c) Hw[c*72 + l] = f2b(h[c]);
    __syncthreads();
    #pragma unroll
    for (int tt = 0; tt < 2; ++tt){
      s16x8 af = *(const s16x8*)&Hw[(l & 15)*72 + tt*32 + (l >> 4)*8];
      acc = __builtin_amdgcn_mfma_f32_16x16x32_bf16(af, af, acc, 0, 0, 0);
    }
    __syncthreads();
  }
  #pragma unroll
  for (int r = 0; r < 4; ++r)
    GS[w][(l>>4)*4 + r][l & 15] = acc[r];
  #pragma unroll
  for (int m = 1; m < 64; m <<= 1){
    #pragma unroll
    for (int r = 0; r < 16; ++r) sh[r] += __shfl_xor(sh[r], m);
  }
  if (l == 0){
    #pragma unroll
    for (int r = 0; r < 16; ++r) SHs[w][r] = sh[r];
  }
  __syncthreads();
  {
    int i = t >> 4, j = t & 15;
    float g = GS[0][i][j] + GS[1][i][j] + GS[2][i][j] + GS[3][i][j];
    PB[(size_t)blockIdx.x*272 + t] = g;
    if (t < 16)
      PB[(size_t)blockIdx.x*272 + 256 + t] = SHs[0][t]+SHs[1][t]+SHs[2][t]+SHs[3][t];
  }
}

// ---------------- k_statG2: h1 Gram (MFMA h1 via w1Bg + MFMA Gram) ----------------
__global__ __launch_bounds__(256) void k_statG2(const float* lc, const float* F,
                                                const u16* w1Bg, float* PB){
  __shared__ f32x4 w0p[16];
  __shared__ __align__(16) u16 Ht0[4][64*40];
  __shared__ __align__(16) u16 Ht1[4][16*72];
  __shared__ float GS[4][16][17];
  __shared__ float SHs[4][16];
  int t = threadIdx.x;
  int w = t >> 6, l = t & 63;
  if (t < 16){
    f32x4 wv = {F[t*3], F[t*3+1], F[t*3+2], F[48+t]};
    w0p[t] = wv;
  }
  s16x8 w1B = *(const s16x8*)&w1Bg[l*8];
  float b1f = F[320 + (l & 15)];
  u16* H0w = &Ht0[w][0];
  u16* H1w = &Ht1[w][0];
  {
    u16x8 z8 = {0,0,0,0,0,0,0,0};
    *(u16x8*)&H0w[l*40 + 16] = z8;
    *(u16x8*)&H0w[l*40 + 24] = z8;
  }
  __syncthreads();
  f32x4 acc = {0.f,0.f,0.f,0.f};
  float shloc = 0.f;
  for (int it = 0; it < SGIT; ++it){
    size_t p = (size_t)blockIdx.x * (SGIT*256) + (size_t)it*256 + w*64 + l;
    float x0 = lc[p*3], x1 = lc[p*3+1], x2 = lc[p*3+2];
    u16x8 p0, p1;
    #pragma unroll
    for (int oc = 0; oc < 8; ++oc){
      f32x4 wv = w0p[oc];
      p0[oc] = f2b(fmaxf(0.f, wv.x*x0 + wv.y*x1 + wv.z*x2 + wv.w));
    }
    #pragma unroll
    for (int oc = 0; oc < 8; ++oc){
      f32x4 wv = w0p[8+oc];
      p1[oc] = f2b(fmaxf(0.f, wv.x*x0 + wv.y*x1 + wv.z*x2 + wv.w));
    }
    *(u16x8*)&H0w[l*40]     = p0;
    *(u16x8*)&H0w[l*40 + 8] = p1;
    __syncthreads();
    #pragma unroll
    for (int mt = 0; mt < 4; ++mt){
      s16x8 af = *(const s16x8*)&H0w[(mt*16 + (l & 15))*40 + (l >> 4)*8];
      f32x4 c = {b1f, b1f, b1f, b1f};
      c = __builtin_amdgcn_mfma_f32_16x16x32_bf16(af, w1B, c, 0, 0, 0);
      #pragma unroll
      for (int r = 0; r < 4; ++r){
        float v = fmaxf(0.f, c[r]);
        shloc += v;
        H1w[(l & 15)*72 + mt*16 + (l >> 4)*4 + r] = f2b(v);
      }
    }
    __syncthreads();
    #pragma unroll
    for (int tt = 0; tt < 2; ++tt){
      s16x8 afg = *(const s16x8*)&H1w[(l & 15)*72 + tt*32 + (l >> 4)*8];
      acc = __builtin_amdgcn_mfma_f32_16x16x32_bf16(afg, afg, acc, 0, 0, 0);
    }
    __syncthreads();
  }
  #pragma unroll
  for (int r = 0; r < 4; ++r)
    GS[w][(l>>4)*4 + r][l & 15] = acc[r];
  shloc += __shfl_xor(shloc, 16);
  shloc += __shfl_xor(shloc, 32);
  if (l < 16) SHs[w][l] = shloc;
  __syncthreads();
  {
    int i = t >> 4, j = t & 15;
    float g = GS[0][i][j] + GS[1][i][j] + GS[2][i][j] + GS[3][i][j];
    PB[(size_t)blockIdx.x*272 + t] = g;
    if (t < 16)
      PB[(size_t)blockIdx.x*272 + 256 + t] = SHs[0][t]+SHs[1][t]+SHs[2][t]+SHs[3][t];
  }
}

// ---------------- k_red1 ----------------
__global__ __launch_bounds__(256) void k_red1(const float* PB, const float* w1, const float* b1,
                                              const float* g1, const float* be1, float* F,
                                              u16* w1Bg){
  __shared__ float red[272];
  __shared__ float a1sh[16];
  int t = threadIdx.x;
  for (int e = t; e < 272; e += 256){
    float s = 0.f;
    for (int r = 0; r < SGBLK; ++r) s += PB[(size_t)r*272 + e];
    red[e] = s;
  }
  __syncthreads();
  if (t < 16){
    float wv[16];
    #pragma unroll
    for (int ic = 0; ic < 16; ++ic) wv[ic] = w1[t*16+ic];
    float lin = 0.f;
    #pragma unroll
    for (int ic = 0; ic < 16; ++ic) lin += wv[ic]*red[256+ic];
    float quad = 0.f;
    for (int i = 0; i < 16; ++i){
      float ri = 0.f;
      #pragma unroll
      for (int j = 0; j < 16; ++j) ri += wv[j]*red[i*16+j];
      quad += wv[i]*ri;
    }
    float bb = b1[t];
    float S = lin + (float)NWN * bb;
    float Q = quad + 2.f*bb*lin + (float)NWN*bb*bb;
    float m = S * (1.f/NWN);
    float v = Q * (1.f/NWN) - m*m;
    float a = g1[t] * rsqrtf(v + EPSF);
    float d = be1[t] - m*a;
    a1sh[t] = a;
    F[320+t] = a*bb + d;
  }
  __syncthreads();
  F[64 + t] = a1sh[t >> 4] * w1[t];
  if (t < 64){
    int oc = t & 15, icb = (t >> 4) * 8;
    u16x8 fr;
    #pragma unroll
    for (int j = 0; j < 8; ++j){
      int ic = icb + j;
      fr[j] = (ic < 16) ? f2b(a1sh[oc] * w1[oc*16 + ic]) : (u16)0;
    }
    *(u16x8*)&w1Bg[t*8] = fr;
  }
}

// ---------------- k_red2 ----------------
__global__ __launch_bounds__(256) void k_red2(const float* PB, const float* w2, const float* b2,
                                              const float* g2, const float* be2, float* F,
                                              u16* w2Bg){
  __shared__ float red[272];
  __shared__ float a2sh[64];
  int t = threadIdx.x;
  for (int e = t; e < 272; e += 256){
    float s = 0.f;
    for (int r = 0; r < SGBLK; ++r) s += PB[(size_t)r*272 + e];
    red[e] = s;
  }
  __syncthreads();
  if (t < 64){
    float wv[16];
    #pragma unroll
    for (int ic = 0; ic < 16; ++ic) wv[ic] = w2[t*16+ic];
    float lin = 0.f;
    #pragma unroll
    for (int ic = 0; ic < 16; ++ic) lin += wv[ic]*red[256+ic];
    float quad = 0.f;
    for (int i = 0; i < 16; ++i){
      float ri = 0.f;
      #pragma unroll
      for (int j = 0; j < 16; ++j) ri += wv[j]*red[i*16+j];
      quad += wv[i]*ri;
    }
    float bb = b2[t];
    float S = lin + (float)NWN * bb;
    float Q = quad + 2.f*bb*lin + (float)NWN*bb*bb;
    float m = S * (1.f/NWN);
    float v = Q * (1.f/NWN) - m*m;
    float a = g2[t] * rsqrtf(v + EPSF);
    float d = be2[t] - m*a;
    a2sh[t] = a;
    F[1360+t] = a*bb + d;
  }
  __syncthreads();
  for (int i = t; i < 1024; i += 256) F[336+i] = a2sh[i >> 4] * w2[i];
  {
    int ot = t >> 6, lane = t & 63;
    int oc = ot*16 + (lane & 15), icb = ((lane >> 4)) * 8;
    u16x8 fr;
    #pragma unroll
    for (int j = 0; j < 8; ++j){
      int ic = icb + j;
      fr[j] = (ic < 16) ? f2b(a2sh[oc] * w2[oc*16 + ic]) : (u16)0;
    }
    *(u16x8*)&w2Bg[t*8] = fr;
  }
}

// ---------------- K5: 16 points/block (8x 2-point pipeline) + fused channel-stat partials ----------------
__global__ __launch_bounds__(256) void k_main(const float* lcg, const int* nbrg,
    const u16* ptsw, const float* F,
    const u16* w1Bg, const u16* w2Bg,
    u16* npw, float* PC){
  __shared__ __align__(16) u16 Gr[2][64*40];        // swizzled K-major per point
  __shared__ __align__(16) u16 WrBuf[2][64*40];     // W output; [0..1279] doubles as H0bf
  __shared__ __align__(16) u16 H1bf[2][32*40];
  int t = threadIdx.x;
  int w = t >> 6, l = t & 63;
  int pbase = blockIdx.x * 16;
  s16x8 w1B  = *(const s16x8*)&w1Bg[l*8];
  s16x8 w2B0 = *(const s16x8*)&w2Bg[(0*64 + l)*8];
  s16x8 w2B1 = *(const s16x8*)&w2Bg[(1*64 + l)*8];
  s16x8 w2B2 = *(const s16x8*)&w2Bg[(2*64 + l)*8];
  s16x8 w2B3 = *(const s16x8*)&w2Bg[(3*64 + l)*8];
  float b1f  = F[320 + (l & 15)];
  float b2f0 = F[1360 +  0 + (l & 15)];
  float b2f1 = F[1360 + 16 + (l & 15)];
  float b2f2 = F[1360 + 32 + (l & 15)];
  float b2f3 = F[1360 + 48 + (l & 15)];
  int oc0 = (t & 7) * 2;
  f32x4 w0a = {F[oc0*3], F[oc0*3+1], F[oc0*3+2], F[48+oc0]};
  f32x4 w0b = {F[oc0*3+3], F[oc0*3+4], F[oc0*3+5], F[48+oc0+1]};
  // H1bf pads (columns 16..31 never written by H1 phase -> survive the loop)
  {
    int k = t >> 3, c = 16 + (t & 7)*2;
    *(unsigned int*)&H1bf[0][k*40 + c] = 0u;
    *(unsigned int*)&H1bf[1][k*40 + c] = 0u;
  }
  // per-thread channel-stat accumulators (positions are point-invariant)
  float sacc[16], qacc[16];
  #pragma unroll
  for (int j = 0; j < 16; ++j){ sacc[j] = 0.f; qacc[j] = 0.f; }
  __syncthreads();   // H1bf pads visible before first H1 phase

  for (int g = 0; g < 8; ++g){
    int p0 = pbase + g*2;
    // gather both points -> Gr swizzled K-major
    {
      int kg = w*8 + (l >> 3), c8 = l & 7;
      int kphys = ((w ^ (c8 & 3)) << 3) + (l >> 3);
      #pragma unroll
      for (int pt = 0; pt < 2; ++pt){
        int point = p0 + pt;
        int bbp = point >> 10;
        int n = nbrg[(size_t)point*32 + kg];
        u16x8 gv = *(const u16x8*)(ptsw + (size_t)(bbp * NN + n)*64 + c8*8);
        #pragma unroll
        for (int j = 0; j < 8; ++j)
          Gr[pt][(c8*8 + j)*40 + kphys] = gv[j];
      }
    }
    // H0 both points + re-zero H0 pads (W phase overwrote them last iter)
    {
      int k = t >> 3, cpad = 16 + (t & 7)*2;
      #pragma unroll
      for (int pt = 0; pt < 2; ++pt){
        const float* xp = lcg + (size_t)(p0 + pt)*96 + k*3;
        float x0 = xp[0], x1 = xp[1], x2 = xp[2];
        WrBuf[pt][k*40 + oc0]     = f2b(fmaxf(0.f, w0a.x*x0 + w0a.y*x1 + w0a.z*x2 + w0a.w));
        WrBuf[pt][k*40 + oc0 + 1] = f2b(fmaxf(0.f, w0b.x*x0 + w0b.y*x1 + w0b.z*x2 + w0b.w));
        *(unsigned int*)&WrBuf[pt][k*40 + cpad] = 0u;
      }
    }
    __syncthreads();   // (1) H0(=WrBuf low) + pads ready
    // H1: wave w -> pt = w>>1, kt = w&1
    {
      int pt = w >> 1, kt = w & 1;
      s16x8 af = *(const s16x8*)&WrBuf[pt][(kt*16 + (l & 15))*40 + (l >> 4)*8];
      f32x4 acc = {b1f, b1f, b1f, b1f};
      acc = __builtin_amdgcn_mfma_f32_16x16x32_bf16(af, w1B, acc, 0, 0, 0);
      #pragma unroll
      for (int r = 0; r < 4; ++r)
        H1bf[pt][(kt*16 + (l >> 4)*4 + r)*40 + (l & 15)] = f2b(fmaxf(0.f, acc[r]));
    }
    __syncthreads();   // (2) H1bf ready; H0 region dead -> Wr may overwrite
    // W: wave w -> pt = w&1, kt = w>>1; 4 o-tiles
    {
      int pt = w & 1, kt = w >> 1;
      s16x8 af = *(const s16x8*)&H1bf[pt][(kt*16 + (l & 15))*40 + (l >> 4)*8];
      int kbase = kt*16 + (l >> 4)*4;
      f32x4 a0c = {b2f0,b2f0,b2f0,b2f0};
      a0c = __builtin_amdgcn_mfma_f32_16x16x32_bf16(af, w2B0, a0c, 0, 0, 0);
      u16x4 s0v; s0v[0]=f2b(fmaxf(0.f,a0c[0])); s0v[1]=f2b(fmaxf(0.f,a0c[1]));
      s0v[2]=f2b(fmaxf(0.f,a0c[2])); s0v[3]=f2b(fmaxf(0.f,a0c[3]));
      *(u16x4*)&WrBuf[pt][( 0 + (l & 15))*40 + kbase] = s0v;
      f32x4 a1c = {b2f1,b2f1,b2f1,b2f1};
      a1c = __builtin_amdgcn_mfma_f32_16x16x32_bf16(af, w2B1, a1c, 0, 0, 0);
      u16x4 s1v; s1v[0]=f2b(fmaxf(0.f,a1c[0])); s1v[1]=f2b(fmaxf(0.f,a1c[1]));
      s1v[2]=f2b(fmaxf(0.f,a1c[2])); s1v[3]=f2b(fmaxf(0.f,a1c[3]));
      *(u16x4*)&WrBuf[pt][(16 + (l & 15))*40 + kbase] = s1v;
      f32x4 a2c = {b2f2,b2f2,b2f2,b2f2};
      a2c = __builtin_amdgcn_mfma_f32_16x16x32_bf16(af, w2B2, a2c, 0, 0, 0);
      u16x4 s2v; s2v[0]=f2b(fmaxf(0.f,a2c[0])); s2v[1]=f2b(fmaxf(0.f,a2c[1]));
      s2v[2]=f2b(fmaxf(0.f,a2c[2])); s2v[3]=f2b(fmaxf(0.f,a2c[3]));
      *(u16x4*)&WrBuf[pt][(32 + (l & 15))*40 + kbase] = s2v;
      f32x4 a3c = {b2f3,b2f3,b2f3,b2f3};
      a3c = __builtin_amdgcn_mfma_f32_16x16x32_bf16(af, w2B3, a3c, 0, 0, 0);
      u16x4 s3v; s3v[0]=f2b(fmaxf(0.f,a3c[0])); s3v[1]=f2b(fmaxf(0.f,a3c[1]));
      s3v[2]=f2b(fmaxf(0.f,a3c[2])); s3v[3]=f2b(fmaxf(0.f,a3c[3]));
      *(u16x4*)&WrBuf[pt][(48 + (l & 15))*40 + kbase] = s3v;
    }
    __syncthreads();   // (3) Gr, Wr ready
    // np = G^T W: wave w owns o-tile w, both points; accumulate stats in regs
    {
      int li = l & 15, lkb = l >> 4, lr = (l >> 4) * 4;
      #pragma unroll
      for (int pt = 0; pt < 2; ++pt){
        s16x8 bfrag = *(const s16x8*)&WrBuf[pt][(w*16 + li)*40 + lkb*8];
        size_t obase = (size_t)(p0 + pt)*4096 + (size_t)(w*16 + li)*64 + lr;
        #pragma unroll
        for (int it = 0; it < 4; ++it){
          int ch = it*16 + li;
          int key = (ch >> 3) & 3;
          s16x8 afrag = *(const s16x8*)&Gr[pt][ch*40 + ((lkb ^ key) << 3)];
          f32x4 z = {0.f, 0.f, 0.f, 0.f};
          f32x4 d = __builtin_amdgcn_mfma_f32_16x16x32_bf16(afrag, bfrag, z, 0, 0, 0);
          u16x4 st;
          st[0] = f2b(d[0]); st[1] = f2b(d[1]); st[2] = f2b(d[2]); st[3] = f2b(d[3]);
          *(u16x4*)(npw + obase + it*16) = st;
          #pragma unroll
          for (int r = 0; r < 4; ++r){
            sacc[it*4 + r] += d[r];
            qacc[it*4 + r] += d[r]*d[r];
          }
        }
      }
    }
    __syncthreads();   // (0) final reads done before next iter's gather/H0 overwrite
  }
  // write block channel-stat partials: PC[block][q] = s, PC[block][4096+q] = q
  {
    int qb = (w*16 + (l & 15))*64 + (l >> 4)*4;
    float* dst = PC + (size_t)blockIdx.x * 8192;
    #pragma unroll
    for (int it = 0; it < 4; ++it){
      f32x4 sv = {sacc[it*4+0], sacc[it*4+1], sacc[it*4+2], sacc[it*4+3]};
      f32x4 qv = {qacc[it*4+0], qacc[it*4+1], qacc[it*4+2], qacc[it*4+3]};
      *(f32x4*)(dst + qb + it*16) = sv;
      *(f32x4*)(dst + 4096 + qb + it*16) = qv;
    }
  }
}

// ---------------- k_finC: reduce 1024 block partials + finalize (grid 256) ----------------
__global__ __launch_bounds__(256) void k_finC(const float* PC, const float* gc, const float* bc,
                                              float* AC, float* DC){
  __shared__ float shs[16][17], shq[16][17];
  int t = threadIdx.x;
  int ql = t & 15, rc = t >> 4;     // 16 qpos x 16 row-chunks
  int qpos = blockIdx.x * 16 + ql;
  float s = 0.f, q = 0.f;
  int r0 = rc * 64;
  #pragma unroll 4
  for (int r = r0; r < r0 + 64; ++r){
    s += PC[(size_t)r * 8192 + qpos];
    q += PC[(size_t)r * 8192 + 4096 + qpos];
  }
  shs[ql][rc] = s; shq[ql][rc] = q;
  __syncthreads();
  if (t < 16){
    float ss = 0.f, qq = 0.f;
    #pragma unroll
    for (int c = 0; c < 16; ++c){ ss += shs[t][c]; qq += shq[t][c]; }
    int qp = blockIdx.x * 16 + t;
    int ch = (qp & 63)*64 + (qp >> 6);
    float m = ss * (1.f/16384.f);
    float v = qq * (1.f/16384.f) - m*m;
    float a = gc[ch] * rsqrtf(v + EPSF);
    AC[qp] = a; DC[qp] = bc[ch] - m*a;
  }
}

// ---------------- k_linear: 16 rows/block, grid 1024, double-buffered LDS ----------------
__global__ __launch_bounds__(256) void k_linear(const u16* npw, const float* AC, const float* DC,
                                                const u16* lwbt, const float* lb, float* yw,
                                                float* PL){
  __shared__ u16 Al[2][16*72];
  __shared__ u16 Bl[2][64*72];
  __shared__ float cps[64], cpq[64];
  int t = threadIdx.x;
  int w = t >> 6, l = t & 63;
  int rowbase = blockIdx.x * 16;
  int rA = t >> 4, cA = t & 15;
  int nB = t >> 3, cB = t & 7;
  const u16* Aptr  = npw  + (size_t)(rowbase + rA)*4096 + cA*4;
  const u16* B0ptr = lwbt + (size_t)nB*4096 + cB*8;
  const u16* B1ptr = lwbt + (size_t)(nB + 32)*4096 + cB*8;
  f32x4 acc0 = {0.f,0.f,0.f,0.f};
  u16x4 uA  = *(const u16x4*)(Aptr);
  u16x8 uB0 = *(const u16x8*)(B0ptr);
  u16x8 uB1 = *(const u16x8*)(B1ptr);
  {
    int kk = cA*4;
    f32x4 av = *(const f32x4*)(AC + kk);
    f32x4 dv = *(const f32x4*)(DC + kk);
    u16x4 o;
    o[0] = f2b(fmaxf(0.f, av.x*bf(uA[0]) + dv.x));
    o[1] = f2b(fmaxf(0.f, av.y*bf(uA[1]) + dv.y));
    o[2] = f2b(fmaxf(0.f, av.z*bf(uA[2]) + dv.z));
    o[3] = f2b(fmaxf(0.f, av.w*bf(uA[3]) + dv.w));
    *(u16x4*)&Al[0][rA*72 + cA*4] = o;
    *(u16x8*)&Bl[0][nB*72 + cB*8]        = uB0;
    *(u16x8*)&Bl[0][(nB + 32)*72 + cB*8] = uB1;
  }
  uA  = *(const u16x4*)(Aptr + 64);
  uB0 = *(const u16x8*)(B0ptr + 64);
  uB1 = *(const u16x8*)(B1ptr + 64);
  __syncthreads();
  int cur = 0;
  for (int kb = 0; kb < 4096; kb += 64){
    if (kb + 64 < 4096){
      int kk = kb + 64 + cA*4;
      f32x4 av = *(const f32x4*)(AC + kk);
      f32x4 dv = *(const f32x4*)(DC + kk);
      u16x4 o;
      o[0] = f2b(fmaxf(0.f, av.x*bf(uA[0]) + dv.x));
      o[1] = f2b(fmaxf(0.f, av.y*bf(uA[1]) + dv.y));
      o[2] = f2b(fmaxf(0.f, av.z*bf(uA[2]) + dv.z));
      o[3] = f2b(fmaxf(0.f, av.w*bf(uA[3]) + dv.w));
      *(u16x4*)&Al[cur^1][rA*72 + cA*4] = o;
      *(u16x8*)&Bl[cur^1][nB*72 + cB*8]        = uB0;
      *(u16x8*)&Bl[cur^1][(nB + 32)*72 + cB*8] = uB1;
      if (kb + 128 < 4096){
        uA  = *(const u16x4*)(Aptr + kb + 128);
        uB0 = *(const u16x8*)(B0ptr + kb + 128);
        uB1 = *(const u16x8*)(B1ptr + kb + 128);
      }
    }
    #pragma unroll
    for (int ks = 0; ks < 2; ++ks){
      s16x8 af  = *(const s16x8*)&Al[cur][((l & 15))*72 + ks*32 + (l >> 4)*8];
      s16x8 bf0 = *(const s16x8*)&Bl[cur][(w*16 + (l & 15))*72 + ks*32 + (l >> 4)*8];
      acc0 = __builtin_amdgcn_mfma_f32_16x16x32_bf16(af, bf0, acc0, 0, 0, 0);
    }
    __syncthreads();
    cur ^= 1;
  }
  int col0 = w*16 + (l & 15);
  float lb0 = lb[col0];
  float s0 = 0.f, q0 = 0.f;
  if (t < 64){ cps[t] = 0.f; cpq[t] = 0.f; }
  __syncthreads();
  #pragma unroll
  for (int r = 0; r < 4; ++r){
    int row = rowbase + (l >> 4)*4 + r;
    float y0 = acc0[r] + lb0;
    yw[(size_t)row*64 + col0] = y0;
    s0 += y0; q0 += y0*y0;
  }
  atomicAdd(&cps[col0], s0); atomicAdd(&cpq[col0], q0);
  __syncthreads();
  if (t < 64){
    PL[blockIdx.x*128 + t]      = cps[t];
    PL[blockIdx.x*128 + 64 + t] = cpq[t];
  }
}

// ---------------- k_redF (1024 blocks of PL) ----------------
__global__ __launch_bounds__(128) void k_redF(const float* PL, float* SL){
  int t = threadIdx.x;
  float s = 0.f;
  for (int b = 0; b < 1024; ++b) s += PL[b*128 + t];
  SL[t] = s;
}

// ---------------- k_final ----------------
__global__ __launch_bounds__(256) void k_final(const float* yw, const float* SL,
                                               const float* gl, const float* bl, float* out){
  int e = (blockIdx.x * 256 + threadIdx.x) * 4;
  int o = e & 63;
  f32x4 y = *(const f32x4*)(yw + e);
  f32x4 r;
  #pragma unroll
  for (int j = 0; j < 4; ++j){
    float m = SL[o+j] * (1.f/16384.f);
    float v = SL[64+o+j] * (1.f/16384.f) - m*m;
    float a = gl[o+j] * rsqrtf(v + EPSF);
    float d = bl[o+j] - m*a;
    r[j] = fmaxf(0.f, a*y[j] + d);
  }
  *(f32x4*)(out + 49152 + e) = r;
}

extern "C" void kernel_launch(void* const* d_in, const int* in_sizes, int n_in,
                              void* d_out, int out_size, void* d_ws, size_t ws_size,
                              hipStream_t stream){
  (void)in_sizes; (void)n_in; (void)out_size; (void)ws_size;
  const float* xyz    = (const float*)d_in[0];
  const float* points = (const float*)d_in[1];
  const float* lc     = (const float*)d_in[2];
  const int*   nbrl   = (const int*)d_in[3];
  const int*   didx   = (const int*)d_in[4];
  const float* w0 = (const float*)d_in[5];
  const float* b0 = (const float*)d_in[6];
  const float* g0 = (const float*)d_in[7];
  const float* be0= (const float*)d_in[8];
  const float* w1 = (const float*)d_in[9];
  const float* b1 = (const float*)d_in[10];
  const float* g1 = (const float*)d_in[11];
  const float* be1= (const float*)d_in[12];
  const float* w2 = (const float*)d_in[13];
  const float* b2 = (const float*)d_in[14];
  const float* g2 = (const float*)d_in[15];
  const float* be2= (const float*)d_in[16];
  const float* gc = (const float*)d_in[17];
  const float* bc = (const float*)d_in[18];
  const float* lw = (const float*)d_in[19];
  const float* lb = (const float*)d_in[20];
  const float* gl = (const float*)d_in[21];
  const float* bl = (const float*)d_in[22];
  float* out = (float*)d_out;
  char* ws = (char*)d_ws;

  // small region (< 2 MB)
  float* F   = (float*)ws;           // 1536
  float* SL  = F + 1536;             // 128
  float* AC  = SL + 128;             // 4096
  float* DC  = AC + 4096;            // 4096
  float* PA  = DC + 4096;            // 32768
  float* PB1 = PA + 32768;           // 139264
  float* PB2 = PB1 + 139264;         // 139264
  float* PL  = PB2 + 139264;         // 131072
  u16*  w1Bg = (u16*)(PL + 131072);  // 512 u16
  u16*  w2Bg = w1Bg + 512;           // 2048 u16
  u16*  lwbt = (u16*)(ws + 2097152);                 // 512 KB (permuted), @2MB
  float* PC  = (float*)(ws + 4194304);               // 32 MB (1024 x 8192), @4MB
  float* yw  = (float*)(ws + 4194304);               // 4 MB, ALIASES PC (disjoint lifetime)
  u16*  npw  = (u16*)(ws + 37748736);                // 128 MB bf16 (transposed), @36MB
  u16*  ptsw = (u16*)(ws + 171966464);               // 8 MB bf16, @164MB (end 172MB)

  k_init  <<<1152,  256, 0, stream>>>(xyz, didx, out, lw, lwbt, points, ptsw, lc, PA);
  k_red0  <<<1,     256, 0, stream>>>(PA, w0, b0, g0, be0, F);
  k_statG1<<<SGBLK, 256, 0, stream>>>(lc, F, PB1);
  k_red1  <<<1,     256, 0, stream>>>(PB1, w1, b1, g1, be1, F, w1Bg);
  k_statG2<<<SGBLK, 256, 0, stream>>>(lc, F, w1Bg, PB2);
  k_red2  <<<1,     256, 0, stream>>>(PB2, w2, b2, g2, be2, F, w2Bg);
  k_main  <<<1024,  256, 0, stream>>>(lc, nbrl, ptsw, F, w1Bg, w2Bg, npw, PC);
  k_finC  <<<256,   256, 0, stream>>>(PC, gc, bc, AC, DC);
  k_linear<<<1024,  256, 0, stream>>>(npw, AC, DC, lwbt, lb, yw, PL);
  k_redF  <<<1,     128, 0, stream>>>(PL, SL);
  k_final <<<1024,  256, 0, stream>>>(yw, SL, gl, bl, out);
}

// Round 24
// 228.487 us; speedup vs baseline: 1.1590x; 1.0911x over previous
//
#include <hip/hip_runtime.h>
#include <hip/hip_bf16.h>

#define BB 16
#define NN 4096
#define NPOINTS 1024
#define KK 32
#define NPTS (BB*NPOINTS)        // 16384
#define NWN  (BB*NPOINTS*KK)     // 524288
#define EPSF 1e-5f
#define SGBLK 512
#define SGIT  4

typedef unsigned short u16;
typedef u16  u16x8 __attribute__((ext_vector_type(8)));
typedef u16  u16x4 __attribute__((ext_vector_type(4)));
typedef short s16x8 __attribute__((ext_vector_type(8)));
typedef float f32x4 __attribute__((ext_vector_type(4)));
typedef float f32x4u __attribute__((ext_vector_type(4), aligned(4)));

__device__ __forceinline__ float bf(u16 u){
  union { unsigned int i; float f; } v; v.i = ((unsigned int)u) << 16; return v.f;
}
__device__ __forceinline__ u16 f2b(float f){
  __hip_bfloat16 h = __float2bfloat16(f);
  union { __hip_bfloat16 hh; u16 u; } v; v.hh = h; return v.u;
}

// F layout (folded weights): [0..47] w0f, [48..63] b0f, [64..319] w1f,
// [320..335] b1f, [336..1359] w2f, [1360..1423] b2f
// npw: transposed position space q = o*64 + i  (original channel ch = i*64 + o)
// ptsw[B*N][64] bf16: pre-converted concat(points, xyz) rows
// Gr LDS: K-major, 16B k-blocks XOR-swizzled by (ch>>3)&3
// k_main (round 24): 16 points/block (grid 1024), fused stat partials -> PC[1024][8192],
//   PLUS register prefetch of next group's gather (nbr/ptsw/lc) issued before barrier(1)
//   so the dependent-load chain hides under H1/W/final MFMA phases (round-23 fix).
// yw aliases the PC region (PC dead after k_finC, yw born at k_linear).
// NOTE (round 15): device atomics bypass L2 on MI355X -> keep stats streaming.

// ---------------- k_init: newxyz (0..63) + lwbt (64..127) + ptsw (128..639) + lc moments (640..1151) ----------------
__global__ __launch_bounds__(256) void k_init(const float* xyz, const int* didx, float* out,
                                              const float* lw, u16* lwbt,
                                              const float* points, u16* ptsw,
                                              const float* lc, float* PA){
  int t = threadIdx.x;
  if (blockIdx.x < 64){
    int p = blockIdx.x * 256 + t;
    int b = p >> 10;
    int idx = didx[p];
    const float* src = xyz + ((size_t)(b * NN + idx)) * 3;
    float* dst = out + (size_t)p * 3;
    dst[0] = src[0]; dst[1] = src[1]; dst[2] = src[2];
  } else if (blockIdx.x < 128){
    __shared__ float T[64][65];
    int ib = blockIdx.x - 64;
    int kb = ib * 64;
    {
      int k = t >> 2, c4 = t & 3;
      #pragma unroll
      for (int j = 0; j < 4; ++j)
        *(f32x4*)&T[k][c4*16 + j*4] = *(const f32x4*)(lw + (size_t)(kb + k)*64 + c4*16 + j*4);
    }
    __syncthreads();
    {
      int n = t >> 2, k4 = t & 3;
      #pragma unroll
      for (int j = 0; j < 16; ++j){
        int k = k4*16 + j;
        lwbt[(size_t)n*4096 + k*64 + ib] = f2b(T[k][n]);
      }
    }
  } else if (blockIdx.x < 640){
    int gid0 = (blockIdx.x - 128) * 256 + t;
    #pragma unroll
    for (int rep = 0; rep < 4; ++rep){
      int idx = gid0 + rep * 131072;
      int row = idx >> 3, c8 = idx & 7;
      const float* prow = points + (size_t)row * 61;
      u16x8 g;
      if (c8 < 7){
        f32x4 lo = *(const f32x4u*)(prow + c8*8);
        f32x4 hi = *(const f32x4u*)(prow + c8*8 + 4);
        g[0]=f2b(lo.x); g[1]=f2b(lo.y); g[2]=f2b(lo.z); g[3]=f2b(lo.w);
        g[4]=f2b(hi.x); g[5]=f2b(hi.y); g[6]=f2b(hi.z); g[7]=f2b(hi.w);
      } else {
        const float* xr = xyz + (size_t)row * 3;
        f32x4 lo = *(const f32x4u*)(prow + 56);
        g[0]=f2b(lo.x); g[1]=f2b(lo.y); g[2]=f2b(lo.z); g[3]=f2b(lo.w);
        g[4]=f2b(prow[60]);
        g[5]=f2b(xr[0]); g[6]=f2b(xr[1]); g[7]=f2b(xr[2]);
      }
      *(u16x8*)(ptsw + (size_t)row*64 + c8*8) = g;
    }
  } else {
    int bid = blockIdx.x - 640;
    float a[9];
    #pragma unroll
    for (int r = 0; r < 9; ++r) a[r] = 0.f;
    size_t base = (size_t)bid * 1024 + t;
    for (int ip = 0; ip < 4; ++ip){
      size_t p = base + (size_t)ip * 256;
      float x0 = lc[p*3], x1 = lc[p*3+1], x2 = lc[p*3+2];
      a[0]+=x0; a[1]+=x1; a[2]+=x2;
      a[3]+=x0*x0; a[4]+=x0*x1; a[5]+=x0*x2;
      a[6]+=x1*x1; a[7]+=x1*x2; a[8]+=x2*x2;
    }
    #pragma unroll
    for (int m = 1; m < 64; m <<= 1){
      #pragma unroll
      for (int r = 0; r < 9; ++r) a[r] += __shfl_xor(a[r], m);
    }
    if ((t & 63) == 0){
      float* dst = PA + (size_t)(bid*4 + (t>>6)) * 16;
      f32x4 v0 = {a[0],a[1],a[2],a[3]}, v1 = {a[4],a[5],a[6],a[7]}, v2 = {a[8],0.f,0.f,0.f};
      *(f32x4*)dst = v0; *(f32x4*)(dst+4) = v1; *(f32x4*)(dst+8) = v2;
    }
  }
}

// ---------------- k_red0 ----------------
__global__ __launch_bounds__(256) void k_red0(const float* PA, const float* w0, const float* b0,
                                              const float* g0, const float* be0, float* F){
  __shared__ float ms[12];
  __shared__ float a0sh[16];
  int t = threadIdx.x;
  if (t < 12){
    float s0=0,s1=0,s2=0,s3=0;
    const float* p = PA + t;
    for (int r = 0; r < 2048; r += 4){
      s0 += p[(size_t)(r+0)*16]; s1 += p[(size_t)(r+1)*16];
      s2 += p[(size_t)(r+2)*16]; s3 += p[(size_t)(r+3)*16];
    }
    ms[t] = (s0+s1)+(s2+s3);
  }
  __syncthreads();
  if (t < 16){
    float wx = w0[t*3], wy = w0[t*3+1], wz = w0[t*3+2], bb = b0[t];
    float lin = wx*ms[0] + wy*ms[1] + wz*ms[2];
    float quad = wx*wx*ms[3] + wy*wy*ms[6] + wz*wz*ms[8]
               + 2.f*(wx*wy*ms[4] + wx*wz*ms[5] + wy*wz*ms[7]);
    float S = lin + (float)NWN * bb;
    float Q = quad + 2.f*bb*lin + (float)NWN*bb*bb;
    float m = S * (1.f/NWN);
    float v = Q * (1.f/NWN) - m*m;
    float a = g0[t] * rsqrtf(v + EPSF);
    float d = be0[t] - m*a;
    a0sh[t] = a;
    F[48+t] = a*bb + d;
  }
  __syncthreads();
  if (t < 48) F[t] = a0sh[t/3] * w0[t];
}

// ---------------- k_statG1: h0 Gram (VALU h0, MFMA Gram) ----------------
__global__ __launch_bounds__(256) void k_statG1(const float* lc, const float* F, float* PB){
  __shared__ f32x4 w0p[16];
  __shared__ __align__(16) u16 Ht[4][16*72];
  __shared__ float GS[4][16][17];
  __shared__ float SHs[4][16];
  int t = threadIdx.x;
  int w = t >> 6, l = t & 63;
  if (t < 16){
    f32x4 wv = {F[t*3], F[t*3+1], F[t*3+2], F[48+t]};
    w0p[t] = wv;
  }
  __syncthreads();
  f32x4 acc = {0.f,0.f,0.f,0.f};
  float sh[16];
  #pragma unroll
  for (int r = 0; r < 16; ++r) sh[r] = 0.f;
  u16* Hw = &Ht[w][0];
  for (int it = 0; it < SGIT; ++it){
    size_t p = (size_t)blockIdx.x * (SGIT*256) + (size_t)it*256 + w*64 + l;
    float x0 = lc[p*3], x1 = lc[p*3+1], x2 = lc[p*3+2];
    float h[16];
    #pragma unroll
    for (int oc = 0; oc < 16; ++oc){
      f32x4 wv = w0p[oc];
      h[oc] = fmaxf(0.f, wv.x*x0 + wv.y*x1 + wv.z*x2 + wv.w);
      sh[oc] += h[oc];
    }
    #pragma unroll
    for (int c = 0; c < 16; ++c) Hw[c*72 + l] = f2b(h[c]);
    __syncthreads();
    #pragma unroll
    for (int tt = 0; tt < 2; ++tt){
      s16x8 af = *(const s16x8*)&Hw[(l & 15)*72 + tt*32 + (l >> 4)*8];
      acc = __builtin_amdgcn_mfma_f32_16x16x32_bf16(af, af, acc, 0, 0, 0);
    }
    __syncthreads();
  }
  #pragma unroll
  for (int r = 0; r < 4; ++r)
    GS[w][(l>>4)*4 + r][l & 15] = acc[r];
  #pragma unroll
  for (int m = 1; m < 64; m <<= 1){
    #pragma unroll
    for (int r = 0; r < 16; ++r) sh[r] += __shfl_xor(sh[r], m);
  }
  if (l == 0){
    #pragma unroll
    for (int r = 0; r < 16; ++r) SHs[w][r] = sh[r];
  }
  __syncthreads();
  {
    int i = t >> 4, j = t & 15;
    float g = GS[0][i][j] + GS[1][i][j] + GS[2][i][j] + GS[3][i][j];
    PB[(size_t)blockIdx.x*272 + t] = g;
    if (t < 16)
      PB[(size_t)blockIdx.x*272 + 256 + t] = SHs[0][t]+SHs[1][t]+SHs[2][t]+SHs[3][t];
  }
}

// ---------------- k_statG2: h1 Gram (MFMA h1 via w1Bg + MFMA Gram) ----------------
__global__ __launch_bounds__(256) void k_statG2(const float* lc, const float* F,
                                                const u16* w1Bg, float* PB){
  __shared__ f32x4 w0p[16];
  __shared__ __align__(16) u16 Ht0[4][64*40];
  __shared__ __align__(16) u16 Ht1[4][16*72];
  __shared__ float GS[4][16][17];
  __shared__ float SHs[4][16];
  int t = threadIdx.x;
  int w = t >> 6, l = t & 63;
  if (t < 16){
    f32x4 wv = {F[t*3], F[t*3+1], F[t*3+2], F[48+t]};
    w0p[t] = wv;
  }
  s16x8 w1B = *(const s16x8*)&w1Bg[l*8];
  float b1f = F[320 + (l & 15)];
  u16* H0w = &Ht0[w][0];
  u16* H1w = &Ht1[w][0];
  {
    u16x8 z8 = {0,0,0,0,0,0,0,0};
    *(u16x8*)&H0w[l*40 + 16] = z8;
    *(u16x8*)&H0w[l*40 + 24] = z8;
  }
  __syncthreads();
  f32x4 acc = {0.f,0.f,0.f,0.f};
  float shloc = 0.f;
  for (int it = 0; it < SGIT; ++it){
    size_t p = (size_t)blockIdx.x * (SGIT*256) + (size_t)it*256 + w*64 + l;
    float x0 = lc[p*3], x1 = lc[p*3+1], x2 = lc[p*3+2];
    u16x8 p0, p1;
    #pragma unroll
    for (int oc = 0; oc < 8; ++oc){
      f32x4 wv = w0p[oc];
      p0[oc] = f2b(fmaxf(0.f, wv.x*x0 + wv.y*x1 + wv.z*x2 + wv.w));
    }
    #pragma unroll
    for (int oc = 0; oc < 8; ++oc){
      f32x4 wv = w0p[8+oc];
      p1[oc] = f2b(fmaxf(0.f, wv.x*x0 + wv.y*x1 + wv.z*x2 + wv.w));
    }
    *(u16x8*)&H0w[l*40]     = p0;
    *(u16x8*)&H0w[l*40 + 8] = p1;
    __syncthreads();
    #pragma unroll
    for (int mt = 0; mt < 4; ++mt){
      s16x8 af = *(const s16x8*)&H0w[(mt*16 + (l & 15))*40 + (l >> 4)*8];
      f32x4 c = {b1f, b1f, b1f, b1f};
      c = __builtin_amdgcn_mfma_f32_16x16x32_bf16(af, w1B, c, 0, 0, 0);
      #pragma unroll
      for (int r = 0; r < 4; ++r){
        float v = fmaxf(0.f, c[r]);
        shloc += v;
        H1w[(l & 15)*72 + mt*16 + (l >> 4)*4 + r] = f2b(v);
      }
    }
    __syncthreads();
    #pragma unroll
    for (int tt = 0; tt < 2; ++tt){
      s16x8 afg = *(const s16x8*)&H1w[(l & 15)*72 + tt*32 + (l >> 4)*8];
      acc = __builtin_amdgcn_mfma_f32_16x16x32_bf16(afg, afg, acc, 0, 0, 0);
    }
    __syncthreads();
  }
  #pragma unroll
  for (int r = 0; r < 4; ++r)
    GS[w][(l>>4)*4 + r][l & 15] = acc[r];
  shloc += __shfl_xor(shloc, 16);
  shloc += __shfl_xor(shloc, 32);
  if (l < 16) SHs[w][l] = shloc;
  __syncthreads();
  {
    int i = t >> 4, j = t & 15;
    float g = GS[0][i][j] + GS[1][i][j] + GS[2][i][j] + GS[3][i][j];
    PB[(size_t)blockIdx.x*272 + t] = g;
    if (t < 16)
      PB[(size_t)blockIdx.x*272 + 256 + t] = SHs[0][t]+SHs[1][t]+SHs[2][t]+SHs[3][t];
  }
}

// ---------------- k_red1 ----------------
__global__ __launch_bounds__(256) void k_red1(const float* PB, const float* w1, const float* b1,
                                              const float* g1, const float* be1, float* F,
                                              u16* w1Bg){
  __shared__ float red[272];
  __shared__ float a1sh[16];
  int t = threadIdx.x;
  for (int e = t; e < 272; e += 256){
    float s = 0.f;
    for (int r = 0; r < SGBLK; ++r) s += PB[(size_t)r*272 + e];
    red[e] = s;
  }
  __syncthreads();
  if (t < 16){
    float wv[16];
    #pragma unroll
    for (int ic = 0; ic < 16; ++ic) wv[ic] = w1[t*16+ic];
    float lin = 0.f;
    #pragma unroll
    for (int ic = 0; ic < 16; ++ic) lin += wv[ic]*red[256+ic];
    float quad = 0.f;
    for (int i = 0; i < 16; ++i){
      float ri = 0.f;
      #pragma unroll
      for (int j = 0; j < 16; ++j) ri += wv[j]*red[i*16+j];
      quad += wv[i]*ri;
    }
    float bb = b1[t];
    float S = lin + (float)NWN * bb;
    float Q = quad + 2.f*bb*lin + (float)NWN*bb*bb;
    float m = S * (1.f/NWN);
    float v = Q * (1.f/NWN) - m*m;
    float a = g1[t] * rsqrtf(v + EPSF);
    float d = be1[t] - m*a;
    a1sh[t] = a;
    F[320+t] = a*bb + d;
  }
  __syncthreads();
  F[64 + t] = a1sh[t >> 4] * w1[t];
  if (t < 64){
    int oc = t & 15, icb = (t >> 4) * 8;
    u16x8 fr;
    #pragma unroll
    for (int j = 0; j < 8; ++j){
      int ic = icb + j;
      fr[j] = (ic < 16) ? f2b(a1sh[oc] * w1[oc*16 + ic]) : (u16)0;
    }
    *(u16x8*)&w1Bg[t*8] = fr;
  }
}

// ---------------- k_red2 ----------------
__global__ __launch_bounds__(256) void k_red2(const float* PB, const float* w2, const float* b2,
                                              const float* g2, const float* be2, float* F,
                                              u16* w2Bg){
  __shared__ float red[272];
  __shared__ float a2sh[64];
  int t = threadIdx.x;
  for (int e = t; e < 272; e += 256){
    float s = 0.f;
    for (int r = 0; r < SGBLK; ++r) s += PB[(size_t)r*272 + e];
    red[e] = s;
  }
  __syncthreads();
  if (t < 64){
    float wv[16];
    #pragma unroll
    for (int ic = 0; ic < 16; ++ic) wv[ic] = w2[t*16+ic];
    float lin = 0.f;
    #pragma unroll
    for (int ic = 0; ic < 16; ++ic) lin += wv[ic]*red[256+ic];
    float quad = 0.f;
    for (int i = 0; i < 16; ++i){
      float ri = 0.f;
      #pragma unroll
      for (int j = 0; j < 16; ++j) ri += wv[j]*red[i*16+j];
      quad += wv[i]*ri;
    }
    float bb = b2[t];
    float S = lin + (float)NWN * bb;
    float Q = quad + 2.f*bb*lin + (float)NWN*bb*bb;
    float m = S * (1.f/NWN);
    float v = Q * (1.f/NWN) - m*m;
    float a = g2[t] * rsqrtf(v + EPSF);
    float d = be2[t] - m*a;
    a2sh[t] = a;
    F[1360+t] = a*bb + d;
  }
  __syncthreads();
  for (int i = t; i < 1024; i += 256) F[336+i] = a2sh[i >> 4] * w2[i];
  {
    int ot = t >> 6, lane = t & 63;
    int oc = ot*16 + (lane & 15), icb = ((lane >> 4)) * 8;
    u16x8 fr;
    #pragma unroll
    for (int j = 0; j < 8; ++j){
      int ic = icb + j;
      fr[j] = (ic < 16) ? f2b(a2sh[oc] * w2[oc*16 + ic]) : (u16)0;
    }
    *(u16x8*)&w2Bg[t*8] = fr;
  }
}

// ---------------- K5: 16 points/block + fused stats + register gather-prefetch ----------------
__global__ __launch_bounds__(256) void k_main(const float* lcg, const int* nbrg,
    const u16* ptsw, const float* F,
    const u16* w1Bg, const u16* w2Bg,
    u16* npw, float* PC){
  __shared__ __align__(16) u16 Gr[2][64*40];        // swizzled K-major per point
  __shared__ __align__(16) u16 WrBuf[2][64*40];     // W output; [0..1279] doubles as H0bf
  __shared__ __align__(16) u16 H1bf[2][32*40];
  int t = threadIdx.x;
  int w = t >> 6, l = t & 63;
  int pbase = blockIdx.x * 16;
  s16x8 w1B  = *(const s16x8*)&w1Bg[l*8];
  s16x8 w2B0 = *(const s16x8*)&w2Bg[(0*64 + l)*8];
  s16x8 w2B1 = *(const s16x8*)&w2Bg[(1*64 + l)*8];
  s16x8 w2B2 = *(const s16x8*)&w2Bg[(2*64 + l)*8];
  s16x8 w2B3 = *(const s16x8*)&w2Bg[(3*64 + l)*8];
  float b1f  = F[320 + (l & 15)];
  float b2f0 = F[1360 +  0 + (l & 15)];
  float b2f1 = F[1360 + 16 + (l & 15)];
  float b2f2 = F[1360 + 32 + (l & 15)];
  float b2f3 = F[1360 + 48 + (l & 15)];
  int oc0 = (t & 7) * 2;
  f32x4 w0a = {F[oc0*3], F[oc0*3+1], F[oc0*3+2], F[48+oc0]};
  f32x4 w0b = {F[oc0*3+3], F[oc0*3+4], F[oc0*3+5], F[48+oc0+1]};
  // thread-geometry constants
  int kg = w*8 + (l >> 3), c8 = l & 7;
  int kphys = ((w ^ (c8 & 3)) << 3) + (l >> 3);
  int kH = t >> 3, cpad = 16 + (t & 7)*2;
  // H1bf pads (columns 16..31 never written by H1 phase -> survive the loop)
  {
    *(unsigned int*)&H1bf[0][kH*40 + cpad] = 0u;
    *(unsigned int*)&H1bf[1][kH*40 + cpad] = 0u;
  }
  // per-thread channel-stat accumulators (positions are point-invariant)
  float sacc[16], qacc[16];
  #pragma unroll
  for (int j = 0; j < 16; ++j){ sacc[j] = 0.f; qacc[j] = 0.f; }
  // prologue prefetch: group 0's gather + lc
  u16x8 gv0, gv1;
  float lx00, lx01, lx02, lx10, lx11, lx12;
  {
    int point = pbase;
    int bbp = point >> 10;
    int n = nbrg[(size_t)point*32 + kg];
    gv0 = *(const u16x8*)(ptsw + (size_t)(bbp * NN + n)*64 + c8*8);
    const float* xp = lcg + (size_t)point*96 + kH*3;
    lx00 = xp[0]; lx01 = xp[1]; lx02 = xp[2];
    int point1 = pbase + 1;
    int bbp1 = point1 >> 10;
    int n1 = nbrg[(size_t)point1*32 + kg];
    gv1 = *(const u16x8*)(ptsw + (size_t)(bbp1 * NN + n1)*64 + c8*8);
    const float* xp1 = lcg + (size_t)point1*96 + kH*3;
    lx10 = xp1[0]; lx11 = xp1[1]; lx12 = xp1[2];
  }
  __syncthreads();   // H1bf pads visible before first H1 phase

  for (int g = 0; g < 8; ++g){
    int p0 = pbase + g*2;
    // write prefetched gather -> Gr swizzled K-major
    {
      #pragma unroll
      for (int j = 0; j < 8; ++j)
        Gr[0][(c8*8 + j)*40 + kphys] = gv0[j];
      #pragma unroll
      for (int j = 0; j < 8; ++j)
        Gr[1][(c8*8 + j)*40 + kphys] = gv1[j];
    }
    // H0 both points from prefetched lc + re-zero H0 pads
    {
      WrBuf[0][kH*40 + oc0]     = f2b(fmaxf(0.f, w0a.x*lx00 + w0a.y*lx01 + w0a.z*lx02 + w0a.w));
      WrBuf[0][kH*40 + oc0 + 1] = f2b(fmaxf(0.f, w0b.x*lx00 + w0b.y*lx01 + w0b.z*lx02 + w0b.w));
      *(unsigned int*)&WrBuf[0][kH*40 + cpad] = 0u;
      WrBuf[1][kH*40 + oc0]     = f2b(fmaxf(0.f, w0a.x*lx10 + w0a.y*lx11 + w0a.z*lx12 + w0a.w));
      WrBuf[1][kH*40 + oc0 + 1] = f2b(fmaxf(0.f, w0b.x*lx10 + w0b.y*lx11 + w0b.z*lx12 + w0b.w));
      *(unsigned int*)&WrBuf[1][kH*40 + cpad] = 0u;
    }
    // prefetch next group's gather + lc (latency hides under H1/W/final phases)
    if (g < 7){
      int pn0 = p0 + 2, pn1 = p0 + 3;
      int bn0 = pn0 >> 10, bn1 = pn1 >> 10;
      int n0 = nbrg[(size_t)pn0*32 + kg];
      int n1 = nbrg[(size_t)pn1*32 + kg];
      gv0 = *(const u16x8*)(ptsw + (size_t)(bn0 * NN + n0)*64 + c8*8);
      gv1 = *(const u16x8*)(ptsw + (size_t)(bn1 * NN + n1)*64 + c8*8);
      const float* xp0 = lcg + (size_t)pn0*96 + kH*3;
      lx00 = xp0[0]; lx01 = xp0[1]; lx02 = xp0[2];
      const float* xp1 = lcg + (size_t)pn1*96 + kH*3;
      lx10 = xp1[0]; lx11 = xp1[1]; lx12 = xp1[2];
    }
    __syncthreads();   // (1) H0(=WrBuf low) + pads + Gr ready
    // H1: wave w -> pt = w>>1, kt = w&1
    {
      int pt = w >> 1, kt = w & 1;
      s16x8 af = *(const s16x8*)&WrBuf[pt][(kt*16 + (l & 15))*40 + (l >> 4)*8];
      f32x4 acc = {b1f, b1f, b1f, b1f};
      acc = __builtin_amdgcn_mfma_f32_16x16x32_bf16(af, w1B, acc, 0, 0, 0);
      #pragma unroll
      for (int r = 0; r < 4; ++r)
        H1bf[pt][(kt*16 + (l >> 4)*4 + r)*40 + (l & 15)] = f2b(fmaxf(0.f, acc[r]));
    }
    __syncthreads();   // (2) H1bf ready; H0 region dead -> Wr may overwrite
    // W: wave w -> pt = w&1, kt = w>>1; 4 o-tiles
    {
      int pt = w & 1, kt = w >> 1;
      s16x8 af = *(const s16x8*)&H1bf[pt][(kt*16 + (l & 15))*40 + (l >> 4)*8];
      int kbase = kt*16 + (l >> 4)*4;
      f32x4 a0c = {b2f0,b2f0,b2f0,b2f0};
      a0c = __builtin_amdgcn_mfma_f32_16x16x32_bf16(af, w2B0, a0c, 0, 0, 0);
      u16x4 s0v; s0v[0]=f2b(fmaxf(0.f,a0c[0])); s0v[1]=f2b(fmaxf(0.f,a0c[1]));
      s0v[2]=f2b(fmaxf(0.f,a0c[2])); s0v[3]=f2b(fmaxf(0.f,a0c[3]));
      *(u16x4*)&WrBuf[pt][( 0 + (l & 15))*40 + kbase] = s0v;
      f32x4 a1c = {b2f1,b2f1,b2f1,b2f1};
      a1c = __builtin_amdgcn_mfma_f32_16x16x32_bf16(af, w2B1, a1c, 0, 0, 0);
      u16x4 s1v; s1v[0]=f2b(fmaxf(0.f,a1c[0])); s1v[1]=f2b(fmaxf(0.f,a1c[1]));
      s1v[2]=f2b(fmaxf(0.f,a1c[2])); s1v[3]=f2b(fmaxf(0.f,a1c[3]));
      *(u16x4*)&WrBuf[pt][(16 + (l & 15))*40 + kbase] = s1v;
      f32x4 a2c = {b2f2,b2f2,b2f2,b2f2};
      a2c = __builtin_amdgcn_mfma_f32_16x16x32_bf16(af, w2B2, a2c, 0, 0, 0);
      u16x4 s2v; s2v[0]=f2b(fmaxf(0.f,a2c[0])); s2v[1]=f2b(fmaxf(0.f,a2c[1]));
      s2v[2]=f2b(fmaxf(0.f,a2c[2])); s2v[3]=f2b(fmaxf(0.f,a2c[3]));
      *(u16x4*)&WrBuf[pt][(32 + (l & 15))*40 + kbase] = s2v;
      f32x4 a3c = {b2f3,b2f3,b2f3,b2f3};
      a3c = __builtin_amdgcn_mfma_f32_16x16x32_bf16(af, w2B3, a3c, 0, 0, 0);
      u16x4 s3v; s3v[0]=f2b(fmaxf(0.f,a3c[0])); s3v[1]=f2b(fmaxf(0.f,a3c[1]));
      s3v[2]=f2b(fmaxf(0.f,a3c[2])); s3v[3]=f2b(fmaxf(0.f,a3c[3]));
      *(u16x4*)&WrBuf[pt][(48 + (l & 15))*40 + kbase] = s3v;
    }
    __syncthreads();   // (3) Gr, Wr ready
    // np = G^T W: wave w owns o-tile w, both points; accumulate stats in regs
    {
      int li = l & 15, lkb = l >> 4, lr = (l >> 4) * 4;
      #pragma unroll
      for (int pt = 0; pt < 2; ++pt){
        s16x8 bfrag = *(const s16x8*)&WrBuf[pt][(w*16 + li)*40 + lkb*8];
        size_t obase = (size_t)(p0 + pt)*4096 + (size_t)(w*16 + li)*64 + lr;
        #pragma unroll
        for (int it = 0; it < 4; ++it){
          int ch = it*16 + li;
          int key = (ch >> 3) & 3;
          s16x8 afrag = *(const s16x8*)&Gr[pt][ch*40 + ((lkb ^ key) << 3)];
          f32x4 z = {0.f, 0.f, 0.f, 0.f};
          f32x4 d = __builtin_amdgcn_mfma_f32_16x16x32_bf16(afrag, bfrag, z, 0, 0, 0);
          u16x4 st;
          st[0] = f2b(d[0]); st[1] = f2b(d[1]); st[2] = f2b(d[2]); st[3] = f2b(d[3]);
          *(u16x4*)(npw + obase + it*16) = st;
          #pragma unroll
          for (int r = 0; r < 4; ++r){
            sacc[it*4 + r] += d[r];
            qacc[it*4 + r] += d[r]*d[r];
          }
        }
      }
    }
    __syncthreads();   // (0) final reads done before next iter's Gr/H0 overwrite
  }
  // write block channel-stat partials
  {
    int qb = (w*16 + (l & 15))*64 + (l >> 4)*4;
    float* dst = PC + (size_t)blockIdx.x * 8192;
    #pragma unroll
    for (int it = 0; it < 4; ++it){
      f32x4 sv = {sacc[it*4+0], sacc[it*4+1], sacc[it*4+2], sacc[it*4+3]};
      f32x4 qv = {qacc[it*4+0], qacc[it*4+1], qacc[it*4+2], qacc[it*4+3]};
      *(f32x4*)(dst + qb + it*16) = sv;
      *(f32x4*)(dst + 4096 + qb + it*16) = qv;
    }
  }
}

// ---------------- k_finC: reduce 1024 block partials + finalize (grid 256) ----------------
__global__ __launch_bounds__(256) void k_finC(const float* PC, const float* gc, const float* bc,
                                              float* AC, float* DC){
  __shared__ float shs[16][17], shq[16][17];
  int t = threadIdx.x;
  int ql = t & 15, rc = t >> 4;     // 16 qpos x 16 row-chunks
  int qpos = blockIdx.x * 16 + ql;
  float s = 0.f, q = 0.f;
  int r0 = rc * 64;
  #pragma unroll 4
  for (int r = r0; r < r0 + 64; ++r){
    s += PC[(size_t)r * 8192 + qpos];
    q += PC[(size_t)r * 8192 + 4096 + qpos];
  }
  shs[ql][rc] = s; shq[ql][rc] = q;
  __syncthreads();
  if (t < 16){
    float ss = 0.f, qq = 0.f;
    #pragma unroll
    for (int c = 0; c < 16; ++c){ ss += shs[t][c]; qq += shq[t][c]; }
    int qp = blockIdx.x * 16 + t;
    int ch = (qp & 63)*64 + (qp >> 6);
    float m = ss * (1.f/16384.f);
    float v = qq * (1.f/16384.f) - m*m;
    float a = gc[ch] * rsqrtf(v + EPSF);
    AC[qp] = a; DC[qp] = bc[ch] - m*a;
  }
}

// ---------------- k_linear: 16 rows/block, grid 1024, double-buffered LDS ----------------
__global__ __launch_bounds__(256) void k_linear(const u16* npw, const float* AC, const float* DC,
                                                const u16* lwbt, const float* lb, float* yw,
                                                float* PL){
  __shared__ u16 Al[2][16*72];
  __shared__ u16 Bl[2][64*72];
  __shared__ float cps[64], cpq[64];
  int t = threadIdx.x;
  int w = t >> 6, l = t & 63;
  int rowbase = blockIdx.x * 16;
  int rA = t >> 4, cA = t & 15;
  int nB = t >> 3, cB = t & 7;
  const u16* Aptr  = npw  + (size_t)(rowbase + rA)*4096 + cA*4;
  const u16* B0ptr = lwbt + (size_t)nB*4096 + cB*8;
  const u16* B1ptr = lwbt + (size_t)(nB + 32)*4096 + cB*8;
  f32x4 acc0 = {0.f,0.f,0.f,0.f};
  u16x4 uA  = *(const u16x4*)(Aptr);
  u16x8 uB0 = *(const u16x8*)(B0ptr);
  u16x8 uB1 = *(const u16x8*)(B1ptr);
  {
    int kk = cA*4;
    f32x4 av = *(const f32x4*)(AC + kk);
    f32x4 dv = *(const f32x4*)(DC + kk);
    u16x4 o;
    o[0] = f2b(fmaxf(0.f, av.x*bf(uA[0]) + dv.x));
    o[1] = f2b(fmaxf(0.f, av.y*bf(uA[1]) + dv.y));
    o[2] = f2b(fmaxf(0.f, av.z*bf(uA[2]) + dv.z));
    o[3] = f2b(fmaxf(0.f, av.w*bf(uA[3]) + dv.w));
    *(u16x4*)&Al[0][rA*72 + cA*4] = o;
    *(u16x8*)&Bl[0][nB*72 + cB*8]        = uB0;
    *(u16x8*)&Bl[0][(nB + 32)*72 + cB*8] = uB1;
  }
  uA  = *(const u16x4*)(Aptr + 64);
  uB0 = *(const u16x8*)(B0ptr + 64);
  uB1 = *(const u16x8*)(B1ptr + 64);
  __syncthreads();
  int cur = 0;
  for (int kb = 0; kb < 4096; kb += 64){
    if (kb + 64 < 4096){
      int kk = kb + 64 + cA*4;
      f32x4 av = *(const f32x4*)(AC + kk);
      f32x4 dv = *(const f32x4*)(DC + kk);
      u16x4 o;
      o[0] = f2b(fmaxf(0.f, av.x*bf(uA[0]) + dv.x));
      o[1] = f2b(fmaxf(0.f, av.y*bf(uA[1]) + dv.y));
      o[2] = f2b(fmaxf(0.f, av.z*bf(uA[2]) + dv.z));
      o[3] = f2b(fmaxf(0.f, av.w*bf(uA[3]) + dv.w));
      *(u16x4*)&Al[cur^1][rA*72 + cA*4] = o;
      *(u16x8*)&Bl[cur^1][nB*72 + cB*8]        = uB0;
      *(u16x8*)&Bl[cur^1][(nB + 32)*72 + cB*8] = uB1;
      if (kb + 128 < 4096){
        uA  = *(const u16x4*)(Aptr + kb + 128);
        uB0 = *(const u16x8*)(B0ptr + kb + 128);
        uB1 = *(const u16x8*)(B1ptr + kb + 128);
      }
    }
    #pragma unroll
    for (int ks = 0; ks < 2; ++ks){
      s16x8 af  = *(const s16x8*)&Al[cur][((l & 15))*72 + ks*32 + (l >> 4)*8];
      s16x8 bf0 = *(const s16x8*)&Bl[cur][(w*16 + (l & 15))*72 + ks*32 + (l >> 4)*8];
      acc0 = __builtin_amdgcn_mfma_f32_16x16x32_bf16(af, bf0, acc0, 0, 0, 0);
    }
    __syncthreads();
    cur ^= 1;
  }
  int col0 = w*16 + (l & 15);
  float lb0 = lb[col0];
  float s0 = 0.f, q0 = 0.f;
  if (t < 64){ cps[t] = 0.f; cpq[t] = 0.f; }
  __syncthreads();
  #pragma unroll
  for (int r = 0; r < 4; ++r){
    int row = rowbase + (l >> 4)*4 + r;
    float y0 = acc0[r] + lb0;
    yw[(size_t)row*64 + col0] = y0;
    s0 += y0; q0 += y0*y0;
  }
  atomicAdd(&cps[col0], s0); atomicAdd(&cpq[col0], q0);
  __syncthreads();
  if (t < 64){
    PL[blockIdx.x*128 + t]      = cps[t];
    PL[blockIdx.x*128 + 64 + t] = cpq[t];
  }
}

// ---------------- k_redF (1024 blocks of PL) ----------------
__global__ __launch_bounds__(128) void k_redF(const float* PL, float* SL){
  int t = threadIdx.x;
  float s = 0.f;
  for (int b = 0; b < 1024; ++b) s += PL[b*128 + t];
  SL[t] = s;
}

// ---------------- k_final ----------------
__global__ __launch_bounds__(256) void k_final(const float* yw, const float* SL,
                                               const float* gl, const float* bl, float* out){
  int e = (blockIdx.x * 256 + threadIdx.x) * 4;
  int o = e & 63;
  f32x4 y = *(const f32x4*)(yw + e);
  f32x4 r;
  #pragma unroll
  for (int j = 0; j < 4; ++j){
    float m = SL[o+j] * (1.f/16384.f);
    float v = SL[64+o+j] * (1.f/16384.f) - m*m;
    float a = gl[o+j] * rsqrtf(v + EPSF);
    float d = bl[o+j] - m*a;
    r[j] = fmaxf(0.f, a*y[j] + d);
  }
  *(f32x4*)(out + 49152 + e) = r;
}

extern "C" void kernel_launch(void* const* d_in, const int* in_sizes, int n_in,
                              void* d_out, int out_size, void* d_ws, size_t ws_size,
                              hipStream_t stream){
  (void)in_sizes; (void)n_in; (void)out_size; (void)ws_size;
  const float* xyz    = (const float*)d_in[0];
  const float* points = (const float*)d_in[1];
  const float* lc     = (const float*)d_in[2];
  const int*   nbrl   = (const int*)d_in[3];
  const int*   didx   = (const int*)d_in[4];
  const float* w0 = (const float*)d_in[5];
  const float* b0 = (const float*)d_in[6];
  const float* g0 = (const float*)d_in[7];
  const float* be0= (const float*)d_in[8];
  const float* w1 = (const float*)d_in[9];
  const float* b1 = (const float*)d_in[10];
  const float* g1 = (const float*)d_in[11];
  const float* be1= (const float*)d_in[12];
  const float* w2 = (const float*)d_in[13];
  const float* b2 = (const float*)d_in[14];
  const float* g2 = (const float*)d_in[15];
  const float* be2= (const float*)d_in[16];
  const float* gc = (const float*)d_in[17];
  const float* bc = (const float*)d_in[18];
  const float* lw = (const float*)d_in[19];
  const float* lb = (const float*)d_in[20];
  const float* gl = (const float*)d_in[21];
  const float* bl = (const float*)d_in[22];
  float* out = (float*)d_out;
  char* ws = (char*)d_ws;

  // small region (< 2 MB)
  float* F   = (float*)ws;           // 1536
  float* SL  = F + 1536;             // 128
  float* AC  = SL + 128;             // 4096
  float* DC  = AC + 4096;            // 4096
  float* PA  = DC + 4096;            // 32768
  float* PB1 = PA + 32768;           // 139264
  float* PB2 = PB1 + 139264;         // 139264
  float* PL  = PB2 + 139264;         // 131072
  u16*  w1Bg = (u16*)(PL + 131072);  // 512 u16
  u16*  w2Bg = w1Bg + 512;           // 2048 u16
  u16*  lwbt = (u16*)(ws + 2097152);                 // 512 KB (permuted), @2MB
  float* PC  = (float*)(ws + 4194304);               // 32 MB (1024 x 8192), @4MB
  float* yw  = (float*)(ws + 4194304);               // 4 MB, ALIASES PC (disjoint lifetime)
  u16*  npw  = (u16*)(ws + 37748736);                // 128 MB bf16 (transposed), @36MB
  u16*  ptsw = (u16*)(ws + 171966464);               // 8 MB bf16, @164MB (end 172MB)

  k_init  <<<1152,  256, 0, stream>>>(xyz, didx, out, lw, lwbt, points, ptsw, lc, PA);
  k_red0  <<<1,     256, 0, stream>>>(PA, w0, b0, g0, be0, F);
  k_statG1<<<SGBLK, 256, 0, stream>>>(lc, F, PB1);
  k_red1  <<<1,     256, 0, stream>>>(PB1, w1, b1, g1, be1, F, w1Bg);
  k_statG2<<<SGBLK, 256, 0, stream>>>(lc, F, w1Bg, PB2);
  k_red2  <<<1,     256, 0, stream>>>(PB2, w2, b2, g2, be2, F, w2Bg);
  k_main  <<<1024,  256, 0, stream>>>(lc, nbrl, ptsw, F, w1Bg, w2Bg, npw, PC);
  k_finC  <<<256,   256, 0, stream>>>(PC, gc, bc, AC, DC);
  k_linear<<<1024,  256, 0, stream>>>(npw, AC, DC, lwbt, lb, yw, PL);
  k_redF  <<<1,     128, 0, stream>>>(PL, SL);
  k_final <<<1024,  256, 0, stream>>>(yw, SL, gl, bl, out);
}

// Round 25
// 226.779 us; speedup vs baseline: 1.1677x; 1.0075x over previous
//
#include <hip/hip_runtime.h>
#include <hip/hip_bf16.h>

#define BB 16
#define NN 4096
#define NPOINTS 1024
#define KK 32
#define NPTS (BB*NPOINTS)        // 16384
#define NWN  (BB*NPOINTS*KK)     // 524288
#define EPSF 1e-5f
#define SGBLK 512
#define SGIT  4

typedef unsigned short u16;
typedef u16  u16x8 __attribute__((ext_vector_type(8)));
typedef u16  u16x4 __attribute__((ext_vector_type(4)));
typedef short s16x8 __attribute__((ext_vector_type(8)));
typedef float f32x4 __attribute__((ext_vector_type(4)));
typedef float f32x4u __attribute__((ext_vector_type(4), aligned(4)));

__device__ __forceinline__ float bf(u16 u){
  union { unsigned int i; float f; } v; v.i = ((unsigned int)u) << 16; return v.f;
}
__device__ __forceinline__ u16 f2b(float f){
  __hip_bfloat16 h = __float2bfloat16(f);
  union { __hip_bfloat16 hh; u16 u; } v; v.hh = h; return v.u;
}

// F layout (folded weights): [0..47] w0f, [48..63] b0f, [64..319] w1f,
// [320..335] b1f, [336..1359] w2f, [1360..1423] b2f
// npw: transposed position space q = o*64 + i  (original channel ch = i*64 + o)
// ptsw[B*N][64] bf16: pre-converted concat(points, xyz) rows
// Gr LDS: K-major, 16B k-blocks XOR-swizzled by (ch>>3)&3
// k_main (round 25): 16 points/block, fused stat partials -> PC, gather prefetch,
//   H1+W phases MERGED per wave (H1bf slices are wave-private; same-wave LDS
//   ordering via lgkmcnt — pattern proven rounds 11-12). 3 barriers/group.
//   H0bf is a separate buffer again (no WrBuf alias); pads written once.
// yw aliases the PC region (PC dead after k_finC, yw born at k_linear).
// NOTE (round 15): device atomics bypass L2 on MI355X -> keep stats streaming.

// ---------------- k_init: newxyz (0..63) + lwbt (64..127) + ptsw (128..639) + lc moments (640..1151) ----------------
__global__ __launch_bounds__(256) void k_init(const float* xyz, const int* didx, float* out,
                                              const float* lw, u16* lwbt,
                                              const float* points, u16* ptsw,
                                              const float* lc, float* PA){
  int t = threadIdx.x;
  if (blockIdx.x < 64){
    int p = blockIdx.x * 256 + t;
    int b = p >> 10;
    int idx = didx[p];
    const float* src = xyz + ((size_t)(b * NN + idx)) * 3;
    float* dst = out + (size_t)p * 3;
    dst[0] = src[0]; dst[1] = src[1]; dst[2] = src[2];
  } else if (blockIdx.x < 128){
    __shared__ float T[64][65];
    int ib = blockIdx.x - 64;
    int kb = ib * 64;
    {
      int k = t >> 2, c4 = t & 3;
      #pragma unroll
      for (int j = 0; j < 4; ++j)
        *(f32x4*)&T[k][c4*16 + j*4] = *(const f32x4*)(lw + (size_t)(kb + k)*64 + c4*16 + j*4);
    }
    __syncthreads();
    {
      int n = t >> 2, k4 = t & 3;
      #pragma unroll
      for (int j = 0; j < 16; ++j){
        int k = k4*16 + j;
        lwbt[(size_t)n*4096 + k*64 + ib] = f2b(T[k][n]);
      }
    }
  } else if (blockIdx.x < 640){
    int gid0 = (blockIdx.x - 128) * 256 + t;
    #pragma unroll
    for (int rep = 0; rep < 4; ++rep){
      int idx = gid0 + rep * 131072;
      int row = idx >> 3, c8 = idx & 7;
      const float* prow = points + (size_t)row * 61;
      u16x8 g;
      if (c8 < 7){
        f32x4 lo = *(const f32x4u*)(prow + c8*8);
        f32x4 hi = *(const f32x4u*)(prow + c8*8 + 4);
        g[0]=f2b(lo.x); g[1]=f2b(lo.y); g[2]=f2b(lo.z); g[3]=f2b(lo.w);
        g[4]=f2b(hi.x); g[5]=f2b(hi.y); g[6]=f2b(hi.z); g[7]=f2b(hi.w);
      } else {
        const float* xr = xyz + (size_t)row * 3;
        f32x4 lo = *(const f32x4u*)(prow + 56);
        g[0]=f2b(lo.x); g[1]=f2b(lo.y); g[2]=f2b(lo.z); g[3]=f2b(lo.w);
        g[4]=f2b(prow[60]);
        g[5]=f2b(xr[0]); g[6]=f2b(xr[1]); g[7]=f2b(xr[2]);
      }
      *(u16x8*)(ptsw + (size_t)row*64 + c8*8) = g;
    }
  } else {
    int bid = blockIdx.x - 640;
    float a[9];
    #pragma unroll
    for (int r = 0; r < 9; ++r) a[r] = 0.f;
    size_t base = (size_t)bid * 1024 + t;
    for (int ip = 0; ip < 4; ++ip){
      size_t p = base + (size_t)ip * 256;
      float x0 = lc[p*3], x1 = lc[p*3+1], x2 = lc[p*3+2];
      a[0]+=x0; a[1]+=x1; a[2]+=x2;
      a[3]+=x0*x0; a[4]+=x0*x1; a[5]+=x0*x2;
      a[6]+=x1*x1; a[7]+=x1*x2; a[8]+=x2*x2;
    }
    #pragma unroll
    for (int m = 1; m < 64; m <<= 1){
      #pragma unroll
      for (int r = 0; r < 9; ++r) a[r] += __shfl_xor(a[r], m);
    }
    if ((t & 63) == 0){
      float* dst = PA + (size_t)(bid*4 + (t>>6)) * 16;
      f32x4 v0 = {a[0],a[1],a[2],a[3]}, v1 = {a[4],a[5],a[6],a[7]}, v2 = {a[8],0.f,0.f,0.f};
      *(f32x4*)dst = v0; *(f32x4*)(dst+4) = v1; *(f32x4*)(dst+8) = v2;
    }
  }
}

// ---------------- k_red0 ----------------
__global__ __launch_bounds__(256) void k_red0(const float* PA, const float* w0, const float* b0,
                                              const float* g0, const float* be0, float* F){
  __shared__ float ms[12];
  __shared__ float a0sh[16];
  int t = threadIdx.x;
  if (t < 12){
    float s0=0,s1=0,s2=0,s3=0;
    const float* p = PA + t;
    for (int r = 0; r < 2048; r += 4){
      s0 += p[(size_t)(r+0)*16]; s1 += p[(size_t)(r+1)*16];
      s2 += p[(size_t)(r+2)*16]; s3 += p[(size_t)(r+3)*16];
    }
    ms[t] = (s0+s1)+(s2+s3);
  }
  __syncthreads();
  if (t < 16){
    float wx = w0[t*3], wy = w0[t*3+1], wz = w0[t*3+2], bb = b0[t];
    float lin = wx*ms[0] + wy*ms[1] + wz*ms[2];
    float quad = wx*wx*ms[3] + wy*wy*ms[6] + wz*wz*ms[8]
               + 2.f*(wx*wy*ms[4] + wx*wz*ms[5] + wy*wz*ms[7]);
    float S = lin + (float)NWN * bb;
    float Q = quad + 2.f*bb*lin + (float)NWN*bb*bb;
    float m = S * (1.f/NWN);
    float v = Q * (1.f/NWN) - m*m;
    float a = g0[t] * rsqrtf(v + EPSF);
    float d = be0[t] - m*a;
    a0sh[t] = a;
    F[48+t] = a*bb + d;
  }
  __syncthreads();
  if (t < 48) F[t] = a0sh[t/3] * w0[t];
}

// ---------------- k_statG1: h0 Gram (VALU h0, MFMA Gram) ----------------
__global__ __launch_bounds__(256) void k_statG1(const float* lc, const float* F, float* PB){
  __shared__ f32x4 w0p[16];
  __shared__ __align__(16) u16 Ht[4][16*72];
  __shared__ float GS[4][16][17];
  __shared__ float SHs[4][16];
  int t = threadIdx.x;
  int w = t >> 6, l = t & 63;
  if (t < 16){
    f32x4 wv = {F[t*3], F[t*3+1], F[t*3+2], F[48+t]};
    w0p[t] = wv;
  }
  __syncthreads();
  f32x4 acc = {0.f,0.f,0.f,0.f};
  float sh[16];
  #pragma unroll
  for (int r = 0; r < 16; ++r) sh[r] = 0.f;
  u16* Hw = &Ht[w][0];
  for (int it = 0; it < SGIT; ++it){
    size_t p = (size_t)blockIdx.x * (SGIT*256) + (size_t)it*256 + w*64 + l;
    float x0 = lc[p*3], x1 = lc[p*3+1], x2 = lc[p*3+2];
    float h[16];
    #pragma unroll
    for (int oc = 0; oc < 16; ++oc){
      f32x4 wv = w0p[oc];
      h[oc] = fmaxf(0.f, wv.x*x0 + wv.y*x1 + wv.z*x2 + wv.w);
      sh[oc] += h[oc];
    }
    #pragma unroll
    for (int c = 0; c < 16; ++c) Hw[c*72 + l] = f2b(h[c]);
    __syncthreads();
    #pragma unroll
    for (int tt = 0; tt < 2; ++tt){
      s16x8 af = *(const s16x8*)&Hw[(l & 15)*72 + tt*32 + (l >> 4)*8];
      acc = __builtin_amdgcn_mfma_f32_16x16x32_bf16(af, af, acc, 0, 0, 0);
    }
    __syncthreads();
  }
  #pragma unroll
  for (int r = 0; r < 4; ++r)
    GS[w][(l>>4)*4 + r][l & 15] = acc[r];
  #pragma unroll
  for (int m = 1; m < 64; m <<= 1){
    #pragma unroll
    for (int r = 0; r < 16; ++r) sh[r] += __shfl_xor(sh[r], m);
  }
  if (l == 0){
    #pragma unroll
    for (int r = 0; r < 16; ++r) SHs[w][r] = sh[r];
  }
  __syncthreads();
  {
    int i = t >> 4, j = t & 15;
    float g = GS[0][i][j] + GS[1][i][j] + GS[2][i][j] + GS[3][i][j];
    PB[(size_t)blockIdx.x*272 + t] = g;
    if (t < 16)
      PB[(size_t)blockIdx.x*272 + 256 + t] = SHs[0][t]+SHs[1][t]+SHs[2][t]+SHs[3][t];
  }
}

// ---------------- k_statG2: h1 Gram (MFMA h1 via w1Bg + MFMA Gram) ----------------
__global__ __launch_bounds__(256) void k_statG2(const float* lc, const float* F,
                                                const u16* w1Bg, float* PB){
  __shared__ f32x4 w0p[16];
  __shared__ __align__(16) u16 Ht0[4][64*40];
  __shared__ __align__(16) u16 Ht1[4][16*72];
  __shared__ float GS[4][16][17];
  __shared__ float SHs[4][16];
  int t = threadIdx.x;
  int w = t >> 6, l = t & 63;
  if (t < 16){
    f32x4 wv = {F[t*3], F[t*3+1], F[t*3+2], F[48+t]};
    w0p[t] = wv;
  }
  s16x8 w1B = *(const s16x8*)&w1Bg[l*8];
  float b1f = F[320 + (l & 15)];
  u16* H0w = &Ht0[w][0];
  u16* H1w = &Ht1[w][0];
  {
    u16x8 z8 = {0,0,0,0,0,0,0,0};
    *(u16x8*)&H0w[l*40 + 16] = z8;
    *(u16x8*)&H0w[l*40 + 24] = z8;
  }
  __syncthreads();
  f32x4 acc = {0.f,0.f,0.f,0.f};
  float shloc = 0.f;
  for (int it = 0; it < SGIT; ++it){
    size_t p = (size_t)blockIdx.x * (SGIT*256) + (size_t)it*256 + w*64 + l;
    float x0 = lc[p*3], x1 = lc[p*3+1], x2 = lc[p*3+2];
    u16x8 p0, p1;
    #pragma unroll
    for (int oc = 0; oc < 8; ++oc){
      f32x4 wv = w0p[oc];
      p0[oc] = f2b(fmaxf(0.f, wv.x*x0 + wv.y*x1 + wv.z*x2 + wv.w));
    }
    #pragma unroll
    for (int oc = 0; oc < 8; ++oc){
      f32x4 wv = w0p[8+oc];
      p1[oc] = f2b(fmaxf(0.f, wv.x*x0 + wv.y*x1 + wv.z*x2 + wv.w));
    }
    *(u16x8*)&H0w[l*40]     = p0;
    *(u16x8*)&H0w[l*40 + 8] = p1;
    __syncthreads();
    #pragma unroll
    for (int mt = 0; mt < 4; ++mt){
      s16x8 af = *(const s16x8*)&H0w[(mt*16 + (l & 15))*40 + (l >> 4)*8];
      f32x4 c = {b1f, b1f, b1f, b1f};
      c = __builtin_amdgcn_mfma_f32_16x16x32_bf16(af, w1B, c, 0, 0, 0);
      #pragma unroll
      for (int r = 0; r < 4; ++r){
        float v = fmaxf(0.f, c[r]);
        shloc += v;
        H1w[(l & 15)*72 + mt*16 + (l >> 4)*4 + r] = f2b(v);
      }
    }
    __syncthreads();
    #pragma unroll
    for (int tt = 0; tt < 2; ++tt){
      s16x8 afg = *(const s16x8*)&H1w[(l & 15)*72 + tt*32 + (l >> 4)*8];
      acc = __builtin_amdgcn_mfma_f32_16x16x32_bf16(afg, afg, acc, 0, 0, 0);
    }
    __syncthreads();
  }
  #pragma unroll
  for (int r = 0; r < 4; ++r)
    GS[w][(l>>4)*4 + r][l & 15] = acc[r];
  shloc += __shfl_xor(shloc, 16);
  shloc += __shfl_xor(shloc, 32);
  if (l < 16) SHs[w][l] = shloc;
  __syncthreads();
  {
    int i = t >> 4, j = t & 15;
    float g = GS[0][i][j] + GS[1][i][j] + GS[2][i][j] + GS[3][i][j];
    PB[(size_t)blockIdx.x*272 + t] = g;
    if (t < 16)
      PB[(size_t)blockIdx.x*272 + 256 + t] = SHs[0][t]+SHs[1][t]+SHs[2][t]+SHs[3][t];
  }
}

// ---------------- k_red1 ----------------
__global__ __launch_bounds__(256) void k_red1(const float* PB, const float* w1, const float* b1,
                                              const float* g1, const float* be1, float* F,
                                              u16* w1Bg){
  __shared__ float red[272];
  __shared__ float a1sh[16];
  int t = threadIdx.x;
  for (int e = t; e < 272; e += 256){
    float s = 0.f;
    for (int r = 0; r < SGBLK; ++r) s += PB[(size_t)r*272 + e];
    red[e] = s;
  }
  __syncthreads();
  if (t < 16){
    float wv[16];
    #pragma unroll
    for (int ic = 0; ic < 16; ++ic) wv[ic] = w1[t*16+ic];
    float lin = 0.f;
    #pragma unroll
    for (int ic = 0; ic < 16; ++ic) lin += wv[ic]*red[256+ic];
    float quad = 0.f;
    for (int i = 0; i < 16; ++i){
      float ri = 0.f;
      #pragma unroll
      for (int j = 0; j < 16; ++j) ri += wv[j]*red[i*16+j];
      quad += wv[i]*ri;
    }
    float bb = b1[t];
    float S = lin + (float)NWN * bb;
    float Q = quad + 2.f*bb*lin + (float)NWN*bb*bb;
    float m = S * (1.f/NWN);
    float v = Q * (1.f/NWN) - m*m;
    float a = g1[t] * rsqrtf(v + EPSF);
    float d = be1[t] - m*a;
    a1sh[t] = a;
    F[320+t] = a*bb + d;
  }
  __syncthreads();
  F[64 + t] = a1sh[t >> 4] * w1[t];
  if (t < 64){
    int oc = t & 15, icb = (t >> 4) * 8;
    u16x8 fr;
    #pragma unroll
    for (int j = 0; j < 8; ++j){
      int ic = icb + j;
      fr[j] = (ic < 16) ? f2b(a1sh[oc] * w1[oc*16 + ic]) : (u16)0;
    }
    *(u16x8*)&w1Bg[t*8] = fr;
  }
}

// ---------------- k_red2 ----------------
__global__ __launch_bounds__(256) void k_red2(const float* PB, const float* w2, const float* b2,
                                              const float* g2, const float* be2, float* F,
                                              u16* w2Bg){
  __shared__ float red[272];
  __shared__ float a2sh[64];
  int t = threadIdx.x;
  for (int e = t; e < 272; e += 256){
    float s = 0.f;
    for (int r = 0; r < SGBLK; ++r) s += PB[(size_t)r*272 + e];
    red[e] = s;
  }
  __syncthreads();
  if (t < 64){
    float wv[16];
    #pragma unroll
    for (int ic = 0; ic < 16; ++ic) wv[ic] = w2[t*16+ic];
    float lin = 0.f;
    #pragma unroll
    for (int ic = 0; ic < 16; ++ic) lin += wv[ic]*red[256+ic];
    float quad = 0.f;
    for (int i = 0; i < 16; ++i){
      float ri = 0.f;
      #pragma unroll
      for (int j = 0; j < 16; ++j) ri += wv[j]*red[i*16+j];
      quad += wv[i]*ri;
    }
    float bb = b2[t];
    float S = lin + (float)NWN * bb;
    float Q = quad + 2.f*bb*lin + (float)NWN*bb*bb;
    float m = S * (1.f/NWN);
    float v = Q * (1.f/NWN) - m*m;
    float a = g2[t] * rsqrtf(v + EPSF);
    float d = be2[t] - m*a;
    a2sh[t] = a;
    F[1360+t] = a*bb + d;
  }
  __syncthreads();
  for (int i = t; i < 1024; i += 256) F[336+i] = a2sh[i >> 4] * w2[i];
  {
    int ot = t >> 6, lane = t & 63;
    int oc = ot*16 + (lane & 15), icb = ((lane >> 4)) * 8;
    u16x8 fr;
    #pragma unroll
    for (int j = 0; j < 8; ++j){
      int ic = icb + j;
      fr[j] = (ic < 16) ? f2b(a2sh[oc] * w2[oc*16 + ic]) : (u16)0;
    }
    *(u16x8*)&w2Bg[t*8] = fr;
  }
}

// ---------------- K5: 16 points/block + fused stats + gather prefetch + merged H1/W ----------------
__global__ __launch_bounds__(256) void k_main(const float* lcg, const int* nbrg,
    const u16* ptsw, const float* F,
    const u16* w1Bg, const u16* w2Bg,
    u16* npw, float* PC){
  __shared__ __align__(16) u16 Gr[2][64*40];        // swizzled K-major per point
  __shared__ __align__(16) u16 Wr[2][64*40];        // W output (separate buffer)
  __shared__ __align__(16) u16 H0bf[2][32*40];      // [k][ic], ic zero-padded (pads persist)
  __shared__ __align__(16) u16 H1bf[2][32*40];      // wave-private slices
  int t = threadIdx.x;
  int w = t >> 6, l = t & 63;
  int pbase = blockIdx.x * 16;
  s16x8 w1B  = *(const s16x8*)&w1Bg[l*8];
  s16x8 w2B0 = *(const s16x8*)&w2Bg[(0*64 + l)*8];
  s16x8 w2B1 = *(const s16x8*)&w2Bg[(1*64 + l)*8];
  s16x8 w2B2 = *(const s16x8*)&w2Bg[(2*64 + l)*8];
  s16x8 w2B3 = *(const s16x8*)&w2Bg[(3*64 + l)*8];
  float b1f  = F[320 + (l & 15)];
  float b2f0 = F[1360 +  0 + (l & 15)];
  float b2f1 = F[1360 + 16 + (l & 15)];
  float b2f2 = F[1360 + 32 + (l & 15)];
  float b2f3 = F[1360 + 48 + (l & 15)];
  int oc0 = (t & 7) * 2;
  f32x4 w0a = {F[oc0*3], F[oc0*3+1], F[oc0*3+2], F[48+oc0]};
  f32x4 w0b = {F[oc0*3+3], F[oc0*3+4], F[oc0*3+5], F[48+oc0+1]};
  // thread-geometry constants
  int kg = w*8 + (l >> 3), c8 = l & 7;
  int kphys = ((w ^ (c8 & 3)) << 3) + (l >> 3);
  int kH = t >> 3, cpad = 16 + (t & 7)*2;
  // pads written ONCE (H0bf and H1bf are never overwritten by other phases now)
  {
    *(unsigned int*)&H0bf[0][kH*40 + cpad] = 0u;
    *(unsigned int*)&H0bf[1][kH*40 + cpad] = 0u;
    *(unsigned int*)&H1bf[0][kH*40 + cpad] = 0u;
    *(unsigned int*)&H1bf[1][kH*40 + cpad] = 0u;
  }
  // per-thread channel-stat accumulators (positions are point-invariant)
  float sacc[16], qacc[16];
  #pragma unroll
  for (int j = 0; j < 16; ++j){ sacc[j] = 0.f; qacc[j] = 0.f; }
  // prologue prefetch: group 0's gather + lc
  u16x8 gv0, gv1;
  float lx00, lx01, lx02, lx10, lx11, lx12;
  {
    int point = pbase;
    int bbp = point >> 10;
    int n = nbrg[(size_t)point*32 + kg];
    gv0 = *(const u16x8*)(ptsw + (size_t)(bbp * NN + n)*64 + c8*8);
    const float* xp = lcg + (size_t)point*96 + kH*3;
    lx00 = xp[0]; lx01 = xp[1]; lx02 = xp[2];
    int point1 = pbase + 1;
    int bbp1 = point1 >> 10;
    int n1 = nbrg[(size_t)point1*32 + kg];
    gv1 = *(const u16x8*)(ptsw + (size_t)(bbp1 * NN + n1)*64 + c8*8);
    const float* xp1 = lcg + (size_t)point1*96 + kH*3;
    lx10 = xp1[0]; lx11 = xp1[1]; lx12 = xp1[2];
  }
  __syncthreads();   // pads visible before first merged phase

  for (int g = 0; g < 8; ++g){
    int p0 = pbase + g*2;
    // write prefetched gather -> Gr swizzled K-major
    {
      #pragma unroll
      for (int j = 0; j < 8; ++j)
        Gr[0][(c8*8 + j)*40 + kphys] = gv0[j];
      #pragma unroll
      for (int j = 0; j < 8; ++j)
        Gr[1][(c8*8 + j)*40 + kphys] = gv1[j];
    }
    // H0 both points from prefetched lc
    {
      H0bf[0][kH*40 + oc0]     = f2b(fmaxf(0.f, w0a.x*lx00 + w0a.y*lx01 + w0a.z*lx02 + w0a.w));
      H0bf[0][kH*40 + oc0 + 1] = f2b(fmaxf(0.f, w0b.x*lx00 + w0b.y*lx01 + w0b.z*lx02 + w0b.w));
      H0bf[1][kH*40 + oc0]     = f2b(fmaxf(0.f, w0a.x*lx10 + w0a.y*lx11 + w0a.z*lx12 + w0a.w));
      H0bf[1][kH*40 + oc0 + 1] = f2b(fmaxf(0.f, w0b.x*lx10 + w0b.y*lx11 + w0b.z*lx12 + w0b.w));
    }
    // prefetch next group's gather + lc (latency hides under MFMA phases)
    if (g < 7){
      int pn0 = p0 + 2, pn1 = p0 + 3;
      int bn0 = pn0 >> 10, bn1 = pn1 >> 10;
      int n0 = nbrg[(size_t)pn0*32 + kg];
      int n1 = nbrg[(size_t)pn1*32 + kg];
      gv0 = *(const u16x8*)(ptsw + (size_t)(bn0 * NN + n0)*64 + c8*8);
      gv1 = *(const u16x8*)(ptsw + (size_t)(bn1 * NN + n1)*64 + c8*8);
      const float* xp0 = lcg + (size_t)pn0*96 + kH*3;
      lx00 = xp0[0]; lx01 = xp0[1]; lx02 = xp0[2];
      const float* xp1 = lcg + (size_t)pn1*96 + kH*3;
      lx10 = xp1[0]; lx11 = xp1[1]; lx12 = xp1[2];
    }
    __syncthreads();   // (1) Gr + H0bf ready
    // merged H1+W: wave w -> pt = w>>1, kt = w&1; H1bf slice is wave-private
    {
      int pt = w >> 1, kt = w & 1;
      s16x8 af = *(const s16x8*)&H0bf[pt][(kt*16 + (l & 15))*40 + (l >> 4)*8];
      f32x4 acc = {b1f, b1f, b1f, b1f};
      acc = __builtin_amdgcn_mfma_f32_16x16x32_bf16(af, w1B, acc, 0, 0, 0);
      #pragma unroll
      for (int r = 0; r < 4; ++r)
        H1bf[pt][(kt*16 + (l >> 4)*4 + r)*40 + (l & 15)] = f2b(fmaxf(0.f, acc[r]));
      // same wave reads its own H1bf slice (lgkmcnt-ordered)
      s16x8 af2 = *(const s16x8*)&H1bf[pt][(kt*16 + (l & 15))*40 + (l >> 4)*8];
      int kbase = kt*16 + (l >> 4)*4;
      f32x4 a0c = {b2f0,b2f0,b2f0,b2f0};
      a0c = __builtin_amdgcn_mfma_f32_16x16x32_bf16(af2, w2B0, a0c, 0, 0, 0);
      u16x4 s0v; s0v[0]=f2b(fmaxf(0.f,a0c[0])); s0v[1]=f2b(fmaxf(0.f,a0c[1]));
      s0v[2]=f2b(fmaxf(0.f,a0c[2])); s0v[3]=f2b(fmaxf(0.f,a0c[3]));
      *(u16x4*)&Wr[pt][( 0 + (l & 15))*40 + kbase] = s0v;
      f32x4 a1c = {b2f1,b2f1,b2f1,b2f1};
      a1c = __builtin_amdgcn_mfma_f32_16x16x32_bf16(af2, w2B1, a1c, 0, 0, 0);
      u16x4 s1v; s1v[0]=f2b(fmaxf(0.f,a1c[0])); s1v[1]=f2b(fmaxf(0.f,a1c[1]));
      s1v[2]=f2b(fmaxf(0.f,a1c[2])); s1v[3]=f2b(fmaxf(0.f,a1c[3]));
      *(u16x4*)&Wr[pt][(16 + (l & 15))*40 + kbase] = s1v;
      f32x4 a2c = {b2f2,b2f2,b2f2,b2f2};
      a2c = __builtin_amdgcn_mfma_f32_16x16x32_bf16(af2, w2B2, a2c, 0, 0, 0);
      u16x4 s2v; s2v[0]=f2b(fmaxf(0.f,a2c[0])); s2v[1]=f2b(fmaxf(0.f,a2c[1]));
      s2v[2]=f2b(fmaxf(0.f,a2c[2])); s2v[3]=f2b(fmaxf(0.f,a2c[3]));
      *(u16x4*)&Wr[pt][(32 + (l & 15))*40 + kbase] = s2v;
      f32x4 a3c = {b2f3,b2f3,b2f3,b2f3};
      a3c = __builtin_amdgcn_mfma_f32_16x16x32_bf16(af2, w2B3, a3c, 0, 0, 0);
      u16x4 s3v; s3v[0]=f2b(fmaxf(0.f,a3c[0])); s3v[1]=f2b(fmaxf(0.f,a3c[1]));
      s3v[2]=f2b(fmaxf(0.f,a3c[2])); s3v[3]=f2b(fmaxf(0.f,a3c[3]));
      *(u16x4*)&Wr[pt][(48 + (l & 15))*40 + kbase] = s3v;
    }
    __syncthreads();   // (3) Wr ready (all waves' columns)
    // np = G^T W: wave w owns o-tile w, both points; accumulate stats in regs
    {
      int li = l & 15, lkb = l >> 4, lr = (l >> 4) * 4;
      #pragma unroll
      for (int pt = 0; pt < 2; ++pt){
        s16x8 bfrag = *(const s16x8*)&Wr[pt][(w*16 + li)*40 + lkb*8];
        size_t obase = (size_t)(p0 + pt)*4096 + (size_t)(w*16 + li)*64 + lr;
        #pragma unroll
        for (int it = 0; it < 4; ++it){
          int ch = it*16 + li;
          int key = (ch >> 3) & 3;
          s16x8 afrag = *(const s16x8*)&Gr[pt][ch*40 + ((lkb ^ key) << 3)];
          f32x4 z = {0.f, 0.f, 0.f, 0.f};
          f32x4 d = __builtin_amdgcn_mfma_f32_16x16x32_bf16(afrag, bfrag, z, 0, 0, 0);
          u16x4 st;
          st[0] = f2b(d[0]); st[1] = f2b(d[1]); st[2] = f2b(d[2]); st[3] = f2b(d[3]);
          *(u16x4*)(npw + obase + it*16) = st;
          #pragma unroll
          for (int r = 0; r < 4; ++r){
            sacc[it*4 + r] += d[r];
            qacc[it*4 + r] += d[r]*d[r];
          }
        }
      }
    }
    __syncthreads();   // (0) final reads done before next iter's Gr/H0 overwrite
  }
  // write block channel-stat partials
  {
    int qb = (w*16 + (l & 15))*64 + (l >> 4)*4;
    float* dst = PC + (size_t)blockIdx.x * 8192;
    #pragma unroll
    for (int it = 0; it < 4; ++it){
      f32x4 sv = {sacc[it*4+0], sacc[it*4+1], sacc[it*4+2], sacc[it*4+3]};
      f32x4 qv = {qacc[it*4+0], qacc[it*4+1], qacc[it*4+2], qacc[it*4+3]};
      *(f32x4*)(dst + qb + it*16) = sv;
      *(f32x4*)(dst + 4096 + qb + it*16) = qv;
    }
  }
}

// ---------------- k_finC: reduce 1024 block partials + finalize (grid 256) ----------------
__global__ __launch_bounds__(256) void k_finC(const float* PC, const float* gc, const float* bc,
                                              float* AC, float* DC){
  __shared__ float shs[16][17], shq[16][17];
  int t = threadIdx.x;
  int ql = t & 15, rc = t >> 4;
  int qpos = blockIdx.x * 16 + ql;
  float s = 0.f, q = 0.f;
  int r0 = rc * 64;
  #pragma unroll 4
  for (int r = r0; r < r0 + 64; ++r){
    s += PC[(size_t)r * 8192 + qpos];
    q += PC[(size_t)r * 8192 + 4096 + qpos];
  }
  shs[ql][rc] = s; shq[ql][rc] = q;
  __syncthreads();
  if (t < 16){
    float ss = 0.f, qq = 0.f;
    #pragma unroll
    for (int c = 0; c < 16; ++c){ ss += shs[t][c]; qq += shq[t][c]; }
    int qp = blockIdx.x * 16 + t;
    int ch = (qp & 63)*64 + (qp >> 6);
    float m = ss * (1.f/16384.f);
    float v = qq * (1.f/16384.f) - m*m;
    float a = gc[ch] * rsqrtf(v + EPSF);
    AC[qp] = a; DC[qp] = bc[ch] - m*a;
  }
}

// ---------------- k_linear: 16 rows/block, grid 1024, double-buffered LDS ----------------
__global__ __launch_bounds__(256) void k_linear(const u16* npw, const float* AC, const float* DC,
                                                const u16* lwbt, const float* lb, float* yw,
                                                float* PL){
  __shared__ u16 Al[2][16*72];
  __shared__ u16 Bl[2][64*72];
  __shared__ float cps[64], cpq[64];
  int t = threadIdx.x;
  int w = t >> 6, l = t & 63;
  int rowbase = blockIdx.x * 16;
  int rA = t >> 4, cA = t & 15;
  int nB = t >> 3, cB = t & 7;
  const u16* Aptr  = npw  + (size_t)(rowbase + rA)*4096 + cA*4;
  const u16* B0ptr = lwbt + (size_t)nB*4096 + cB*8;
  const u16* B1ptr = lwbt + (size_t)(nB + 32)*4096 + cB*8;
  f32x4 acc0 = {0.f,0.f,0.f,0.f};
  u16x4 uA  = *(const u16x4*)(Aptr);
  u16x8 uB0 = *(const u16x8*)(B0ptr);
  u16x8 uB1 = *(const u16x8*)(B1ptr);
  {
    int kk = cA*4;
    f32x4 av = *(const f32x4*)(AC + kk);
    f32x4 dv = *(const f32x4*)(DC + kk);
    u16x4 o;
    o[0] = f2b(fmaxf(0.f, av.x*bf(uA[0]) + dv.x));
    o[1] = f2b(fmaxf(0.f, av.y*bf(uA[1]) + dv.y));
    o[2] = f2b(fmaxf(0.f, av.z*bf(uA[2]) + dv.z));
    o[3] = f2b(fmaxf(0.f, av.w*bf(uA[3]) + dv.w));
    *(u16x4*)&Al[0][rA*72 + cA*4] = o;
    *(u16x8*)&Bl[0][nB*72 + cB*8]        = uB0;
    *(u16x8*)&Bl[0][(nB + 32)*72 + cB*8] = uB1;
  }
  uA  = *(const u16x4*)(Aptr + 64);
  uB0 = *(const u16x8*)(B0ptr + 64);
  uB1 = *(const u16x8*)(B1ptr + 64);
  __syncthreads();
  int cur = 0;
  for (int kb = 0; kb < 4096; kb += 64){
    if (kb + 64 < 4096){
      int kk = kb + 64 + cA*4;
      f32x4 av = *(const f32x4*)(AC + kk);
      f32x4 dv = *(const f32x4*)(DC + kk);
      u16x4 o;
      o[0] = f2b(fmaxf(0.f, av.x*bf(uA[0]) + dv.x));
      o[1] = f2b(fmaxf(0.f, av.y*bf(uA[1]) + dv.y));
      o[2] = f2b(fmaxf(0.f, av.z*bf(uA[2]) + dv.z));
      o[3] = f2b(fmaxf(0.f, av.w*bf(uA[3]) + dv.w));
      *(u16x4*)&Al[cur^1][rA*72 + cA*4] = o;
      *(u16x8*)&Bl[cur^1][nB*72 + cB*8]        = uB0;
      *(u16x8*)&Bl[cur^1][(nB + 32)*72 + cB*8] = uB1;
      if (kb + 128 < 4096){
        uA  = *(const u16x4*)(Aptr + kb + 128);
        uB0 = *(const u16x8*)(B0ptr + kb + 128);
        uB1 = *(const u16x8*)(B1ptr + kb + 128);
      }
    }
    #pragma unroll
    for (int ks = 0; ks < 2; ++ks){
      s16x8 af  = *(const s16x8*)&Al[cur][((l & 15))*72 + ks*32 + (l >> 4)*8];
      s16x8 bf0 = *(const s16x8*)&Bl[cur][(w*16 + (l & 15))*72 + ks*32 + (l >> 4)*8];
      acc0 = __builtin_amdgcn_mfma_f32_16x16x32_bf16(af, bf0, acc0, 0, 0, 0);
    }
    __syncthreads();
    cur ^= 1;
  }
  int col0 = w*16 + (l & 15);
  float lb0 = lb[col0];
  float s0 = 0.f, q0 = 0.f;
  if (t < 64){ cps[t] = 0.f; cpq[t] = 0.f; }
  __syncthreads();
  #pragma unroll
  for (int r = 0; r < 4; ++r){
    int row = rowbase + (l >> 4)*4 + r;
    float y0 = acc0[r] + lb0;
    yw[(size_t)row*64 + col0] = y0;
    s0 += y0; q0 += y0*y0;
  }
  atomicAdd(&cps[col0], s0); atomicAdd(&cpq[col0], q0);
  __syncthreads();
  if (t < 64){
    PL[blockIdx.x*128 + t]      = cps[t];
    PL[blockIdx.x*128 + 64 + t] = cpq[t];
  }
}

// ---------------- k_redF (1024 blocks of PL) ----------------
__global__ __launch_bounds__(128) void k_redF(const float* PL, float* SL){
  int t = threadIdx.x;
  float s = 0.f;
  for (int b = 0; b < 1024; ++b) s += PL[b*128 + t];
  SL[t] = s;
}

// ---------------- k_final ----------------
__global__ __launch_bounds__(256) void k_final(const float* yw, const float* SL,
                                               const float* gl, const float* bl, float* out){
  int e = (blockIdx.x * 256 + threadIdx.x) * 4;
  int o = e & 63;
  f32x4 y = *(const f32x4*)(yw + e);
  f32x4 r;
  #pragma unroll
  for (int j = 0; j < 4; ++j){
    float m = SL[o+j] * (1.f/16384.f);
    float v = SL[64+o+j] * (1.f/16384.f) - m*m;
    float a = gl[o+j] * rsqrtf(v + EPSF);
    float d = bl[o+j] - m*a;
    r[j] = fmaxf(0.f, a*y[j] + d);
  }
  *(f32x4*)(out + 49152 + e) = r;
}

extern "C" void kernel_launch(void* const* d_in, const int* in_sizes, int n_in,
                              void* d_out, int out_size, void* d_ws, size_t ws_size,
                              hipStream_t stream){
  (void)in_sizes; (void)n_in; (void)out_size; (void)ws_size;
  const float* xyz    = (const float*)d_in[0];
  const float* points = (const float*)d_in[1];
  const float* lc     = (const float*)d_in[2];
  const int*   nbrl   = (const int*)d_in[3];
  const int*   didx   = (const int*)d_in[4];
  const float* w0 = (const float*)d_in[5];
  const float* b0 = (const float*)d_in[6];
  const float* g0 = (const float*)d_in[7];
  const float* be0= (const float*)d_in[8];
  const float* w1 = (const float*)d_in[9];
  const float* b1 = (const float*)d_in[10];
  const float* g1 = (const float*)d_in[11];
  const float* be1= (const float*)d_in[12];
  const float* w2 = (const float*)d_in[13];
  const float* b2 = (const float*)d_in[14];
  const float* g2 = (const float*)d_in[15];
  const float* be2= (const float*)d_in[16];
  const float* gc = (const float*)d_in[17];
  const float* bc = (const float*)d_in[18];
  const float* lw = (const float*)d_in[19];
  const float* lb = (const float*)d_in[20];
  const float* gl = (const float*)d_in[21];
  const float* bl = (const float*)d_in[22];
  float* out = (float*)d_out;
  char* ws = (char*)d_ws;

  // small region (< 2 MB)
  float* F   = (float*)ws;           // 1536
  float* SL  = F + 1536;             // 128
  float* AC  = SL + 128;             // 4096
  float* DC  = AC + 4096;            // 4096
  float* PA  = DC + 4096;            // 32768
  float* PB1 = PA + 32768;           // 139264
  float* PB2 = PB1 + 139264;         // 139264
  float* PL  = PB2 + 139264;         // 131072
  u16*  w1Bg = (u16*)(PL + 131072);  // 512 u16
  u16*  w2Bg = w1Bg + 512;           // 2048 u16
  u16*  lwbt = (u16*)(ws + 2097152);                 // 512 KB (permuted), @2MB
  float* PC  = (float*)(ws + 4194304);               // 32 MB (1024 x 8192), @4MB
  float* yw  = (float*)(ws + 4194304);               // 4 MB, ALIASES PC (disjoint lifetime)
  u16*  npw  = (u16*)(ws + 37748736);                // 128 MB bf16 (transposed), @36MB
  u16*  ptsw = (u16*)(ws + 171966464);               // 8 MB bf16, @164MB (end 172MB)

  k_init  <<<1152,  256, 0, stream>>>(xyz, didx, out, lw, lwbt, points, ptsw, lc, PA);
  k_red0  <<<1,     256, 0, stream>>>(PA, w0, b0, g0, be0, F);
  k_statG1<<<SGBLK, 256, 0, stream>>>(lc, F, PB1);
  k_red1  <<<1,     256, 0, stream>>>(PB1, w1, b1, g1, be1, F, w1Bg);
  k_statG2<<<SGBLK, 256, 0, stream>>>(lc, F, w1Bg, PB2);
  k_red2  <<<1,     256, 0, stream>>>(PB2, w2, b2, g2, be2, F, w2Bg);
  k_main  <<<1024,  256, 0, stream>>>(lc, nbrl, ptsw, F, w1Bg, w2Bg, npw, PC);
  k_finC  <<<256,   256, 0, stream>>>(PC, gc, bc, AC, DC);
  k_linear<<<1024,  256, 0, stream>>>(npw, AC, DC, lwbt, lb, yw, PL);
  k_redF  <<<1,     128, 0, stream>>>(PL, SL);
  k_final <<<1024,  256, 0, stream>>>(yw, SL, gl, bl, out);
}

// Round 26
// 225.884 us; speedup vs baseline: 1.1724x; 1.0040x over previous
//
#include <hip/hip_runtime.h>
#include <hip/hip_bf16.h>

#define BB 16
#define NN 4096
#define NPOINTS 1024
#define KK 32
#define NPTS (BB*NPOINTS)        // 16384
#define NWN  (BB*NPOINTS*KK)     // 524288
#define EPSF 1e-5f
#define SGBLK 512
#define SGIT  4

typedef unsigned short u16;
typedef u16  u16x8 __attribute__((ext_vector_type(8)));
typedef u16  u16x4 __attribute__((ext_vector_type(4)));
typedef short s16x8 __attribute__((ext_vector_type(8)));
typedef float f32x4 __attribute__((ext_vector_type(4)));
typedef float f32x4u __attribute__((ext_vector_type(4), aligned(4)));

__device__ __forceinline__ float bf(u16 u){
  union { unsigned int i; float f; } v; v.i = ((unsigned int)u) << 16; return v.f;
}
__device__ __forceinline__ u16 f2b(float f){
  __hip_bfloat16 h = __float2bfloat16(f);
  union { __hip_bfloat16 hh; u16 u; } v; v.hh = h; return v.u;
}

// F layout (folded weights): [0..47] w0f, [48..63] b0f, [64..319] w1f,
// [320..335] b1f, [336..1359] w2f, [1360..1423] b2f
// npw: transposed position space q = o*64 + i  (original channel ch = i*64 + o)
// ptsw[B*N][64] bf16: pre-converted concat(points, xyz) rows
// Gr LDS: K-major, 16B k-blocks XOR-swizzled by (ch>>3)&3
// k_main (round 25): 16 pts/block, fused stat partials -> PC, gather prefetch, merged H1/W.
// k_linear (round 26): K-SPLIT into two independent halves (grid 2048) writing
//   f32 partials ywA/ywB; lb + final-BN stats handled by k_statY/k_final.
// ywA/ywB alias the PC region (PC dead after k_finC).
// NOTE (round 15): device atomics bypass L2 on MI355X -> keep stats streaming.

// ---------------- k_init: newxyz (0..63) + lwbt (64..127) + ptsw (128..639) + lc moments (640..1151) ----------------
__global__ __launch_bounds__(256) void k_init(const float* xyz, const int* didx, float* out,
                                              const float* lw, u16* lwbt,
                                              const float* points, u16* ptsw,
                                              const float* lc, float* PA){
  int t = threadIdx.x;
  if (blockIdx.x < 64){
    int p = blockIdx.x * 256 + t;
    int b = p >> 10;
    int idx = didx[p];
    const float* src = xyz + ((size_t)(b * NN + idx)) * 3;
    float* dst = out + (size_t)p * 3;
    dst[0] = src[0]; dst[1] = src[1]; dst[2] = src[2];
  } else if (blockIdx.x < 128){
    __shared__ float T[64][65];
    int ib = blockIdx.x - 64;
    int kb = ib * 64;
    {
      int k = t >> 2, c4 = t & 3;
      #pragma unroll
      for (int j = 0; j < 4; ++j)
        *(f32x4*)&T[k][c4*16 + j*4] = *(const f32x4*)(lw + (size_t)(kb + k)*64 + c4*16 + j*4);
    }
    __syncthreads();
    {
      int n = t >> 2, k4 = t & 3;
      #pragma unroll
      for (int j = 0; j < 16; ++j){
        int k = k4*16 + j;
        lwbt[(size_t)n*4096 + k*64 + ib] = f2b(T[k][n]);
      }
    }
  } else if (blockIdx.x < 640){
    int gid0 = (blockIdx.x - 128) * 256 + t;
    #pragma unroll
    for (int rep = 0; rep < 4; ++rep){
      int idx = gid0 + rep * 131072;
      int row = idx >> 3, c8 = idx & 7;
      const float* prow = points + (size_t)row * 61;
      u16x8 g;
      if (c8 < 7){
        f32x4 lo = *(const f32x4u*)(prow + c8*8);
        f32x4 hi = *(const f32x4u*)(prow + c8*8 + 4);
        g[0]=f2b(lo.x); g[1]=f2b(lo.y); g[2]=f2b(lo.z); g[3]=f2b(lo.w);
        g[4]=f2b(hi.x); g[5]=f2b(hi.y); g[6]=f2b(hi.z); g[7]=f2b(hi.w);
      } else {
        const float* xr = xyz + (size_t)row * 3;
        f32x4 lo = *(const f32x4u*)(prow + 56);
        g[0]=f2b(lo.x); g[1]=f2b(lo.y); g[2]=f2b(lo.z); g[3]=f2b(lo.w);
        g[4]=f2b(prow[60]);
        g[5]=f2b(xr[0]); g[6]=f2b(xr[1]); g[7]=f2b(xr[2]);
      }
      *(u16x8*)(ptsw + (size_t)row*64 + c8*8) = g;
    }
  } else {
    int bid = blockIdx.x - 640;
    float a[9];
    #pragma unroll
    for (int r = 0; r < 9; ++r) a[r] = 0.f;
    size_t base = (size_t)bid * 1024 + t;
    for (int ip = 0; ip < 4; ++ip){
      size_t p = base + (size_t)ip * 256;
      float x0 = lc[p*3], x1 = lc[p*3+1], x2 = lc[p*3+2];
      a[0]+=x0; a[1]+=x1; a[2]+=x2;
      a[3]+=x0*x0; a[4]+=x0*x1; a[5]+=x0*x2;
      a[6]+=x1*x1; a[7]+=x1*x2; a[8]+=x2*x2;
    }
    #pragma unroll
    for (int m = 1; m < 64; m <<= 1){
      #pragma unroll
      for (int r = 0; r < 9; ++r) a[r] += __shfl_xor(a[r], m);
    }
    if ((t & 63) == 0){
      float* dst = PA + (size_t)(bid*4 + (t>>6)) * 16;
      f32x4 v0 = {a[0],a[1],a[2],a[3]}, v1 = {a[4],a[5],a[6],a[7]}, v2 = {a[8],0.f,0.f,0.f};
      *(f32x4*)dst = v0; *(f32x4*)(dst+4) = v1; *(f32x4*)(dst+8) = v2;
    }
  }
}

// ---------------- k_red0 ----------------
__global__ __launch_bounds__(256) void k_red0(const float* PA, const float* w0, const float* b0,
                                              const float* g0, const float* be0, float* F){
  __shared__ float ms[12];
  __shared__ float a0sh[16];
  int t = threadIdx.x;
  if (t < 12){
    float s0=0,s1=0,s2=0,s3=0;
    const float* p = PA + t;
    for (int r = 0; r < 2048; r += 4){
      s0 += p[(size_t)(r+0)*16]; s1 += p[(size_t)(r+1)*16];
      s2 += p[(size_t)(r+2)*16]; s3 += p[(size_t)(r+3)*16];
    }
    ms[t] = (s0+s1)+(s2+s3);
  }
  __syncthreads();
  if (t < 16){
    float wx = w0[t*3], wy = w0[t*3+1], wz = w0[t*3+2], bb = b0[t];
    float lin = wx*ms[0] + wy*ms[1] + wz*ms[2];
    float quad = wx*wx*ms[3] + wy*wy*ms[6] + wz*wz*ms[8]
               + 2.f*(wx*wy*ms[4] + wx*wz*ms[5] + wy*wz*ms[7]);
    float S = lin + (float)NWN * bb;
    float Q = quad + 2.f*bb*lin + (float)NWN*bb*bb;
    float m = S * (1.f/NWN);
    float v = Q * (1.f/NWN) - m*m;
    float a = g0[t] * rsqrtf(v + EPSF);
    float d = be0[t] - m*a;
    a0sh[t] = a;
    F[48+t] = a*bb + d;
  }
  __syncthreads();
  if (t < 48) F[t] = a0sh[t/3] * w0[t];
}

// ---------------- k_statG1: h0 Gram (VALU h0, MFMA Gram) ----------------
__global__ __launch_bounds__(256) void k_statG1(const float* lc, const float* F, float* PB){
  __shared__ f32x4 w0p[16];
  __shared__ __align__(16) u16 Ht[4][16*72];
  __shared__ float GS[4][16][17];
  __shared__ float SHs[4][16];
  int t = threadIdx.x;
  int w = t >> 6, l = t & 63;
  if (t < 16){
    f32x4 wv = {F[t*3], F[t*3+1], F[t*3+2], F[48+t]};
    w0p[t] = wv;
  }
  __syncthreads();
  f32x4 acc = {0.f,0.f,0.f,0.f};
  float sh[16];
  #pragma unroll
  for (int r = 0; r < 16; ++r) sh[r] = 0.f;
  u16* Hw = &Ht[w][0];
  for (int it = 0; it < SGIT; ++it){
    size_t p = (size_t)blockIdx.x * (SGIT*256) + (size_t)it*256 + w*64 + l;
    float x0 = lc[p*3], x1 = lc[p*3+1], x2 = lc[p*3+2];
    float h[16];
    #pragma unroll
    for (int oc = 0; oc < 16; ++oc){
      f32x4 wv = w0p[oc];
      h[oc] = fmaxf(0.f, wv.x*x0 + wv.y*x1 + wv.z*x2 + wv.w);
      sh[oc] += h[oc];
    }
    #pragma unroll
    for (int c = 0; c < 16; ++c) Hw[c*72 + l] = f2b(h[c]);
    __syncthreads();
    #pragma unroll
    for (int tt = 0; tt < 2; ++tt){
      s16x8 af = *(const s16x8*)&Hw[(l & 15)*72 + tt*32 + (l >> 4)*8];
      acc = __builtin_amdgcn_mfma_f32_16x16x32_bf16(af, af, acc, 0, 0, 0);
    }
    __syncthreads();
  }
  #pragma unroll
  for (int r = 0; r < 4; ++r)
    GS[w][(l>>4)*4 + r][l & 15] = acc[r];
  #pragma unroll
  for (int m = 1; m < 64; m <<= 1){
    #pragma unroll
    for (int r = 0; r < 16; ++r) sh[r] += __shfl_xor(sh[r], m);
  }
  if (l == 0){
    #pragma unroll
    for (int r = 0; r < 16; ++r) SHs[w][r] = sh[r];
  }
  __syncthreads();
  {
    int i = t >> 4, j = t & 15;
    float g = GS[0][i][j] + GS[1][i][j] + GS[2][i][j] + GS[3][i][j];
    PB[(size_t)blockIdx.x*272 + t] = g;
    if (t < 16)
      PB[(size_t)blockIdx.x*272 + 256 + t] = SHs[0][t]+SHs[1][t]+SHs[2][t]+SHs[3][t];
  }
}

// ---------------- k_statG2: h1 Gram (MFMA h1 via w1Bg + MFMA Gram) ----------------
__global__ __launch_bounds__(256) void k_statG2(const float* lc, const float* F,
                                                const u16* w1Bg, float* PB){
  __shared__ f32x4 w0p[16];
  __shared__ __align__(16) u16 Ht0[4][64*40];
  __shared__ __align__(16) u16 Ht1[4][16*72];
  __shared__ float GS[4][16][17];
  __shared__ float SHs[4][16];
  int t = threadIdx.x;
  int w = t >> 6, l = t & 63;
  if (t < 16){
    f32x4 wv = {F[t*3], F[t*3+1], F[t*3+2], F[48+t]};
    w0p[t] = wv;
  }
  s16x8 w1B = *(const s16x8*)&w1Bg[l*8];
  float b1f = F[320 + (l & 15)];
  u16* H0w = &Ht0[w][0];
  u16* H1w = &Ht1[w][0];
  {
    u16x8 z8 = {0,0,0,0,0,0,0,0};
    *(u16x8*)&H0w[l*40 + 16] = z8;
    *(u16x8*)&H0w[l*40 + 24] = z8;
  }
  __syncthreads();
  f32x4 acc = {0.f,0.f,0.f,0.f};
  float shloc = 0.f;
  for (int it = 0; it < SGIT; ++it){
    size_t p = (size_t)blockIdx.x * (SGIT*256) + (size_t)it*256 + w*64 + l;
    float x0 = lc[p*3], x1 = lc[p*3+1], x2 = lc[p*3+2];
    u16x8 p0, p1;
    #pragma unroll
    for (int oc = 0; oc < 8; ++oc){
      f32x4 wv = w0p[oc];
      p0[oc] = f2b(fmaxf(0.f, wv.x*x0 + wv.y*x1 + wv.z*x2 + wv.w));
    }
    #pragma unroll
    for (int oc = 0; oc < 8; ++oc){
      f32x4 wv = w0p[8+oc];
      p1[oc] = f2b(fmaxf(0.f, wv.x*x0 + wv.y*x1 + wv.z*x2 + wv.w));
    }
    *(u16x8*)&H0w[l*40]     = p0;
    *(u16x8*)&H0w[l*40 + 8] = p1;
    __syncthreads();
    #pragma unroll
    for (int mt = 0; mt < 4; ++mt){
      s16x8 af = *(const s16x8*)&H0w[(mt*16 + (l & 15))*40 + (l >> 4)*8];
      f32x4 c = {b1f, b1f, b1f, b1f};
      c = __builtin_amdgcn_mfma_f32_16x16x32_bf16(af, w1B, c, 0, 0, 0);
      #pragma unroll
      for (int r = 0; r < 4; ++r){
        float v = fmaxf(0.f, c[r]);
        shloc += v;
        H1w[(l & 15)*72 + mt*16 + (l >> 4)*4 + r] = f2b(v);
      }
    }
    __syncthreads();
    #pragma unroll
    for (int tt = 0; tt < 2; ++tt){
      s16x8 afg = *(const s16x8*)&H1w[(l & 15)*72 + tt*32 + (l >> 4)*8];
      acc = __builtin_amdgcn_mfma_f32_16x16x32_bf16(afg, afg, acc, 0, 0, 0);
    }
    __syncthreads();
  }
  #pragma unroll
  for (int r = 0; r < 4; ++r)
    GS[w][(l>>4)*4 + r][l & 15] = acc[r];
  shloc += __shfl_xor(shloc, 16);
  shloc += __shfl_xor(shloc, 32);
  if (l < 16) SHs[w][l] = shloc;
  __syncthreads();
  {
    int i = t >> 4, j = t & 15;
    float g = GS[0][i][j] + GS[1][i][j] + GS[2][i][j] + GS[3][i][j];
    PB[(size_t)blockIdx.x*272 + t] = g;
    if (t < 16)
      PB[(size_t)blockIdx.x*272 + 256 + t] = SHs[0][t]+SHs[1][t]+SHs[2][t]+SHs[3][t];
  }
}

// ---------------- k_red1 ----------------
__global__ __launch_bounds__(256) void k_red1(const float* PB, const float* w1, const float* b1,
                                              const float* g1, const float* be1, float* F,
                                              u16* w1Bg){
  __shared__ float red[272];
  __shared__ float a1sh[16];
  int t = threadIdx.x;
  for (int e = t; e < 272; e += 256){
    float s = 0.f;
    for (int r = 0; r < SGBLK; ++r) s += PB[(size_t)r*272 + e];
    red[e] = s;
  }
  __syncthreads();
  if (t < 16){
    float wv[16];
    #pragma unroll
    for (int ic = 0; ic < 16; ++ic) wv[ic] = w1[t*16+ic];
    float lin = 0.f;
    #pragma unroll
    for (int ic = 0; ic < 16; ++ic) lin += wv[ic]*red[256+ic];
    float quad = 0.f;
    for (int i = 0; i < 16; ++i){
      float ri = 0.f;
      #pragma unroll
      for (int j = 0; j < 16; ++j) ri += wv[j]*red[i*16+j];
      quad += wv[i]*ri;
    }
    float bb = b1[t];
    float S = lin + (float)NWN * bb;
    float Q = quad + 2.f*bb*lin + (float)NWN*bb*bb;
    float m = S * (1.f/NWN);
    float v = Q * (1.f/NWN) - m*m;
    float a = g1[t] * rsqrtf(v + EPSF);
    float d = be1[t] - m*a;
    a1sh[t] = a;
    F[320+t] = a*bb + d;
  }
  __syncthreads();
  F[64 + t] = a1sh[t >> 4] * w1[t];
  if (t < 64){
    int oc = t & 15, icb = (t >> 4) * 8;
    u16x8 fr;
    #pragma unroll
    for (int j = 0; j < 8; ++j){
      int ic = icb + j;
      fr[j] = (ic < 16) ? f2b(a1sh[oc] * w1[oc*16 + ic]) : (u16)0;
    }
    *(u16x8*)&w1Bg[t*8] = fr;
  }
}

// ---------------- k_red2 ----------------
__global__ __launch_bounds__(256) void k_red2(const float* PB, const float* w2, const float* b2,
                                              const float* g2, const float* be2, float* F,
                                              u16* w2Bg){
  __shared__ float red[272];
  __shared__ float a2sh[64];
  int t = threadIdx.x;
  for (int e = t; e < 272; e += 256){
    float s = 0.f;
    for (int r = 0; r < SGBLK; ++r) s += PB[(size_t)r*272 + e];
    red[e] = s;
  }
  __syncthreads();
  if (t < 64){
    float wv[16];
    #pragma unroll
    for (int ic = 0; ic < 16; ++ic) wv[ic] = w2[t*16+ic];
    float lin = 0.f;
    #pragma unroll
    for (int ic = 0; ic < 16; ++ic) lin += wv[ic]*red[256+ic];
    float quad = 0.f;
    for (int i = 0; i < 16; ++i){
      float ri = 0.f;
      #pragma unroll
      for (int j = 0; j < 16; ++j) ri += wv[j]*red[i*16+j];
      quad += wv[i]*ri;
    }
    float bb = b2[t];
    float S = lin + (float)NWN * bb;
    float Q = quad + 2.f*bb*lin + (float)NWN*bb*bb;
    float m = S * (1.f/NWN);
    float v = Q * (1.f/NWN) - m*m;
    float a = g2[t] * rsqrtf(v + EPSF);
    float d = be2[t] - m*a;
    a2sh[t] = a;
    F[1360+t] = a*bb + d;
  }
  __syncthreads();
  for (int i = t; i < 1024; i += 256) F[336+i] = a2sh[i >> 4] * w2[i];
  {
    int ot = t >> 6, lane = t & 63;
    int oc = ot*16 + (lane & 15), icb = ((lane >> 4)) * 8;
    u16x8 fr;
    #pragma unroll
    for (int j = 0; j < 8; ++j){
      int ic = icb + j;
      fr[j] = (ic < 16) ? f2b(a2sh[oc] * w2[oc*16 + ic]) : (u16)0;
    }
    *(u16x8*)&w2Bg[t*8] = fr;
  }
}

// ---------------- K5: 16 points/block + fused stats + gather prefetch + merged H1/W ----------------
__global__ __launch_bounds__(256) void k_main(const float* lcg, const int* nbrg,
    const u16* ptsw, const float* F,
    const u16* w1Bg, const u16* w2Bg,
    u16* npw, float* PC){
  __shared__ __align__(16) u16 Gr[2][64*40];
  __shared__ __align__(16) u16 Wr[2][64*40];
  __shared__ __align__(16) u16 H0bf[2][32*40];
  __shared__ __align__(16) u16 H1bf[2][32*40];
  int t = threadIdx.x;
  int w = t >> 6, l = t & 63;
  int pbase = blockIdx.x * 16;
  s16x8 w1B  = *(const s16x8*)&w1Bg[l*8];
  s16x8 w2B0 = *(const s16x8*)&w2Bg[(0*64 + l)*8];
  s16x8 w2B1 = *(const s16x8*)&w2Bg[(1*64 + l)*8];
  s16x8 w2B2 = *(const s16x8*)&w2Bg[(2*64 + l)*8];
  s16x8 w2B3 = *(const s16x8*)&w2Bg[(3*64 + l)*8];
  float b1f  = F[320 + (l & 15)];
  float b2f0 = F[1360 +  0 + (l & 15)];
  float b2f1 = F[1360 + 16 + (l & 15)];
  float b2f2 = F[1360 + 32 + (l & 15)];
  float b2f3 = F[1360 + 48 + (l & 15)];
  int oc0 = (t & 7) * 2;
  f32x4 w0a = {F[oc0*3], F[oc0*3+1], F[oc0*3+2], F[48+oc0]};
  f32x4 w0b = {F[oc0*3+3], F[oc0*3+4], F[oc0*3+5], F[48+oc0+1]};
  int kg = w*8 + (l >> 3), c8 = l & 7;
  int kphys = ((w ^ (c8 & 3)) << 3) + (l >> 3);
  int kH = t >> 3, cpad = 16 + (t & 7)*2;
  {
    *(unsigned int*)&H0bf[0][kH*40 + cpad] = 0u;
    *(unsigned int*)&H0bf[1][kH*40 + cpad] = 0u;
    *(unsigned int*)&H1bf[0][kH*40 + cpad] = 0u;
    *(unsigned int*)&H1bf[1][kH*40 + cpad] = 0u;
  }
  float sacc[16], qacc[16];
  #pragma unroll
  for (int j = 0; j < 16; ++j){ sacc[j] = 0.f; qacc[j] = 0.f; }
  u16x8 gv0, gv1;
  float lx00, lx01, lx02, lx10, lx11, lx12;
  {
    int point = pbase;
    int bbp = point >> 10;
    int n = nbrg[(size_t)point*32 + kg];
    gv0 = *(const u16x8*)(ptsw + (size_t)(bbp * NN + n)*64 + c8*8);
    const float* xp = lcg + (size_t)point*96 + kH*3;
    lx00 = xp[0]; lx01 = xp[1]; lx02 = xp[2];
    int point1 = pbase + 1;
    int bbp1 = point1 >> 10;
    int n1 = nbrg[(size_t)point1*32 + kg];
    gv1 = *(const u16x8*)(ptsw + (size_t)(bbp1 * NN + n1)*64 + c8*8);
    const float* xp1 = lcg + (size_t)point1*96 + kH*3;
    lx10 = xp1[0]; lx11 = xp1[1]; lx12 = xp1[2];
  }
  __syncthreads();

  for (int g = 0; g < 8; ++g){
    int p0 = pbase + g*2;
    {
      #pragma unroll
      for (int j = 0; j < 8; ++j)
        Gr[0][(c8*8 + j)*40 + kphys] = gv0[j];
      #pragma unroll
      for (int j = 0; j < 8; ++j)
        Gr[1][(c8*8 + j)*40 + kphys] = gv1[j];
    }
    {
      H0bf[0][kH*40 + oc0]     = f2b(fmaxf(0.f, w0a.x*lx00 + w0a.y*lx01 + w0a.z*lx02 + w0a.w));
      H0bf[0][kH*40 + oc0 + 1] = f2b(fmaxf(0.f, w0b.x*lx00 + w0b.y*lx01 + w0b.z*lx02 + w0b.w));
      H0bf[1][kH*40 + oc0]     = f2b(fmaxf(0.f, w0a.x*lx10 + w0a.y*lx11 + w0a.z*lx12 + w0a.w));
      H0bf[1][kH*40 + oc0 + 1] = f2b(fmaxf(0.f, w0b.x*lx10 + w0b.y*lx11 + w0b.z*lx12 + w0b.w));
    }
    if (g < 7){
      int pn0 = p0 + 2, pn1 = p0 + 3;
      int bn0 = pn0 >> 10, bn1 = pn1 >> 10;
      int n0 = nbrg[(size_t)pn0*32 + kg];
      int n1 = nbrg[(size_t)pn1*32 + kg];
      gv0 = *(const u16x8*)(ptsw + (size_t)(bn0 * NN + n0)*64 + c8*8);
      gv1 = *(const u16x8*)(ptsw + (size_t)(bn1 * NN + n1)*64 + c8*8);
      const float* xp0 = lcg + (size_t)pn0*96 + kH*3;
      lx00 = xp0[0]; lx01 = xp0[1]; lx02 = xp0[2];
      const float* xp1 = lcg + (size_t)pn1*96 + kH*3;
      lx10 = xp1[0]; lx11 = xp1[1]; lx12 = xp1[2];
    }
    __syncthreads();   // (1) Gr + H0bf ready
    {
      int pt = w >> 1, kt = w & 1;
      s16x8 af = *(const s16x8*)&H0bf[pt][(kt*16 + (l & 15))*40 + (l >> 4)*8];
      f32x4 acc = {b1f, b1f, b1f, b1f};
      acc = __builtin_amdgcn_mfma_f32_16x16x32_bf16(af, w1B, acc, 0, 0, 0);
      #pragma unroll
      for (int r = 0; r < 4; ++r)
        H1bf[pt][(kt*16 + (l >> 4)*4 + r)*40 + (l & 15)] = f2b(fmaxf(0.f, acc[r]));
      s16x8 af2 = *(const s16x8*)&H1bf[pt][(kt*16 + (l & 15))*40 + (l >> 4)*8];
      int kbase = kt*16 + (l >> 4)*4;
      f32x4 a0c = {b2f0,b2f0,b2f0,b2f0};
      a0c = __builtin_amdgcn_mfma_f32_16x16x32_bf16(af2, w2B0, a0c, 0, 0, 0);
      u16x4 s0v; s0v[0]=f2b(fmaxf(0.f,a0c[0])); s0v[1]=f2b(fmaxf(0.f,a0c[1]));
      s0v[2]=f2b(fmaxf(0.f,a0c[2])); s0v[3]=f2b(fmaxf(0.f,a0c[3]));
      *(u16x4*)&Wr[pt][( 0 + (l & 15))*40 + kbase] = s0v;
      f32x4 a1c = {b2f1,b2f1,b2f1,b2f1};
      a1c = __builtin_amdgcn_mfma_f32_16x16x32_bf16(af2, w2B1, a1c, 0, 0, 0);
      u16x4 s1v; s1v[0]=f2b(fmaxf(0.f,a1c[0])); s1v[1]=f2b(fmaxf(0.f,a1c[1]));
      s1v[2]=f2b(fmaxf(0.f,a1c[2])); s1v[3]=f2b(fmaxf(0.f,a1c[3]));
      *(u16x4*)&Wr[pt][(16 + (l & 15))*40 + kbase] = s1v;
      f32x4 a2c = {b2f2,b2f2,b2f2,b2f2};
      a2c = __builtin_amdgcn_mfma_f32_16x16x32_bf16(af2, w2B2, a2c, 0, 0, 0);
      u16x4 s2v; s2v[0]=f2b(fmaxf(0.f,a2c[0])); s2v[1]=f2b(fmaxf(0.f,a2c[1]));
      s2v[2]=f2b(fmaxf(0.f,a2c[2])); s2v[3]=f2b(fmaxf(0.f,a2c[3]));
      *(u16x4*)&Wr[pt][(32 + (l & 15))*40 + kbase] = s2v;
      f32x4 a3c = {b2f3,b2f3,b2f3,b2f3};
      a3c = __builtin_amdgcn_mfma_f32_16x16x32_bf16(af2, w2B3, a3c, 0, 0, 0);
      u16x4 s3v; s3v[0]=f2b(fmaxf(0.f,a3c[0])); s3v[1]=f2b(fmaxf(0.f,a3c[1]));
      s3v[2]=f2b(fmaxf(0.f,a3c[2])); s3v[3]=f2b(fmaxf(0.f,a3c[3]));
      *(u16x4*)&Wr[pt][(48 + (l & 15))*40 + kbase] = s3v;
    }
    __syncthreads();   // (3) Wr ready
    {
      int li = l & 15, lkb = l >> 4, lr = (l >> 4) * 4;
      #pragma unroll
      for (int pt = 0; pt < 2; ++pt){
        s16x8 bfrag = *(const s16x8*)&Wr[pt][(w*16 + li)*40 + lkb*8];
        size_t obase = (size_t)(p0 + pt)*4096 + (size_t)(w*16 + li)*64 + lr;
        #pragma unroll
        for (int it = 0; it < 4; ++it){
          int ch = it*16 + li;
          int key = (ch >> 3) & 3;
          s16x8 afrag = *(const s16x8*)&Gr[pt][ch*40 + ((lkb ^ key) << 3)];
          f32x4 z = {0.f, 0.f, 0.f, 0.f};
          f32x4 d = __builtin_amdgcn_mfma_f32_16x16x32_bf16(afrag, bfrag, z, 0, 0, 0);
          u16x4 st;
          st[0] = f2b(d[0]); st[1] = f2b(d[1]); st[2] = f2b(d[2]); st[3] = f2b(d[3]);
          *(u16x4*)(npw + obase + it*16) = st;
          #pragma unroll
          for (int r = 0; r < 4; ++r){
            sacc[it*4 + r] += d[r];
            qacc[it*4 + r] += d[r]*d[r];
          }
        }
      }
    }
    __syncthreads();   // (0)
  }
  {
    int qb = (w*16 + (l & 15))*64 + (l >> 4)*4;
    float* dst = PC + (size_t)blockIdx.x * 8192;
    #pragma unroll
    for (int it = 0; it < 4; ++it){
      f32x4 sv = {sacc[it*4+0], sacc[it*4+1], sacc[it*4+2], sacc[it*4+3]};
      f32x4 qv = {qacc[it*4+0], qacc[it*4+1], qacc[it*4+2], qacc[it*4+3]};
      *(f32x4*)(dst + qb + it*16) = sv;
      *(f32x4*)(dst + 4096 + qb + it*16) = qv;
    }
  }
}

// ---------------- k_finC: reduce 1024 block partials + finalize (grid 256) ----------------
__global__ __launch_bounds__(256) void k_finC(const float* PC, const float* gc, const float* bc,
                                              float* AC, float* DC){
  __shared__ float shs[16][17], shq[16][17];
  int t = threadIdx.x;
  int ql = t & 15, rc = t >> 4;
  int qpos = blockIdx.x * 16 + ql;
  float s = 0.f, q = 0.f;
  int r0 = rc * 64;
  #pragma unroll 4
  for (int r = r0; r < r0 + 64; ++r){
    s += PC[(size_t)r * 8192 + qpos];
    q += PC[(size_t)r * 8192 + 4096 + qpos];
  }
  shs[ql][rc] = s; shq[ql][rc] = q;
  __syncthreads();
  if (t < 16){
    float ss = 0.f, qq = 0.f;
    #pragma unroll
    for (int c = 0; c < 16; ++c){ ss += shs[t][c]; qq += shq[t][c]; }
    int qp = blockIdx.x * 16 + t;
    int ch = (qp & 63)*64 + (qp >> 6);
    float m = ss * (1.f/16384.f);
    float v = qq * (1.f/16384.f) - m*m;
    float a = gc[ch] * rsqrtf(v + EPSF);
    AC[qp] = a; DC[qp] = bc[ch] - m*a;
  }
}

// ---------------- k_linear: K-SPLIT, grid 2048 (half = bid>>10), f32 partial out ----------------
__global__ __launch_bounds__(256) void k_linear(const u16* npw, const float* AC, const float* DC,
                                                const u16* lwbt, float* ywH){
  __shared__ u16 Al[2][16*72];
  __shared__ u16 Bl[2][64*72];
  int t = threadIdx.x;
  int w = t >> 6, l = t & 63;
  int half = blockIdx.x >> 10;
  int rowbase = (blockIdx.x & 1023) * 16;
  int kb0 = half * 2048;
  int rA = t >> 4, cA = t & 15;
  int nB = t >> 3, cB = t & 7;
  const u16* Aptr  = npw  + (size_t)(rowbase + rA)*4096 + kb0 + cA*4;
  const u16* B0ptr = lwbt + (size_t)nB*4096 + kb0 + cB*8;
  const u16* B1ptr = lwbt + (size_t)(nB + 32)*4096 + kb0 + cB*8;
  const float* ACh = AC + kb0;
  const float* DCh = DC + kb0;
  f32x4 acc0 = {0.f,0.f,0.f,0.f};
  u16x4 uA  = *(const u16x4*)(Aptr);
  u16x8 uB0 = *(const u16x8*)(B0ptr);
  u16x8 uB1 = *(const u16x8*)(B1ptr);
  {
    int kk = cA*4;
    f32x4 av = *(const f32x4*)(ACh + kk);
    f32x4 dv = *(const f32x4*)(DCh + kk);
    u16x4 o;
    o[0] = f2b(fmaxf(0.f, av.x*bf(uA[0]) + dv.x));
    o[1] = f2b(fmaxf(0.f, av.y*bf(uA[1]) + dv.y));
    o[2] = f2b(fmaxf(0.f, av.z*bf(uA[2]) + dv.z));
    o[3] = f2b(fmaxf(0.f, av.w*bf(uA[3]) + dv.w));
    *(u16x4*)&Al[0][rA*72 + cA*4] = o;
    *(u16x8*)&Bl[0][nB*72 + cB*8]        = uB0;
    *(u16x8*)&Bl[0][(nB + 32)*72 + cB*8] = uB1;
  }
  uA  = *(const u16x4*)(Aptr + 64);
  uB0 = *(const u16x8*)(B0ptr + 64);
  uB1 = *(const u16x8*)(B1ptr + 64);
  __syncthreads();
  int cur = 0;
  for (int kb = 0; kb < 2048; kb += 64){
    if (kb + 64 < 2048){
      int kk = kb + 64 + cA*4;
      f32x4 av = *(const f32x4*)(ACh + kk);
      f32x4 dv = *(const f32x4*)(DCh + kk);
      u16x4 o;
      o[0] = f2b(fmaxf(0.f, av.x*bf(uA[0]) + dv.x));
      o[1] = f2b(fmaxf(0.f, av.y*bf(uA[1]) + dv.y));
      o[2] = f2b(fmaxf(0.f, av.z*bf(uA[2]) + dv.z));
      o[3] = f2b(fmaxf(0.f, av.w*bf(uA[3]) + dv.w));
      *(u16x4*)&Al[cur^1][rA*72 + cA*4] = o;
      *(u16x8*)&Bl[cur^1][nB*72 + cB*8]        = uB0;
      *(u16x8*)&Bl[cur^1][(nB + 32)*72 + cB*8] = uB1;
      if (kb + 128 < 2048){
        uA  = *(const u16x4*)(Aptr + kb + 128);
        uB0 = *(const u16x8*)(B0ptr + kb + 128);
        uB1 = *(const u16x8*)(B1ptr + kb + 128);
      }
    }
    #pragma unroll
    for (int ks = 0; ks < 2; ++ks){
      s16x8 af  = *(const s16x8*)&Al[cur][((l & 15))*72 + ks*32 + (l >> 4)*8];
      s16x8 bf0 = *(const s16x8*)&Bl[cur][(w*16 + (l & 15))*72 + ks*32 + (l >> 4)*8];
      acc0 = __builtin_amdgcn_mfma_f32_16x16x32_bf16(af, bf0, acc0, 0, 0, 0);
    }
    __syncthreads();
    cur ^= 1;
  }
  int col0 = w*16 + (l & 15);
  float* dst = ywH + (size_t)half * (NPTS*64);
  #pragma unroll
  for (int r = 0; r < 4; ++r){
    int row = rowbase + (l >> 4)*4 + r;
    dst[(size_t)row*64 + col0] = acc0[r];
  }
}

// ---------------- k_statY: final-BN stats from ywA+ywB+lb (grid 64) ----------------
__global__ __launch_bounds__(256) void k_statY(const float* ywH, const float* lb, float* PL){
  __shared__ float sh[4][128];
  int t = threadIdx.x;
  int o = t & 63;
  int w = t >> 6;
  int rg = blockIdx.x * 4 + w;
  float lbv = lb[o];
  const float* ywA = ywH;
  const float* ywB = ywH + (size_t)NPTS*64;
  float s = 0.f, q = 0.f;
  for (int r = rg * 64; r < rg * 64 + 64; ++r){
    float v = ywA[(size_t)r * 64 + o] + ywB[(size_t)r * 64 + o] + lbv;
    s += v; q += v*v;
  }
  sh[w][o] = s; sh[w][64+o] = q;
  __syncthreads();
  if (t < 128) PL[blockIdx.x*128 + t] = sh[0][t] + sh[1][t] + sh[2][t] + sh[3][t];
}

// ---------------- k_redF (64 blocks of PL) ----------------
__global__ __launch_bounds__(128) void k_redF(const float* PL, float* SL){
  int t = threadIdx.x;
  float s = 0.f;
  for (int b = 0; b < 64; ++b) s += PL[b*128 + t];
  SL[t] = s;
}

// ---------------- k_final: y = ywA+ywB+lb, bn+relu ----------------
__global__ __launch_bounds__(256) void k_final(const float* ywH, const float* SL,
                                               const float* gl, const float* bl, const float* lb,
                                               float* out){
  int e = (blockIdx.x * 256 + threadIdx.x) * 4;
  int o = e & 63;
  const float* ywA = ywH;
  const float* ywB = ywH + (size_t)NPTS*64;
  f32x4 ya = *(const f32x4*)(ywA + e);
  f32x4 yb = *(const f32x4*)(ywB + e);
  f32x4 r;
  #pragma unroll
  for (int j = 0; j < 4; ++j){
    float y = ya[j] + yb[j] + lb[o+j];
    float m = SL[o+j] * (1.f/16384.f);
    float v = SL[64+o+j] * (1.f/16384.f) - m*m;
    float a = gl[o+j] * rsqrtf(v + EPSF);
    float d = bl[o+j] - m*a;
    r[j] = fmaxf(0.f, a*y + d);
  }
  *(f32x4*)(out + 49152 + e) = r;
}

extern "C" void kernel_launch(void* const* d_in, const int* in_sizes, int n_in,
                              void* d_out, int out_size, void* d_ws, size_t ws_size,
                              hipStream_t stream){
  (void)in_sizes; (void)n_in; (void)out_size; (void)ws_size;
  const float* xyz    = (const float*)d_in[0];
  const float* points = (const float*)d_in[1];
  const float* lc     = (const float*)d_in[2];
  const int*   nbrl   = (const int*)d_in[3];
  const int*   didx   = (const int*)d_in[4];
  const float* w0 = (const float*)d_in[5];
  const float* b0 = (const float*)d_in[6];
  const float* g0 = (const float*)d_in[7];
  const float* be0= (const float*)d_in[8];
  const float* w1 = (const float*)d_in[9];
  const float* b1 = (const float*)d_in[10];
  const float* g1 = (const float*)d_in[11];
  const float* be1= (const float*)d_in[12];
  const float* w2 = (const float*)d_in[13];
  const float* b2 = (const float*)d_in[14];
  const float* g2 = (const float*)d_in[15];
  const float* be2= (const float*)d_in[16];
  const float* gc = (const float*)d_in[17];
  const float* bc = (const float*)d_in[18];
  const float* lw = (const float*)d_in[19];
  const float* lb = (const float*)d_in[20];
  const float* gl = (const float*)d_in[21];
  const float* bl = (const float*)d_in[22];
  float* out = (float*)d_out;
  char* ws = (char*)d_ws;

  // small region (< 2 MB)
  float* F   = (float*)ws;           // 1536
  float* SL  = F + 1536;             // 128
  float* AC  = SL + 128;             // 4096
  float* DC  = AC + 4096;            // 4096
  float* PA  = DC + 4096;            // 32768
  float* PB1 = PA + 32768;           // 139264
  float* PB2 = PB1 + 139264;         // 139264
  float* PL  = PB2 + 139264;         // 8192 (64 x 128)
  u16*  w1Bg = (u16*)(PL + 131072);  // 512 u16 (keep offset)
  u16*  w2Bg = w1Bg + 512;           // 2048 u16
  u16*  lwbt = (u16*)(ws + 2097152);                 // 512 KB (permuted), @2MB
  float* PC  = (float*)(ws + 4194304);               // 32 MB (1024 x 8192), @4MB
  float* ywH = (float*)(ws + 4194304);               // 8 MB (ywA+ywB), ALIASES PC (disjoint lifetime)
  u16*  npw  = (u16*)(ws + 37748736);                // 128 MB bf16 (transposed), @36MB
  u16*  ptsw = (u16*)(ws + 171966464);               // 8 MB bf16, @164MB (end 172MB)

  k_init  <<<1152,  256, 0, stream>>>(xyz, didx, out, lw, lwbt, points, ptsw, lc, PA);
  k_red0  <<<1,     256, 0, stream>>>(PA, w0, b0, g0, be0, F);
  k_statG1<<<SGBLK, 256, 0, stream>>>(lc, F, PB1);
  k_red1  <<<1,     256, 0, stream>>>(PB1, w1, b1, g1, be1, F, w1Bg);
  k_statG2<<<SGBLK, 256, 0, stream>>>(lc, F, w1Bg, PB2);
  k_red2  <<<1,     256, 0, stream>>>(PB2, w2, b2, g2, be2, F, w2Bg);
  k_main  <<<1024,  256, 0, stream>>>(lc, nbrl, ptsw, F, w1Bg, w2Bg, npw, PC);
  k_finC  <<<256,   256, 0, stream>>>(PC, gc, bc, AC, DC);
  k_linear<<<2048,  256, 0, stream>>>(npw, AC, DC, lwbt, ywH);
  k_statY <<<64,    256, 0, stream>>>(ywH, lb, PL);
  k_redF  <<<1,     128, 0, stream>>>(PL, SL);
  k_final <<<1024,  256, 0, stream>>>(ywH, SL, gl, bl, lb, out);
}